// Round 1
// baseline (1160.115 us; speedup 1.0000x reference)
//
#include <hip/hip_runtime.h>
#include <cstddef>

static constexpr int Bb = 64;     // batch
static constexpr int Nn = 256;    // nodes
static constexpr int Td = 512;    // time dim
static constexpr int NMAXS = 51;  // 256 // 5
static constexpr float EPSN = 1e-5f;
static constexpr float EPSD = 1e-10f;

// ---------------- LayerNorm ----------------
__global__ __launch_bounds__(256) void ln_stats_k(const float* __restrict__ x,
                                                  float* __restrict__ st) {
    int b = blockIdx.x;
    const float* p = x + (size_t)b * Nn * Td;
    float s = 0.f, s2 = 0.f;
    for (int i = threadIdx.x; i < Nn * Td; i += 256) {
        float v = p[i];
        s += v; s2 += v * v;
    }
    __shared__ float sh[256], sh2[256];
    sh[threadIdx.x] = s; sh2[threadIdx.x] = s2;
    __syncthreads();
    for (int o = 128; o > 0; o >>= 1) {
        if (threadIdx.x < o) { sh[threadIdx.x] += sh[threadIdx.x + o]; sh2[threadIdx.x] += sh2[threadIdx.x + o]; }
        __syncthreads();
    }
    if (threadIdx.x == 0) {
        float inv = 1.f / (Nn * Td);
        float mu = sh[0] * inv;
        float var = sh2[0] * inv - mu * mu;
        st[b * 2] = mu;
        st[b * 2 + 1] = rsqrtf(var + EPSN);
    }
}

__global__ __launch_bounds__(256) void ln_apply_k(const float4* __restrict__ x,
                                                  const float4* __restrict__ w,
                                                  const float4* __restrict__ bia,
                                                  const float* __restrict__ st,
                                                  float4* __restrict__ out) {
    int i = blockIdx.x * 256 + threadIdx.x;   // over B*N*T/4 = 2097152
    int r = i & ((Nn * Td / 4) - 1);          // within-batch vec index
    int b = i >> 15;                          // N*T/4 = 32768 = 1<<15
    float mu = st[b * 2], rs = st[b * 2 + 1];
    float4 xv = x[i], wv = w[r], bv = bia[r];
    float4 o;
    o.x = (xv.x - mu) * rs * wv.x + bv.x;
    o.y = (xv.y - mu) * rs * wv.y + bv.y;
    o.z = (xv.z - mu) * rs * wv.z + bv.z;
    o.w = (xv.w - mu) * rs * wv.w + bv.w;
    out[i] = o;
}

// ---------------- BatchNorm (training-mode batch stats, per node) ----------------
__global__ __launch_bounds__(256) void bn_stats_k(const float* __restrict__ x_ln,
                                                  const float* __restrict__ g,
                                                  const float* __restrict__ be,
                                                  float* __restrict__ bnsc,
                                                  float* __restrict__ bnsh) {
    int n = blockIdx.x;
    float s = 0.f, s2 = 0.f;
    for (int i = threadIdx.x; i < Bb * Td; i += 256) {
        int b = i >> 9, t = i & 511;
        float v = x_ln[(size_t)b * Nn * Td + (size_t)n * Td + t];
        s += v; s2 += v * v;
    }
    __shared__ float sh[256], sh2[256];
    sh[threadIdx.x] = s; sh2[threadIdx.x] = s2;
    __syncthreads();
    for (int o = 128; o > 0; o >>= 1) {
        if (threadIdx.x < o) { sh[threadIdx.x] += sh[threadIdx.x + o]; sh2[threadIdx.x] += sh2[threadIdx.x + o]; }
        __syncthreads();
    }
    if (threadIdx.x == 0) {
        float inv = 1.f / (Bb * Td);
        float mu = sh[0] * inv;
        float var = sh2[0] * inv - mu * mu;
        float rs = rsqrtf(var + EPSN);
        float scale = rs * g[n];
        bnsc[n] = scale;
        bnsh[n] = be[n] - mu * scale;
    }
}

__global__ __launch_bounds__(256) void bn_apply_k(float4* __restrict__ x,
                                                  const float* __restrict__ sc,
                                                  const float* __restrict__ shf) {
    int i = blockIdx.x * 256 + threadIdx.x;   // vec index over B*N*T/4
    int n = (i >> 7) & 255;                   // T/4 = 128 vecs per row
    float s = sc[n], h = shf[n];
    float4 v = x[i];
    v.x = v.x * s + h; v.y = v.y * s + h; v.z = v.z * s + h; v.w = v.w * s + h;
    x[i] = v;
}

// ---------------- GEMM NT: C[m,n] = sum_k A[m*K+k]*Bm[n*K+k] (+bias[n]) ----------------
template <bool BIAS>
__global__ __launch_bounds__(256) void gemm_nt_k(const float* __restrict__ A,
                                                 const float* __restrict__ Bm,
                                                 const float* __restrict__ bias,
                                                 float* __restrict__ C,
                                                 int Ncols, int K,
                                                 long long sA, long long sB, long long sC) {
    __shared__ float As[64][17];
    __shared__ float Bs[64][17];
    const float* Ab = A + (size_t)blockIdx.z * sA;
    const float* Bbp = Bm + (size_t)blockIdx.z * sB;
    float* Cb = C + (size_t)blockIdx.z * sC;
    int br = blockIdx.y * 64, bc = blockIdx.x * 64;
    int tid = threadIdx.x;
    int tx = tid & 15, ty = tid >> 4;
    int lr = tid >> 2, lk = (tid & 3) << 2;
    float acc[4][4] = {};
    for (int k0 = 0; k0 < K; k0 += 16) {
        float4 av = *(const float4*)(Ab + (size_t)(br + lr) * K + k0 + lk);
        float4 bv = *(const float4*)(Bbp + (size_t)(bc + lr) * K + k0 + lk);
        As[lr][lk] = av.x; As[lr][lk + 1] = av.y; As[lr][lk + 2] = av.z; As[lr][lk + 3] = av.w;
        Bs[lr][lk] = bv.x; Bs[lr][lk + 1] = bv.y; Bs[lr][lk + 2] = bv.z; Bs[lr][lk + 3] = bv.w;
        __syncthreads();
#pragma unroll
        for (int kk = 0; kk < 16; ++kk) {
            float a[4], bvv[4];
#pragma unroll
            for (int i = 0; i < 4; ++i) a[i] = As[ty * 4 + i][kk];
#pragma unroll
            for (int j = 0; j < 4; ++j) bvv[j] = Bs[tx * 4 + j][kk];
#pragma unroll
            for (int i = 0; i < 4; ++i)
#pragma unroll
                for (int j = 0; j < 4; ++j) acc[i][j] += a[i] * bvv[j];
        }
        __syncthreads();
    }
#pragma unroll
    for (int i = 0; i < 4; ++i)
#pragma unroll
        for (int j = 0; j < 4; ++j) {
            float v = acc[i][j];
            int col = bc + tx * 4 + j;
            if (BIAS) v += bias[col];
            Cb[(size_t)(br + ty * 4 + i) * Ncols + col] = v;
        }
}

// ---------------- GEMM NN: C[m,n] (+)= alpha*sum_k A[m*K+k]*Bm[k*Ncols+n] ----------------
// SUBPREV: v = alpha*acc - prev[idx];  ACC: v += C[idx];  FINAL: v = relu(v + bias[n])
template <bool ACC, bool FINAL, bool SUBPREV>
__global__ __launch_bounds__(256) void gemm_nn_k(const float* __restrict__ A,
                                                 const float* __restrict__ Bm,
                                                 const float* __restrict__ bias,
                                                 const float* __restrict__ prev,
                                                 float* __restrict__ C, float alpha,
                                                 int Ncols, int K,
                                                 long long sA, long long sB, long long sPrev, long long sC) {
    __shared__ float As[64][17];
    __shared__ float Bs[16][68];
    const float* Ab = A + (size_t)blockIdx.z * sA;
    const float* Bbp = Bm + (size_t)blockIdx.z * sB;
    const float* Pb = SUBPREV ? prev + (size_t)blockIdx.z * sPrev : nullptr;
    float* Cb = C + (size_t)blockIdx.z * sC;
    int br = blockIdx.y * 64, bc = blockIdx.x * 64;
    int tid = threadIdx.x;
    int tx = tid & 15, ty = tid >> 4;
    int lar = tid >> 2, lak = (tid & 3) << 2;   // A tile: 64 rows x 16 k
    int lbr = tid >> 4, lbc = (tid & 15) << 2;  // B tile: 16 k x 64 cols
    float acc[4][4] = {};
    for (int k0 = 0; k0 < K; k0 += 16) {
        float4 av = *(const float4*)(Ab + (size_t)(br + lar) * K + k0 + lak);
        float4 bv = *(const float4*)(Bbp + (size_t)(k0 + lbr) * Ncols + bc + lbc);
        As[lar][lak] = av.x; As[lar][lak + 1] = av.y; As[lar][lak + 2] = av.z; As[lar][lak + 3] = av.w;
        Bs[lbr][lbc] = bv.x; Bs[lbr][lbc + 1] = bv.y; Bs[lbr][lbc + 2] = bv.z; Bs[lbr][lbc + 3] = bv.w;
        __syncthreads();
#pragma unroll
        for (int kk = 0; kk < 16; ++kk) {
            float a[4], bvv[4];
#pragma unroll
            for (int i = 0; i < 4; ++i) a[i] = As[ty * 4 + i][kk];
#pragma unroll
            for (int j = 0; j < 4; ++j) bvv[j] = Bs[kk][tx * 4 + j];
#pragma unroll
            for (int i = 0; i < 4; ++i)
#pragma unroll
                for (int j = 0; j < 4; ++j) acc[i][j] += a[i] * bvv[j];
        }
        __syncthreads();
    }
#pragma unroll
    for (int i = 0; i < 4; ++i)
#pragma unroll
        for (int j = 0; j < 4; ++j) {
            float v = alpha * acc[i][j];
            int col = bc + tx * 4 + j;
            size_t idx = (size_t)(br + ty * 4 + i) * Ncols + col;
            if (SUBPREV) v -= Pb[idx];
            if (ACC) v += Cb[idx];
            if (FINAL) v = fmaxf(v + bias[col], 0.f);
            Cb[idx] = v;
        }
}

// ---------------- top-k threshold + adjacency + degree ----------------
__global__ __launch_bounds__(256) void topk_k(float* __restrict__ sc,
                                              const float* __restrict__ dis,
                                              float* __restrict__ dinv) {
    int row = blockIdx.x;       // b*256 + n
    int n = row & 255;
    int tid = threadIdx.x;
    float* srow = sc + (size_t)row * Nn;
    __shared__ float sh[256];
    float myv = srow[tid];
    sh[tid] = myv;
    __syncthreads();
    // bitonic sort ascending
    for (int k = 2; k <= 256; k <<= 1) {
        for (int j = k >> 1; j > 0; j >>= 1) {
            int ixj = tid ^ j;
            if (ixj > tid) {
                float a = sh[tid], b = sh[ixj];
                bool up = ((tid & k) == 0);
                if ((a > b) == up) { sh[tid] = b; sh[ixj] = a; }
            }
            __syncthreads();
        }
    }
    float kth = sh[256 - NMAXS];   // 51st largest
    __syncthreads();
    float as = (myv >= kth) ? myv : 0.f;
    float a = fmaxf(as + dis[(size_t)n * Nn + tid], 0.f);
    srow[tid] = a;
    sh[tid] = a;
    __syncthreads();
    for (int o = 128; o > 0; o >>= 1) {
        if (tid < o) sh[tid] += sh[tid + o];
        __syncthreads();
    }
    if (tid == 0) dinv[row] = rsqrtf(sh[0] + EPSD);
}

// L[b,n,m] = A[b,n,m] * dinv[b,n] * dinv[b,m]
__global__ __launch_bounds__(256) void lscale_k(float* __restrict__ L,
                                                const float* __restrict__ dinv) {
    int i = blockIdx.x * 256 + threadIdx.x;   // over B*N*N
    int m = i & 255;
    int bn = i >> 8;
    int b = bn >> 8;
    L[i] = L[i] * dinv[bn] * dinv[(b << 8) + m];
}

extern "C" void kernel_launch(void* const* d_in, const int* in_sizes, int n_in,
                              void* d_out, int out_size, void* d_ws, size_t ws_size,
                              hipStream_t stream) {
    const float* x      = (const float*)d_in[0];
    const float* dis    = (const float*)d_in[1];
    const float* ln_w   = (const float*)d_in[2];
    const float* ln_b   = (const float*)d_in[3];
    const float* bn_g   = (const float*)d_in[4];
    const float* bn_b   = (const float*)d_in[5];
    const float* li_w   = (const float*)d_in[6];
    const float* li_b   = (const float*)d_in[7];
    const float* cheb_w = (const float*)d_in[8];
    const float* cheb_b = (const float*)d_in[9];
    float* out = (float*)d_out;

    const size_t BNT = (size_t)Bb * Nn * Td;   // 8388608
    const size_t BNN = (size_t)Bb * Nn * Nn;   // 4194304
    float* ws   = (float*)d_ws;
    float* x_ln = ws;              // BNT   (later: x_bn/Tx0, then Tx2 in place)
    float* xp   = x_ln + BNT;      // BNT   (later: Tx1)
    float* sc   = xp + BNT;        // BNN   (scores -> A -> L in place)
    float* lnst = sc + BNN;        // 2*B
    float* dinv = lnst + 2 * Bb;   // B*N
    float* bnsc = dinv + Bb * Nn;  // N
    float* bnsh = bnsc + Nn;       // N

    // 1. LayerNorm
    hipLaunchKernelGGL(ln_stats_k, dim3(Bb), dim3(256), 0, stream, x, lnst);
    hipLaunchKernelGGL(ln_apply_k, dim3(BNT / 1024), dim3(256), 0, stream,
                       (const float4*)x, (const float4*)ln_w, (const float4*)ln_b, lnst, (float4*)x_ln);
    // 2. xp = x_ln @ li_w^T + li_b
    hipLaunchKernelGGL((gemm_nt_k<true>), dim3(Td / 64, Bb * Nn / 64, 1), dim3(256), 0, stream,
                       x_ln, li_w, li_b, xp, Td, Td, 0LL, 0LL, 0LL);
    // 3. scores[b] = xp[b] @ xp[b]^T
    hipLaunchKernelGGL((gemm_nt_k<false>), dim3(Nn / 64, Nn / 64, Bb), dim3(256), 0, stream,
                       xp, xp, (const float*)nullptr, sc, Nn, Td,
                       (long long)Nn * Td, (long long)Nn * Td, (long long)Nn * Nn);
    // 4. top-k threshold, +dis_adj, relu, degree
    hipLaunchKernelGGL(topk_k, dim3(Bb * Nn), dim3(256), 0, stream, sc, dis, dinv);
    // 5. L = D^-1/2 A D^-1/2 (in place)
    hipLaunchKernelGGL(lscale_k, dim3(BNN / 256), dim3(256), 0, stream, sc, dinv);
    // 6. BatchNorm (stats from x_ln, then in-place -> x_bn = Tx0)
    hipLaunchKernelGGL(bn_stats_k, dim3(Nn), dim3(256), 0, stream, x_ln, bn_g, bn_b, bnsc, bnsh);
    hipLaunchKernelGGL(bn_apply_k, dim3(BNT / 1024), dim3(256), 0, stream, (float4*)x_ln, bnsc, bnsh);
    // 7. out = Tx0 @ W0
    hipLaunchKernelGGL((gemm_nn_k<false, false, false>), dim3(Td / 64, Bb * Nn / 64, 1), dim3(256), 0, stream,
                       x_ln, cheb_w, (const float*)nullptr, (const float*)nullptr, out, 1.0f, Td, Td,
                       0LL, 0LL, 0LL, 0LL);
    // 8. Tx1 = L @ Tx0  -> xp buffer
    hipLaunchKernelGGL((gemm_nn_k<false, false, false>), dim3(Td / 64, Nn / 64, Bb), dim3(256), 0, stream,
                       sc, x_ln, (const float*)nullptr, (const float*)nullptr, xp, 1.0f, Td, Nn,
                       (long long)Nn * Nn, (long long)Nn * Td, 0LL, (long long)Nn * Td);
    // 9. out += Tx1 @ W1
    hipLaunchKernelGGL((gemm_nn_k<true, false, false>), dim3(Td / 64, Bb * Nn / 64, 1), dim3(256), 0, stream,
                       xp, cheb_w + (size_t)Td * Td, (const float*)nullptr, (const float*)nullptr, out, 1.0f, Td, Td,
                       0LL, 0LL, 0LL, 0LL);
    // 10. Tx2 = 2 L @ Tx1 - Tx0  -> x_ln buffer (in place over Tx0)
    hipLaunchKernelGGL((gemm_nn_k<false, false, true>), dim3(Td / 64, Nn / 64, Bb), dim3(256), 0, stream,
                       sc, xp, (const float*)nullptr, x_ln, x_ln, 2.0f, Td, Nn,
                       (long long)Nn * Nn, (long long)Nn * Td, (long long)Nn * Td, (long long)Nn * Td);
    // 11. out = relu(out + Tx2 @ W2 + cheb_b)
    hipLaunchKernelGGL((gemm_nn_k<true, true, false>), dim3(Td / 64, Bb * Nn / 64, 1), dim3(256), 0, stream,
                       x_ln, cheb_w + (size_t)2 * Td * Td, cheb_b, (const float*)nullptr, out, 1.0f, Td, Td,
                       0LL, 0LL, 0LL, 0LL);
}

// Round 2
// 802.124 us; speedup vs baseline: 1.4463x; 1.4463x over previous
//
#include <hip/hip_runtime.h>
#include <cstddef>

static constexpr int Bb = 64;     // batch
static constexpr int Nn = 256;    // nodes
static constexpr int Td = 512;    // time dim
static constexpr int NMAXS = 51;  // 256 // 5
static constexpr float EPSN = 1e-5f;
static constexpr float EPSD = 1e-10f;

// ---------------- LayerNorm stats: two-stage ----------------
// Stage A: grid (32, B), 256 thr; each block reduces 4096 floats (1024 float4)
__global__ __launch_bounds__(256) void ln_partial_k(const float4* __restrict__ x,
                                                    float2* __restrict__ part) {
    int b = blockIdx.y, c = blockIdx.x;
    int base = b * 32768 + c * 1024;   // N*T/4 = 32768 vecs per batch
    float s = 0.f, s2 = 0.f;
#pragma unroll
    for (int j = 0; j < 4; ++j) {
        float4 v = x[base + j * 256 + threadIdx.x];
        s += v.x + v.y + v.z + v.w;
        s2 += v.x * v.x + v.y * v.y + v.z * v.z + v.w * v.w;
    }
    __shared__ float sh[256], sh2[256];
    sh[threadIdx.x] = s; sh2[threadIdx.x] = s2;
    __syncthreads();
    for (int o = 128; o > 0; o >>= 1) {
        if (threadIdx.x < o) { sh[threadIdx.x] += sh[threadIdx.x + o]; sh2[threadIdx.x] += sh2[threadIdx.x + o]; }
        __syncthreads();
    }
    if (threadIdx.x == 0) part[b * 32 + c] = make_float2(sh[0], sh2[0]);
}

__global__ __launch_bounds__(64) void ln_final_k(const float2* __restrict__ part,
                                                 float* __restrict__ st) {
    int b = blockIdx.x, t = threadIdx.x;
    float s = 0.f, s2 = 0.f;
    if (t < 32) { float2 p = part[b * 32 + t]; s = p.x; s2 = p.y; }
    for (int o = 32; o > 0; o >>= 1) { s += __shfl_down(s, o, 64); s2 += __shfl_down(s2, o, 64); }
    if (t == 0) {
        float inv = 1.f / (Nn * Td);
        float mu = s * inv;
        float var = s2 * inv - mu * mu;
        st[b * 2] = mu;
        st[b * 2 + 1] = rsqrtf(var + EPSN);
    }
}

__global__ __launch_bounds__(256) void ln_apply_k(const float4* __restrict__ x,
                                                  const float4* __restrict__ w,
                                                  const float4* __restrict__ bia,
                                                  const float* __restrict__ st,
                                                  float4* __restrict__ out) {
    int i = blockIdx.x * 256 + threadIdx.x;   // over B*N*T/4 = 2097152
    int r = i & ((Nn * Td / 4) - 1);
    int b = i >> 15;
    float mu = st[b * 2], rs = st[b * 2 + 1];
    float4 xv = x[i], wv = w[r], bv = bia[r];
    float4 o;
    o.x = (xv.x - mu) * rs * wv.x + bv.x;
    o.y = (xv.y - mu) * rs * wv.y + bv.y;
    o.z = (xv.z - mu) * rs * wv.z + bv.z;
    o.w = (xv.w - mu) * rs * wv.w + bv.w;
    out[i] = o;
}

// ---------------- BatchNorm stats: two-stage ----------------
// Stage A: grid (8, N), 256 thr; block (n,c) reduces batches c*8..c*8+7 of node n
__global__ __launch_bounds__(256) void bn_partial_k(const float4* __restrict__ x,
                                                    float2* __restrict__ part) {
    int n = blockIdx.y, c = blockIdx.x;
    float s = 0.f, s2 = 0.f;
#pragma unroll
    for (int j = 0; j < 4; ++j) {
        int f = j * 256 + threadIdx.x;     // 0..1023
        int bl = f >> 7, t4 = f & 127;     // batch-local, vec within row (T/4=128)
        float4 v = x[((size_t)(c * 8 + bl) * Nn + n) * 128 + t4];
        s += v.x + v.y + v.z + v.w;
        s2 += v.x * v.x + v.y * v.y + v.z * v.z + v.w * v.w;
    }
    __shared__ float sh[256], sh2[256];
    sh[threadIdx.x] = s; sh2[threadIdx.x] = s2;
    __syncthreads();
    for (int o = 128; o > 0; o >>= 1) {
        if (threadIdx.x < o) { sh[threadIdx.x] += sh[threadIdx.x + o]; sh2[threadIdx.x] += sh2[threadIdx.x + o]; }
        __syncthreads();
    }
    if (threadIdx.x == 0) part[n * 8 + c] = make_float2(sh[0], sh2[0]);
}

__global__ __launch_bounds__(64) void bn_final_k(const float2* __restrict__ part,
                                                 const float* __restrict__ g,
                                                 const float* __restrict__ be,
                                                 float* __restrict__ bnsc,
                                                 float* __restrict__ bnsh) {
    int n = blockIdx.x, t = threadIdx.x;
    float s = 0.f, s2 = 0.f;
    if (t < 8) { float2 p = part[n * 8 + t]; s = p.x; s2 = p.y; }
    for (int o = 32; o > 0; o >>= 1) { s += __shfl_down(s, o, 64); s2 += __shfl_down(s2, o, 64); }
    if (t == 0) {
        float inv = 1.f / (Bb * Td);
        float mu = s * inv;
        float var = s2 * inv - mu * mu;
        float rs = rsqrtf(var + EPSN);
        float scale = rs * g[n];
        bnsc[n] = scale;
        bnsh[n] = be[n] - mu * scale;
    }
}

__global__ __launch_bounds__(256) void bn_apply_k(float4* __restrict__ x,
                                                  const float* __restrict__ sc,
                                                  const float* __restrict__ shf) {
    int i = blockIdx.x * 256 + threadIdx.x;
    int n = (i >> 7) & 255;
    float s = sc[n], h = shf[n];
    float4 v = x[i];
    v.x = v.x * s + h; v.y = v.y * s + h; v.z = v.z * s + h; v.w = v.w * s + h;
    x[i] = v;
}

// ---------------- GEMM 128x128 tile, 8x8 microtile ----------------
// NT: C[m,n] = sum_k A[m*K+k]*Bm[n*K+k] (+bias[n]).  Both LDS tiles k-major, pad 132.
template <bool BIAS>
__global__ __launch_bounds__(256) void gemm_nt128_k(const float* __restrict__ A,
                                                    const float* __restrict__ Bm,
                                                    const float* __restrict__ bias,
                                                    float* __restrict__ C,
                                                    int Ncols, int K,
                                                    long long sA, long long sB, long long sC) {
    __shared__ float As[16][132];
    __shared__ float Bs[16][132];
    const float* Ab = A + (size_t)blockIdx.z * sA;
    const float* Bbp = Bm + (size_t)blockIdx.z * sB;
    float* Cb = C + (size_t)blockIdx.z * sC;
    int br = blockIdx.y * 128, bc = blockIdx.x * 128;
    int tid = threadIdx.x;
    int tx = tid & 15, ty = tid >> 4;
    float acc[8][8] = {};
    for (int k0 = 0; k0 < K; k0 += 16) {
#pragma unroll
        for (int h = 0; h < 2; ++h) {
            int f = h * 256 + tid;           // 0..511 float4 slots
            int r = f >> 2, kq = (f & 3) << 2;
            float4 av = *(const float4*)(Ab + (size_t)(br + r) * K + k0 + kq);
            float4 bv = *(const float4*)(Bbp + (size_t)(bc + r) * K + k0 + kq);
            As[kq][r] = av.x; As[kq + 1][r] = av.y; As[kq + 2][r] = av.z; As[kq + 3][r] = av.w;
            Bs[kq][r] = bv.x; Bs[kq + 1][r] = bv.y; Bs[kq + 2][r] = bv.z; Bs[kq + 3][r] = bv.w;
        }
        __syncthreads();
#pragma unroll
        for (int kk = 0; kk < 16; ++kk) {
            float4 a0 = *(const float4*)&As[kk][ty * 8];
            float4 a1 = *(const float4*)&As[kk][ty * 8 + 4];
            float4 b0 = *(const float4*)&Bs[kk][tx * 8];
            float4 b1 = *(const float4*)&Bs[kk][tx * 8 + 4];
            float a[8] = {a0.x, a0.y, a0.z, a0.w, a1.x, a1.y, a1.z, a1.w};
            float b[8] = {b0.x, b0.y, b0.z, b0.w, b1.x, b1.y, b1.z, b1.w};
#pragma unroll
            for (int i = 0; i < 8; ++i)
#pragma unroll
                for (int j = 0; j < 8; ++j) acc[i][j] += a[i] * b[j];
        }
        __syncthreads();
    }
#pragma unroll
    for (int i = 0; i < 8; ++i) {
        size_t base = (size_t)(br + ty * 8 + i) * Ncols + bc + tx * 8;
        float4 v0, v1;
        v0.x = acc[i][0]; v0.y = acc[i][1]; v0.z = acc[i][2]; v0.w = acc[i][3];
        v1.x = acc[i][4]; v1.y = acc[i][5]; v1.z = acc[i][6]; v1.w = acc[i][7];
        if (BIAS) {
            const float* bp = bias + bc + tx * 8;
            v0.x += bp[0]; v0.y += bp[1]; v0.z += bp[2]; v0.w += bp[3];
            v1.x += bp[4]; v1.y += bp[5]; v1.z += bp[6]; v1.w += bp[7];
        }
        *(float4*)(Cb + base) = v0;
        *(float4*)(Cb + base + 4) = v1;
    }
}

// NN: C[m,n] (+)= alpha*sum_k A[m*K+k]*Bm[k*Ncols+n]
// SUBPREV: v = alpha*acc - prev[idx];  ACC: v += C[idx];  FINAL: v = relu(v + bias[n])
template <bool ACC, bool FINAL, bool SUBPREV>
__global__ __launch_bounds__(256) void gemm_nn128_k(const float* __restrict__ A,
                                                    const float* __restrict__ Bm,
                                                    const float* __restrict__ bias,
                                                    const float* __restrict__ prev,
                                                    float* __restrict__ C, float alpha,
                                                    int Ncols, int K,
                                                    long long sA, long long sB,
                                                    long long sPrev, long long sC) {
    __shared__ float As[16][132];
    __shared__ float Bs[16][128];
    const float* Ab = A + (size_t)blockIdx.z * sA;
    const float* Bbp = Bm + (size_t)blockIdx.z * sB;
    const float* Pb = SUBPREV ? prev + (size_t)blockIdx.z * sPrev : nullptr;
    float* Cb = C + (size_t)blockIdx.z * sC;
    int br = blockIdx.y * 128, bc = blockIdx.x * 128;
    int tid = threadIdx.x;
    int tx = tid & 15, ty = tid >> 4;
    float acc[8][8] = {};
    for (int k0 = 0; k0 < K; k0 += 16) {
#pragma unroll
        for (int h = 0; h < 2; ++h) {
            int f = h * 256 + tid;
            int r = f >> 2, kq = (f & 3) << 2;
            float4 av = *(const float4*)(Ab + (size_t)(br + r) * K + k0 + kq);
            As[kq][r] = av.x; As[kq + 1][r] = av.y; As[kq + 2][r] = av.z; As[kq + 3][r] = av.w;
            int rb = f >> 5, cb = (f & 31) << 2;
            float4 bv = *(const float4*)(Bbp + (size_t)(k0 + rb) * Ncols + bc + cb);
            *(float4*)&Bs[rb][cb] = bv;
        }
        __syncthreads();
#pragma unroll
        for (int kk = 0; kk < 16; ++kk) {
            float4 a0 = *(const float4*)&As[kk][ty * 8];
            float4 a1 = *(const float4*)&As[kk][ty * 8 + 4];
            float4 b0 = *(const float4*)&Bs[kk][tx * 8];
            float4 b1 = *(const float4*)&Bs[kk][tx * 8 + 4];
            float a[8] = {a0.x, a0.y, a0.z, a0.w, a1.x, a1.y, a1.z, a1.w};
            float b[8] = {b0.x, b0.y, b0.z, b0.w, b1.x, b1.y, b1.z, b1.w};
#pragma unroll
            for (int i = 0; i < 8; ++i)
#pragma unroll
                for (int j = 0; j < 8; ++j) acc[i][j] += a[i] * b[j];
        }
        __syncthreads();
    }
#pragma unroll
    for (int i = 0; i < 8; ++i) {
        size_t base = (size_t)(br + ty * 8 + i) * Ncols + bc + tx * 8;
        float v[8];
#pragma unroll
        for (int j = 0; j < 8; ++j) v[j] = alpha * acc[i][j];
        if (SUBPREV) {
            float4 p0 = *(const float4*)(Pb + base);
            float4 p1 = *(const float4*)(Pb + base + 4);
            v[0] -= p0.x; v[1] -= p0.y; v[2] -= p0.z; v[3] -= p0.w;
            v[4] -= p1.x; v[5] -= p1.y; v[6] -= p1.z; v[7] -= p1.w;
        }
        if (ACC) {
            float4 c0 = *(const float4*)(Cb + base);
            float4 c1 = *(const float4*)(Cb + base + 4);
            v[0] += c0.x; v[1] += c0.y; v[2] += c0.z; v[3] += c0.w;
            v[4] += c1.x; v[5] += c1.y; v[6] += c1.z; v[7] += c1.w;
        }
        if (FINAL) {
            const float* bp = bias + bc + tx * 8;
#pragma unroll
            for (int j = 0; j < 8; ++j) v[j] = fmaxf(v[j] + bp[j], 0.f);
        }
        float4 o0, o1;
        o0.x = v[0]; o0.y = v[1]; o0.z = v[2]; o0.w = v[3];
        o1.x = v[4]; o1.y = v[5]; o1.z = v[6]; o1.w = v[7];
        *(float4*)(Cb + base) = o0;
        *(float4*)(Cb + base + 4) = o1;
    }
}

// ---------------- top-k threshold + adjacency + degree ----------------
__global__ __launch_bounds__(256) void topk_k(float* __restrict__ sc,
                                              const float* __restrict__ dis,
                                              float* __restrict__ dinv) {
    int row = blockIdx.x;       // b*256 + n
    int n = row & 255;
    int tid = threadIdx.x;
    float* srow = sc + (size_t)row * Nn;
    __shared__ float sh[256];
    float myv = srow[tid];
    sh[tid] = myv;
    __syncthreads();
    for (int k = 2; k <= 256; k <<= 1) {
        for (int j = k >> 1; j > 0; j >>= 1) {
            int ixj = tid ^ j;
            if (ixj > tid) {
                float a = sh[tid], b = sh[ixj];
                bool up = ((tid & k) == 0);
                if ((a > b) == up) { sh[tid] = b; sh[ixj] = a; }
            }
            __syncthreads();
        }
    }
    float kth = sh[256 - NMAXS];   // 51st largest
    __syncthreads();
    float as = (myv >= kth) ? myv : 0.f;
    float a = fmaxf(as + dis[(size_t)n * Nn + tid], 0.f);
    srow[tid] = a;
    sh[tid] = a;
    __syncthreads();
    for (int o = 128; o > 0; o >>= 1) {
        if (tid < o) sh[tid] += sh[tid + o];
        __syncthreads();
    }
    if (tid == 0) dinv[row] = rsqrtf(sh[0] + EPSD);
}

__global__ __launch_bounds__(256) void lscale_k(float* __restrict__ L,
                                                const float* __restrict__ dinv) {
    int i = blockIdx.x * 256 + threadIdx.x;   // over B*N*N
    int m = i & 255;
    int bn = i >> 8;
    int b = bn >> 8;
    L[i] = L[i] * dinv[bn] * dinv[(b << 8) + m];
}

extern "C" void kernel_launch(void* const* d_in, const int* in_sizes, int n_in,
                              void* d_out, int out_size, void* d_ws, size_t ws_size,
                              hipStream_t stream) {
    const float* x      = (const float*)d_in[0];
    const float* dis    = (const float*)d_in[1];
    const float* ln_w   = (const float*)d_in[2];
    const float* ln_b   = (const float*)d_in[3];
    const float* bn_g   = (const float*)d_in[4];
    const float* bn_b   = (const float*)d_in[5];
    const float* li_w   = (const float*)d_in[6];
    const float* li_b   = (const float*)d_in[7];
    const float* cheb_w = (const float*)d_in[8];
    const float* cheb_b = (const float*)d_in[9];
    float* out = (float*)d_out;

    const size_t BNT = (size_t)Bb * Nn * Td;   // 8388608
    const size_t BNN = (size_t)Bb * Nn * Nn;   // 4194304
    float* ws   = (float*)d_ws;
    float* x_ln = ws;              // BNT   (later: x_bn/Tx0, then Tx2 in place)
    float* xp   = x_ln + BNT;      // BNT   (later: Tx1; head doubles as partials scratch)
    float* sc   = xp + BNT;        // BNN   (scores -> A -> L in place)
    float* lnst = sc + BNN;        // 2*B
    float* dinv = lnst + 2 * Bb;   // B*N
    float* bnsc = dinv + Bb * Nn;  // N
    float* bnsh = bnsc + Nn;       // N
    float2* part = (float2*)xp;    // 2048 float2 scratch, free at LN and BN time

    // 1. LayerNorm
    hipLaunchKernelGGL(ln_partial_k, dim3(32, Bb), dim3(256), 0, stream, (const float4*)x, part);
    hipLaunchKernelGGL(ln_final_k, dim3(Bb), dim3(64), 0, stream, part, lnst);
    hipLaunchKernelGGL(ln_apply_k, dim3(BNT / 1024), dim3(256), 0, stream,
                       (const float4*)x, (const float4*)ln_w, (const float4*)ln_b, lnst, (float4*)x_ln);
    // 2. xp = x_ln @ li_w^T + li_b
    hipLaunchKernelGGL((gemm_nt128_k<true>), dim3(Td / 128, Bb * Nn / 128, 1), dim3(256), 0, stream,
                       x_ln, li_w, li_b, xp, Td, Td, 0LL, 0LL, 0LL);
    // 3. scores[b] = xp[b] @ xp[b]^T
    hipLaunchKernelGGL((gemm_nt128_k<false>), dim3(Nn / 128, Nn / 128, Bb), dim3(256), 0, stream,
                       xp, xp, (const float*)nullptr, sc, Nn, Td,
                       (long long)Nn * Td, (long long)Nn * Td, (long long)Nn * Nn);
    // 4. top-k threshold, +dis_adj, relu, degree
    hipLaunchKernelGGL(topk_k, dim3(Bb * Nn), dim3(256), 0, stream, sc, dis, dinv);
    // 5. L = D^-1/2 A D^-1/2 (in place)
    hipLaunchKernelGGL(lscale_k, dim3(BNN / 256), dim3(256), 0, stream, sc, dinv);
    // 6. BatchNorm (stats from x_ln, then in-place -> x_bn = Tx0); xp is free scratch here
    hipLaunchKernelGGL(bn_partial_k, dim3(8, Nn), dim3(256), 0, stream, (const float4*)x_ln, part);
    hipLaunchKernelGGL(bn_final_k, dim3(Nn), dim3(64), 0, stream, part, bn_g, bn_b, bnsc, bnsh);
    hipLaunchKernelGGL(bn_apply_k, dim3(BNT / 1024), dim3(256), 0, stream, (float4*)x_ln, bnsc, bnsh);
    // 7. out = Tx0 @ W0
    hipLaunchKernelGGL((gemm_nn128_k<false, false, false>), dim3(Td / 128, Bb * Nn / 128, 1), dim3(256), 0, stream,
                       x_ln, cheb_w, (const float*)nullptr, (const float*)nullptr, out, 1.0f, Td, Td,
                       0LL, 0LL, 0LL, 0LL);
    // 8. Tx1 = L @ Tx0  -> xp buffer
    hipLaunchKernelGGL((gemm_nn128_k<false, false, false>), dim3(Td / 128, Nn / 128, Bb), dim3(256), 0, stream,
                       sc, x_ln, (const float*)nullptr, (const float*)nullptr, xp, 1.0f, Td, Nn,
                       (long long)Nn * Nn, (long long)Nn * Td, 0LL, (long long)Nn * Td);
    // 9. out += Tx1 @ W1
    hipLaunchKernelGGL((gemm_nn128_k<true, false, false>), dim3(Td / 128, Bb * Nn / 128, 1), dim3(256), 0, stream,
                       xp, cheb_w + (size_t)Td * Td, (const float*)nullptr, (const float*)nullptr, out, 1.0f, Td, Td,
                       0LL, 0LL, 0LL, 0LL);
    // 10. Tx2 = 2 L @ Tx1 - Tx0  -> x_ln buffer (in place over Tx0)
    hipLaunchKernelGGL((gemm_nn128_k<false, false, true>), dim3(Td / 128, Nn / 128, Bb), dim3(256), 0, stream,
                       sc, xp, (const float*)nullptr, x_ln, x_ln, 2.0f, Td, Nn,
                       (long long)Nn * Nn, (long long)Nn * Td, (long long)Nn * Td, (long long)Nn * Td);
    // 11. out = relu(out + Tx2 @ W2 + cheb_b)
    hipLaunchKernelGGL((gemm_nn128_k<true, true, false>), dim3(Td / 128, Bb * Nn / 128, 1), dim3(256), 0, stream,
                       x_ln, cheb_w + (size_t)2 * Td * Td, cheb_b, (const float*)nullptr, out, 1.0f, Td, Td,
                       0LL, 0LL, 0LL, 0LL);
}

// Round 3
// 495.552 us; speedup vs baseline: 2.3411x; 1.6186x over previous
//
#include <hip/hip_runtime.h>
#include <cstddef>

static constexpr int Bb = 64;     // batch
static constexpr int Nn = 256;    // nodes
static constexpr int Td = 512;    // time dim
static constexpr int NMAXS = 51;  // 256 // 5
static constexpr float EPSN = 1e-5f;
static constexpr float EPSD = 1e-10f;

typedef unsigned short u16;
typedef __attribute__((ext_vector_type(8))) short short8;
typedef __attribute__((ext_vector_type(4))) float f32x4;

__device__ __forceinline__ u16 f2b(float f) {
    unsigned u = __float_as_uint(f);
    return (u16)((u + 0x7fffu + ((u >> 16) & 1u)) >> 16);
}

// ---------------- LayerNorm stats: two-stage ----------------
__global__ __launch_bounds__(256) void ln_partial_k(const float4* __restrict__ x,
                                                    float2* __restrict__ part) {
    int b = blockIdx.y, c = blockIdx.x;
    int base = b * 32768 + c * 1024;
    float s = 0.f, s2 = 0.f;
#pragma unroll
    for (int j = 0; j < 4; ++j) {
        float4 v = x[base + j * 256 + threadIdx.x];
        s += v.x + v.y + v.z + v.w;
        s2 += v.x * v.x + v.y * v.y + v.z * v.z + v.w * v.w;
    }
    __shared__ float sh[256], sh2[256];
    sh[threadIdx.x] = s; sh2[threadIdx.x] = s2;
    __syncthreads();
    for (int o = 128; o > 0; o >>= 1) {
        if (threadIdx.x < o) { sh[threadIdx.x] += sh[threadIdx.x + o]; sh2[threadIdx.x] += sh2[threadIdx.x + o]; }
        __syncthreads();
    }
    if (threadIdx.x == 0) part[b * 32 + c] = make_float2(sh[0], sh2[0]);
}

__global__ __launch_bounds__(64) void ln_final_k(const float2* __restrict__ part,
                                                 float* __restrict__ st) {
    int b = blockIdx.x, t = threadIdx.x;
    float s = 0.f, s2 = 0.f;
    if (t < 32) { float2 p = part[b * 32 + t]; s = p.x; s2 = p.y; }
    for (int o = 32; o > 0; o >>= 1) { s += __shfl_down(s, o, 64); s2 += __shfl_down(s2, o, 64); }
    if (t == 0) {
        float inv = 1.f / (Nn * Td);
        float mu = s * inv;
        float var = s2 * inv - mu * mu;
        st[b * 2] = mu;
        st[b * 2 + 1] = rsqrtf(var + EPSN);
    }
}

__global__ __launch_bounds__(256) void ln_apply_k(const float4* __restrict__ x,
                                                  const float4* __restrict__ w,
                                                  const float4* __restrict__ bia,
                                                  const float* __restrict__ st,
                                                  float4* __restrict__ out) {
    int i = blockIdx.x * 256 + threadIdx.x;
    int r = i & ((Nn * Td / 4) - 1);
    int b = i >> 15;
    float mu = st[b * 2], rs = st[b * 2 + 1];
    float4 xv = x[i], wv = w[r], bv = bia[r];
    float4 o;
    o.x = (xv.x - mu) * rs * wv.x + bv.x;
    o.y = (xv.y - mu) * rs * wv.y + bv.y;
    o.z = (xv.z - mu) * rs * wv.z + bv.z;
    o.w = (xv.w - mu) * rs * wv.w + bv.w;
    out[i] = o;
}

// ---------------- BatchNorm stats: two-stage ----------------
__global__ __launch_bounds__(256) void bn_partial_k(const float4* __restrict__ x,
                                                    float2* __restrict__ part) {
    int n = blockIdx.y, c = blockIdx.x;
    float s = 0.f, s2 = 0.f;
#pragma unroll
    for (int j = 0; j < 4; ++j) {
        int f = j * 256 + threadIdx.x;
        int bl = f >> 7, t4 = f & 127;
        float4 v = x[((size_t)(c * 8 + bl) * Nn + n) * 128 + t4];
        s += v.x + v.y + v.z + v.w;
        s2 += v.x * v.x + v.y * v.y + v.z * v.z + v.w * v.w;
    }
    __shared__ float sh[256], sh2[256];
    sh[threadIdx.x] = s; sh2[threadIdx.x] = s2;
    __syncthreads();
    for (int o = 128; o > 0; o >>= 1) {
        if (threadIdx.x < o) { sh[threadIdx.x] += sh[threadIdx.x + o]; sh2[threadIdx.x] += sh2[threadIdx.x + o]; }
        __syncthreads();
    }
    if (threadIdx.x == 0) part[n * 8 + c] = make_float2(sh[0], sh2[0]);
}

__global__ __launch_bounds__(64) void bn_final_k(const float2* __restrict__ part,
                                                 const float* __restrict__ g,
                                                 const float* __restrict__ be,
                                                 float* __restrict__ bnsc,
                                                 float* __restrict__ bnsh) {
    int n = blockIdx.x, t = threadIdx.x;
    float s = 0.f, s2 = 0.f;
    if (t < 8) { float2 p = part[n * 8 + t]; s = p.x; s2 = p.y; }
    for (int o = 32; o > 0; o >>= 1) { s += __shfl_down(s, o, 64); s2 += __shfl_down(s2, o, 64); }
    if (t == 0) {
        float inv = 1.f / (Bb * Td);
        float mu = s * inv;
        float var = s2 * inv - mu * mu;
        float rs = rsqrtf(var + EPSN);
        float scale = rs * g[n];
        bnsc[n] = scale;
        bnsh[n] = be[n] - mu * scale;
    }
}

// BN apply in-place (fp32) + fused bf16 row-major cast
__global__ __launch_bounds__(256) void bn_apply_cast_k(float4* __restrict__ x,
                                                       const float* __restrict__ sc,
                                                       const float* __restrict__ shf,
                                                       uint2* __restrict__ bx) {
    int i = blockIdx.x * 256 + threadIdx.x;
    int n = (i >> 7) & 255;
    float s = sc[n], h = shf[n];
    float4 v = x[i];
    v.x = v.x * s + h; v.y = v.y * s + h; v.z = v.z * s + h; v.w = v.w * s + h;
    x[i] = v;
    uint2 p;
    p.x = (unsigned)f2b(v.x) | ((unsigned)f2b(v.y) << 16);
    p.y = (unsigned)f2b(v.z) | ((unsigned)f2b(v.w) << 16);
    bx[i] = p;
}

// ---------------- fp32 GEMM NT (score path, unchanged numerics) ----------------
template <bool BIAS>
__global__ __launch_bounds__(256) void gemm_nt128_k(const float* __restrict__ A,
                                                    const float* __restrict__ Bm,
                                                    const float* __restrict__ bias,
                                                    float* __restrict__ C,
                                                    int Ncols, int K,
                                                    long long sA, long long sB, long long sC) {
    __shared__ float As[16][132];
    __shared__ float Bs[16][132];
    const float* Ab = A + (size_t)blockIdx.z * sA;
    const float* Bbp = Bm + (size_t)blockIdx.z * sB;
    float* Cb = C + (size_t)blockIdx.z * sC;
    int br = blockIdx.y * 128, bc = blockIdx.x * 128;
    int tid = threadIdx.x;
    int tx = tid & 15, ty = tid >> 4;
    float acc[8][8] = {};
    for (int k0 = 0; k0 < K; k0 += 16) {
#pragma unroll
        for (int h = 0; h < 2; ++h) {
            int f = h * 256 + tid;
            int r = f >> 2, kq = (f & 3) << 2;
            float4 av = *(const float4*)(Ab + (size_t)(br + r) * K + k0 + kq);
            float4 bv = *(const float4*)(Bbp + (size_t)(bc + r) * K + k0 + kq);
            As[kq][r] = av.x; As[kq + 1][r] = av.y; As[kq + 2][r] = av.z; As[kq + 3][r] = av.w;
            Bs[kq][r] = bv.x; Bs[kq + 1][r] = bv.y; Bs[kq + 2][r] = bv.z; Bs[kq + 3][r] = bv.w;
        }
        __syncthreads();
#pragma unroll
        for (int kk = 0; kk < 16; ++kk) {
            float4 a0 = *(const float4*)&As[kk][ty * 8];
            float4 a1 = *(const float4*)&As[kk][ty * 8 + 4];
            float4 b0 = *(const float4*)&Bs[kk][tx * 8];
            float4 b1 = *(const float4*)&Bs[kk][tx * 8 + 4];
            float a[8] = {a0.x, a0.y, a0.z, a0.w, a1.x, a1.y, a1.z, a1.w};
            float b[8] = {b0.x, b0.y, b0.z, b0.w, b1.x, b1.y, b1.z, b1.w};
#pragma unroll
            for (int i = 0; i < 8; ++i)
#pragma unroll
                for (int j = 0; j < 8; ++j) acc[i][j] += a[i] * b[j];
        }
        __syncthreads();
    }
#pragma unroll
    for (int i = 0; i < 8; ++i) {
        size_t base = (size_t)(br + ty * 8 + i) * Ncols + bc + tx * 8;
        float4 v0, v1;
        v0.x = acc[i][0]; v0.y = acc[i][1]; v0.z = acc[i][2]; v0.w = acc[i][3];
        v1.x = acc[i][4]; v1.y = acc[i][5]; v1.z = acc[i][6]; v1.w = acc[i][7];
        if (BIAS) {
            const float* bp = bias + bc + tx * 8;
            v0.x += bp[0]; v0.y += bp[1]; v0.z += bp[2]; v0.w += bp[3];
            v1.x += bp[4]; v1.y += bp[5]; v1.z += bp[6]; v1.w += bp[7];
        }
        *(float4*)(Cb + base) = v0;
        *(float4*)(Cb + base + 4) = v1;
    }
}

// ---------------- top-k threshold + adjacency + degree ----------------
__global__ __launch_bounds__(256) void topk_k(float* __restrict__ sc,
                                              const float* __restrict__ dis,
                                              float* __restrict__ dinv) {
    int row = blockIdx.x;
    int n = row & 255;
    int tid = threadIdx.x;
    float* srow = sc + (size_t)row * Nn;
    __shared__ float sh[256];
    float myv = srow[tid];
    sh[tid] = myv;
    __syncthreads();
    for (int k = 2; k <= 256; k <<= 1) {
        for (int j = k >> 1; j > 0; j >>= 1) {
            int ixj = tid ^ j;
            if (ixj > tid) {
                float a = sh[tid], b = sh[ixj];
                bool up = ((tid & k) == 0);
                if ((a > b) == up) { sh[tid] = b; sh[ixj] = a; }
            }
            __syncthreads();
        }
    }
    float kth = sh[256 - NMAXS];
    __syncthreads();
    float as = (myv >= kth) ? myv : 0.f;
    float a = fmaxf(as + dis[(size_t)n * Nn + tid], 0.f);
    srow[tid] = a;
    sh[tid] = a;
    __syncthreads();
    for (int o = 128; o > 0; o >>= 1) {
        if (tid < o) sh[tid] += sh[tid + o];
        __syncthreads();
    }
    if (tid == 0) dinv[row] = rsqrtf(sh[0] + EPSD);
}

// L = D^-1/2 A D^-1/2, cast to bf16 (fp32 L never materialized)
__global__ __launch_bounds__(256) void lscale_cast_k(const float4* __restrict__ Af,
                                                     const float* __restrict__ dinv,
                                                     uint2* __restrict__ bL) {
    int i = blockIdx.x * 256 + threadIdx.x;   // over B*N*N/4
    int bn = i >> 6;                          // row index b*256+n (N/4=64 vecs/row)
    int b = bn >> 8;
    int m0 = (i & 63) << 2;
    float dn = dinv[bn];
    const float* dm = dinv + (b << 8) + m0;
    float4 v = Af[i];
    uint2 p;
    p.x = (unsigned)f2b(v.x * dn * dm[0]) | ((unsigned)f2b(v.y * dn * dm[1]) << 16);
    p.y = (unsigned)f2b(v.z * dn * dm[2]) | ((unsigned)f2b(v.w * dn * dm[3]) << 16);
    bL[i] = p;
}

// ---------------- transpose + cast: [batch][R][C] (SRC) -> [batch][C][R] (bf16) ----------------
template <typename SRC>
__global__ __launch_bounds__(256) void tcast_k(const SRC* __restrict__ in,
                                               u16* __restrict__ out, int R, int C) {
    __shared__ u16 tile[32][33];
    int b = blockIdx.z;
    int c0 = blockIdx.x * 32, r0 = blockIdx.y * 32;
    int tx = threadIdx.x & 31, ty = threadIdx.x >> 5;
    const SRC* ip = in + ((size_t)b * R + r0) * C + c0;
#pragma unroll
    for (int i = 0; i < 4; ++i) {
        int r = ty + i * 8;
        SRC v = ip[(size_t)r * C + tx];
        if constexpr (sizeof(SRC) == 4) tile[r][tx] = f2b((float)v);
        else tile[r][tx] = (u16)v;
    }
    __syncthreads();
    u16* op = out + ((size_t)b * C + c0) * R + r0;
#pragma unroll
    for (int i = 0; i < 4; ++i) {
        int c = ty + i * 8;
        op[(size_t)c * R + tx] = tile[tx][c];
    }
}

// ---------------- bf16 MFMA GEMM: C = alpha*A·B (+mods) ----------------
// A: [M][K] bf16 row-major;  Bt: [N][K] bf16 row-major (i.e. B transposed)
// SUBPREV: v = alpha*acc - prev;  ACC: v += C;  FINAL: v = relu(v + bias[col])
// WF32: write fp32 C;  WBF: write bf16 Cb
template <bool ACC, bool FINAL, bool SUBPREV, bool WF32, bool WBF>
__global__ __launch_bounds__(256) void gemm_bf_k(const u16* __restrict__ A,
                                                 const u16* __restrict__ Bt,
                                                 const float* __restrict__ bias,
                                                 const float* __restrict__ prev,
                                                 float* __restrict__ C,
                                                 u16* __restrict__ Cb,
                                                 float alpha, int Ncols, int K,
                                                 long long sA, long long sB,
                                                 long long sPrev, long long sC) {
    __shared__ u16 As[128 * 32];
    __shared__ u16 Bs[128 * 32];
    int z = blockIdx.z;
    const u16* Ag = A + (size_t)z * sA;
    const u16* Bg = Bt + (size_t)z * sB;
    int br = blockIdx.y * 128, bc = blockIdx.x * 128;
    int tid = threadIdx.x, lane = tid & 63, wave = tid >> 6;
    int wr = (wave >> 1) * 64, wc = (wave & 1) * 64;
    // staging: row sr = tid>>1; chunks c0=(tid&1), c1=(tid&1)+2 (8 bf16 each); XOR-swizzle by sr&3
    int sr = tid >> 1;
    int c0 = tid & 1, c1 = (tid & 1) + 2;
    int swz = sr & 3;
    int w0 = sr * 32 + (c0 ^ swz) * 8;
    int w1 = sr * 32 + (c1 ^ swz) * 8;
    const u16* Agp = Ag + (size_t)(br + sr) * K;
    const u16* Bgp = Bg + (size_t)(bc + sr) * K;
    f32x4 acc[4][4] = {};
    int fr = lane & 15, fq = lane >> 4;
    for (int k0 = 0; k0 < K; k0 += 32) {
        int4 a0 = *(const int4*)(Agp + k0 + c0 * 8);
        int4 a1 = *(const int4*)(Agp + k0 + c1 * 8);
        int4 b0 = *(const int4*)(Bgp + k0 + c0 * 8);
        int4 b1 = *(const int4*)(Bgp + k0 + c1 * 8);
        *(int4*)&As[w0] = a0;
        *(int4*)&As[w1] = a1;
        *(int4*)&Bs[w0] = b0;
        *(int4*)&Bs[w1] = b1;
        __syncthreads();
        short8 af[4], bf[4];
#pragma unroll
        for (int mi = 0; mi < 4; ++mi) {
            int rr = wr + mi * 16 + fr;
            af[mi] = *(const short8*)&As[rr * 32 + ((fq ^ (rr & 3)) << 3)];
        }
#pragma unroll
        for (int ni = 0; ni < 4; ++ni) {
            int rr = wc + ni * 16 + fr;
            bf[ni] = *(const short8*)&Bs[rr * 32 + ((fq ^ (rr & 3)) << 3)];
        }
#pragma unroll
        for (int mi = 0; mi < 4; ++mi)
#pragma unroll
            for (int ni = 0; ni < 4; ++ni)
                acc[mi][ni] = __builtin_amdgcn_mfma_f32_16x16x32_bf16(af[mi], bf[ni], acc[mi][ni], 0, 0, 0);
        __syncthreads();
    }
    const float* Pp = SUBPREV ? prev + (size_t)z * sPrev : nullptr;
    float* Cp = C + (size_t)z * sC;
    u16* Cbp = WBF ? Cb + (size_t)z * sC : nullptr;
#pragma unroll
    for (int mi = 0; mi < 4; ++mi) {
#pragma unroll
        for (int rg = 0; rg < 4; ++rg) {
            int row = br + wr + mi * 16 + fq * 4 + rg;
            size_t rb = (size_t)row * Ncols;
#pragma unroll
            for (int ni = 0; ni < 4; ++ni) {
                int col = bc + wc + ni * 16 + fr;
                float v = alpha * acc[mi][ni][rg];
                if (SUBPREV) v -= Pp[rb + col];
                if (ACC) v += Cp[rb + col];
                if (FINAL) v = fmaxf(v + bias[col], 0.f);
                if (WF32) Cp[rb + col] = v;
                if (WBF) Cbp[rb + col] = f2b(v);
            }
        }
    }
}

extern "C" void kernel_launch(void* const* d_in, const int* in_sizes, int n_in,
                              void* d_out, int out_size, void* d_ws, size_t ws_size,
                              hipStream_t stream) {
    const float* x      = (const float*)d_in[0];
    const float* dis    = (const float*)d_in[1];
    const float* ln_w   = (const float*)d_in[2];
    const float* ln_b   = (const float*)d_in[3];
    const float* bn_g   = (const float*)d_in[4];
    const float* bn_b   = (const float*)d_in[5];
    const float* li_w   = (const float*)d_in[6];
    const float* li_b   = (const float*)d_in[7];
    const float* cheb_w = (const float*)d_in[8];
    const float* cheb_b = (const float*)d_in[9];
    float* out = (float*)d_out;

    const size_t BNT = (size_t)Bb * Nn * Td;   // 8388608
    const size_t BNN = (size_t)Bb * Nn * Nn;   // 4194304
    float* ws   = (float*)d_ws;
    float* x_ln = ws;                    // BNT fp32: x_ln -> x_bn (kept through step 10)
    float* xp   = x_ln + BNT;            // BNT fp32: xp (steps 2-3); then bufA+bufB bf16
    float* sc   = xp + BNT;              // BNN fp32: scores -> A
    float* smal = sc + BNN;
    float* lnst = smal;                  // 128
    float* dinv = smal + 128;            // B*N = 16384
    float* bnsc = dinv + 16384;          // 256
    float* bnsh = bnsc + 256;            // 256
    float2* part = (float2*)(bnsh + 256);// 2048 float2 = 4096 floats
    float* bigp = bnsh + 256 + 4096;
    u16* bL   = (u16*)bigp;              // BNN bf16 (8.4 MB)
    u16* bW   = bL + BNN;                // 3*T*T bf16 (1.5 MB)
    u16* bTx2 = bW + (size_t)3 * Td * Td;// BNT bf16 (16.7 MB)
    u16* bufA = (u16*)xp;                // BNT bf16: bx_bn, then bTx1
    u16* bufB = bufA + BNT;              // BNT bf16: bx_bn^T, then bTx1^T

    // 1. LayerNorm
    hipLaunchKernelGGL(ln_partial_k, dim3(32, Bb), dim3(256), 0, stream, (const float4*)x, part);
    hipLaunchKernelGGL(ln_final_k, dim3(Bb), dim3(64), 0, stream, part, lnst);
    hipLaunchKernelGGL(ln_apply_k, dim3(BNT / 1024), dim3(256), 0, stream,
                       (const float4*)x, (const float4*)ln_w, (const float4*)ln_b, lnst, (float4*)x_ln);
    // 2. xp = x_ln @ li_w^T + li_b   (fp32 — feeds top-k, keep exact)
    hipLaunchKernelGGL((gemm_nt128_k<true>), dim3(Td / 128, Bb * Nn / 128, 1), dim3(256), 0, stream,
                       x_ln, li_w, li_b, xp, Td, Td, 0LL, 0LL, 0LL);
    // 3. scores[b] = xp[b] @ xp[b]^T  (fp32)
    hipLaunchKernelGGL((gemm_nt128_k<false>), dim3(Nn / 128, Nn / 128, Bb), dim3(256), 0, stream,
                       xp, xp, (const float*)nullptr, sc, Nn, Td,
                       (long long)Nn * Td, (long long)Nn * Td, (long long)Nn * Nn);
    // 4. top-k threshold, +dis_adj, relu, degree
    hipLaunchKernelGGL(topk_k, dim3(Bb * Nn), dim3(256), 0, stream, sc, dis, dinv);
    // 5. L = D^-1/2 A D^-1/2 -> bf16 bL
    hipLaunchKernelGGL(lscale_cast_k, dim3(BNN / 1024), dim3(256), 0, stream,
                       (const float4*)sc, dinv, (uint2*)bL);
    // 6. BatchNorm: stats, then in-place apply + bf16 cast (bufA = bx_bn)
    hipLaunchKernelGGL(bn_partial_k, dim3(8, Nn), dim3(256), 0, stream, (const float4*)x_ln, part);
    hipLaunchKernelGGL(bn_final_k, dim3(Nn), dim3(64), 0, stream, part, bn_g, bn_b, bnsc, bnsh);
    hipLaunchKernelGGL(bn_apply_cast_k, dim3(BNT / 1024), dim3(256), 0, stream,
                       (float4*)x_ln, bnsc, bnsh, (uint2*)bufA);
    // 6b. transposes: x_bn^T -> bufB; cheb_w^T -> bW
    hipLaunchKernelGGL((tcast_k<float>), dim3(Td / 32, Nn / 32, Bb), dim3(256), 0, stream,
                       x_ln, bufB, Nn, Td);
    hipLaunchKernelGGL((tcast_k<float>), dim3(Td / 32, Td / 32, 3), dim3(256), 0, stream,
                       cheb_w, bW, Td, Td);
    // 7. out = Tx0 @ W0
    hipLaunchKernelGGL((gemm_bf_k<false, false, false, true, false>), dim3(Td / 128, Bb * Nn / 128, 1), dim3(256), 0, stream,
                       bufA, bW, (const float*)nullptr, (const float*)nullptr, out, (u16*)nullptr,
                       1.0f, Td, Td, 0LL, 0LL, 0LL, 0LL);
    // 8. Tx1 = L @ Tx0 -> bf16 only (bufA)
    hipLaunchKernelGGL((gemm_bf_k<false, false, false, false, true>), dim3(Td / 128, Nn / 128, Bb), dim3(256), 0, stream,
                       bL, bufB, (const float*)nullptr, (const float*)nullptr, out, bufA,
                       1.0f, Td, Nn, (long long)Nn * Nn, (long long)Td * Nn, 0LL, (long long)Nn * Td);
    // 9. out += Tx1 @ W1
    hipLaunchKernelGGL((gemm_bf_k<true, false, false, true, false>), dim3(Td / 128, Bb * Nn / 128, 1), dim3(256), 0, stream,
                       bufA, bW + (size_t)Td * Td, (const float*)nullptr, (const float*)nullptr, out, (u16*)nullptr,
                       1.0f, Td, Td, 0LL, 0LL, 0LL, 0LL);
    // 9b. Tx1^T -> bufB (bf16 -> bf16 transpose)
    hipLaunchKernelGGL((tcast_k<u16>), dim3(Td / 32, Nn / 32, Bb), dim3(256), 0, stream,
                       bufA, bufB, Nn, Td);
    // 10. Tx2 = 2 L @ Tx1 - Tx0 -> bf16 only (bTx2)
    hipLaunchKernelGGL((gemm_bf_k<false, false, true, false, true>), dim3(Td / 128, Nn / 128, Bb), dim3(256), 0, stream,
                       bL, bufB, (const float*)nullptr, x_ln, out, bTx2,
                       2.0f, Td, Nn, (long long)Nn * Nn, (long long)Td * Nn, (long long)Nn * Td, (long long)Nn * Td);
    // 11. out = relu(out + Tx2 @ W2 + cheb_b)
    hipLaunchKernelGGL((gemm_bf_k<true, true, false, true, false>), dim3(Td / 128, Bb * Nn / 128, 1), dim3(256), 0, stream,
                       bTx2, bW + (size_t)2 * Td * Td, cheb_b, (const float*)nullptr, out, (u16*)nullptr,
                       1.0f, Td, Td, 0LL, 0LL, 0LL, 0LL);
}

// Round 4
// 403.996 us; speedup vs baseline: 2.8716x; 1.2266x over previous
//
#include <hip/hip_runtime.h>
#include <cstddef>

static constexpr int Bb = 64;     // batch
static constexpr int Nn = 256;    // nodes
static constexpr int Td = 512;    // time dim
static constexpr int NMAXS = 51;  // 256 // 5
static constexpr float EPSN = 1e-5f;
static constexpr float EPSD = 1e-10f;

typedef unsigned short u16;
typedef __attribute__((ext_vector_type(8))) short short8;
typedef __attribute__((ext_vector_type(4))) float f32x4;

__device__ __forceinline__ u16 f2b(float f) {
    unsigned u = __float_as_uint(f);
    return (u16)((u + 0x7fffu + ((u >> 16) & 1u)) >> 16);
}
__device__ __forceinline__ float b2f(u16 h) {
    return __uint_as_float(((unsigned)h) << 16);
}

// ---------------- LayerNorm stats: two-stage ----------------
__global__ __launch_bounds__(256) void ln_partial_k(const float4* __restrict__ x,
                                                    float2* __restrict__ part) {
    int b = blockIdx.y, c = blockIdx.x;
    int base = b * 32768 + c * 1024;
    float s = 0.f, s2 = 0.f;
#pragma unroll
    for (int j = 0; j < 4; ++j) {
        float4 v = x[base + j * 256 + threadIdx.x];
        s += v.x + v.y + v.z + v.w;
        s2 += v.x * v.x + v.y * v.y + v.z * v.z + v.w * v.w;
    }
    __shared__ float sh[256], sh2[256];
    sh[threadIdx.x] = s; sh2[threadIdx.x] = s2;
    __syncthreads();
    for (int o = 128; o > 0; o >>= 1) {
        if (threadIdx.x < o) { sh[threadIdx.x] += sh[threadIdx.x + o]; sh2[threadIdx.x] += sh2[threadIdx.x + o]; }
        __syncthreads();
    }
    if (threadIdx.x == 0) part[b * 32 + c] = make_float2(sh[0], sh2[0]);
}

__global__ __launch_bounds__(64) void ln_final_k(const float2* __restrict__ part,
                                                 float* __restrict__ st) {
    int b = blockIdx.x, t = threadIdx.x;
    float s = 0.f, s2 = 0.f;
    if (t < 32) { float2 p = part[b * 32 + t]; s = p.x; s2 = p.y; }
    for (int o = 32; o > 0; o >>= 1) { s += __shfl_down(s, o, 64); s2 += __shfl_down(s2, o, 64); }
    if (t == 0) {
        float inv = 1.f / (Nn * Td);
        float mu = s * inv;
        float var = s2 * inv - mu * mu;
        st[b * 2] = mu;
        st[b * 2 + 1] = rsqrtf(var + EPSN);
    }
}

// LN apply: write fp32 x_ln AND hi/lo bf16 split (for split-MFMA score path)
__global__ __launch_bounds__(256) void ln_apply_split_k(const float4* __restrict__ x,
                                                        const float4* __restrict__ w,
                                                        const float4* __restrict__ bia,
                                                        const float* __restrict__ st,
                                                        float4* __restrict__ out,
                                                        uint2* __restrict__ xhi,
                                                        uint2* __restrict__ xlo) {
    int i = blockIdx.x * 256 + threadIdx.x;
    int r = i & ((Nn * Td / 4) - 1);
    int b = i >> 15;
    float mu = st[b * 2], rs = st[b * 2 + 1];
    float4 xv = x[i], wv = w[r], bv = bia[r];
    float4 o;
    o.x = (xv.x - mu) * rs * wv.x + bv.x;
    o.y = (xv.y - mu) * rs * wv.y + bv.y;
    o.z = (xv.z - mu) * rs * wv.z + bv.z;
    o.w = (xv.w - mu) * rs * wv.w + bv.w;
    out[i] = o;
    u16 hx = f2b(o.x), hy = f2b(o.y), hz = f2b(o.z), hw = f2b(o.w);
    uint2 ph, pl;
    ph.x = (unsigned)hx | ((unsigned)hy << 16);
    ph.y = (unsigned)hz | ((unsigned)hw << 16);
    pl.x = (unsigned)f2b(o.x - b2f(hx)) | ((unsigned)f2b(o.y - b2f(hy)) << 16);
    pl.y = (unsigned)f2b(o.z - b2f(hz)) | ((unsigned)f2b(o.w - b2f(hw)) << 16);
    xhi[i] = ph;
    xlo[i] = pl;
}

// hi/lo split cast for a small fp32 matrix (li_w)
__global__ __launch_bounds__(256) void cast_split_k(const float4* __restrict__ in,
                                                    uint2* __restrict__ hi,
                                                    uint2* __restrict__ lo, int n4) {
    int i = blockIdx.x * 256 + threadIdx.x;
    if (i >= n4) return;
    float4 v = in[i];
    u16 hx = f2b(v.x), hy = f2b(v.y), hz = f2b(v.z), hw = f2b(v.w);
    uint2 ph, pl;
    ph.x = (unsigned)hx | ((unsigned)hy << 16);
    ph.y = (unsigned)hz | ((unsigned)hw << 16);
    pl.x = (unsigned)f2b(v.x - b2f(hx)) | ((unsigned)f2b(v.y - b2f(hy)) << 16);
    pl.y = (unsigned)f2b(v.z - b2f(hz)) | ((unsigned)f2b(v.w - b2f(hw)) << 16);
    hi[i] = ph;
    lo[i] = pl;
}

// ---------------- BatchNorm stats: two-stage ----------------
__global__ __launch_bounds__(256) void bn_partial_k(const float4* __restrict__ x,
                                                    float2* __restrict__ part) {
    int n = blockIdx.y, c = blockIdx.x;
    float s = 0.f, s2 = 0.f;
#pragma unroll
    for (int j = 0; j < 4; ++j) {
        int f = j * 256 + threadIdx.x;
        int bl = f >> 7, t4 = f & 127;
        float4 v = x[((size_t)(c * 8 + bl) * Nn + n) * 128 + t4];
        s += v.x + v.y + v.z + v.w;
        s2 += v.x * v.x + v.y * v.y + v.z * v.z + v.w * v.w;
    }
    __shared__ float sh[256], sh2[256];
    sh[threadIdx.x] = s; sh2[threadIdx.x] = s2;
    __syncthreads();
    for (int o = 128; o > 0; o >>= 1) {
        if (threadIdx.x < o) { sh[threadIdx.x] += sh[threadIdx.x + o]; sh2[threadIdx.x] += sh2[threadIdx.x + o]; }
        __syncthreads();
    }
    if (threadIdx.x == 0) part[n * 8 + c] = make_float2(sh[0], sh2[0]);
}

__global__ __launch_bounds__(64) void bn_final_k(const float2* __restrict__ part,
                                                 const float* __restrict__ g,
                                                 const float* __restrict__ be,
                                                 float* __restrict__ bnsc,
                                                 float* __restrict__ bnsh) {
    int n = blockIdx.x, t = threadIdx.x;
    float s = 0.f, s2 = 0.f;
    if (t < 8) { float2 p = part[n * 8 + t]; s = p.x; s2 = p.y; }
    for (int o = 32; o > 0; o >>= 1) { s += __shfl_down(s, o, 64); s2 += __shfl_down(s2, o, 64); }
    if (t == 0) {
        float inv = 1.f / (Bb * Td);
        float mu = s * inv;
        float var = s2 * inv - mu * mu;
        float rs = rsqrtf(var + EPSN);
        float scale = rs * g[n];
        bnsc[n] = scale;
        bnsh[n] = be[n] - mu * scale;
    }
}

// BN apply in-place (fp32) + fused bf16 row-major cast
__global__ __launch_bounds__(256) void bn_apply_cast_k(float4* __restrict__ x,
                                                       const float* __restrict__ sc,
                                                       const float* __restrict__ shf,
                                                       uint2* __restrict__ bx) {
    int i = blockIdx.x * 256 + threadIdx.x;
    int n = (i >> 7) & 255;
    float s = sc[n], h = shf[n];
    float4 v = x[i];
    v.x = v.x * s + h; v.y = v.y * s + h; v.z = v.z * s + h; v.w = v.w * s + h;
    x[i] = v;
    uint2 p;
    p.x = (unsigned)f2b(v.x) | ((unsigned)f2b(v.y) << 16);
    p.y = (unsigned)f2b(v.z) | ((unsigned)f2b(v.w) << 16);
    bx[i] = p;
}

// ---------------- top-k threshold + adjacency + degree ----------------
__global__ __launch_bounds__(256) void topk_k(float* __restrict__ sc,
                                              const float* __restrict__ dis,
                                              float* __restrict__ dinv) {
    int row = blockIdx.x;
    int n = row & 255;
    int tid = threadIdx.x;
    float* srow = sc + (size_t)row * Nn;
    __shared__ float sh[256];
    float myv = srow[tid];
    sh[tid] = myv;
    __syncthreads();
    for (int k = 2; k <= 256; k <<= 1) {
        for (int j = k >> 1; j > 0; j >>= 1) {
            int ixj = tid ^ j;
            if (ixj > tid) {
                float a = sh[tid], b = sh[ixj];
                bool up = ((tid & k) == 0);
                if ((a > b) == up) { sh[tid] = b; sh[ixj] = a; }
            }
            __syncthreads();
        }
    }
    float kth = sh[256 - NMAXS];
    __syncthreads();
    float as = (myv >= kth) ? myv : 0.f;
    float a = fmaxf(as + dis[(size_t)n * Nn + tid], 0.f);
    srow[tid] = a;
    sh[tid] = a;
    __syncthreads();
    for (int o = 128; o > 0; o >>= 1) {
        if (tid < o) sh[tid] += sh[tid + o];
        __syncthreads();
    }
    if (tid == 0) dinv[row] = rsqrtf(sh[0] + EPSD);
}

// L = D^-1/2 A D^-1/2, cast to bf16
__global__ __launch_bounds__(256) void lscale_cast_k(const float4* __restrict__ Af,
                                                     const float* __restrict__ dinv,
                                                     uint2* __restrict__ bL) {
    int i = blockIdx.x * 256 + threadIdx.x;
    int bn = i >> 6;
    int b = bn >> 8;
    int m0 = (i & 63) << 2;
    float dn = dinv[bn];
    const float* dm = dinv + (b << 8) + m0;
    float4 v = Af[i];
    uint2 p;
    p.x = (unsigned)f2b(v.x * dn * dm[0]) | ((unsigned)f2b(v.y * dn * dm[1]) << 16);
    p.y = (unsigned)f2b(v.z * dn * dm[2]) | ((unsigned)f2b(v.w * dn * dm[3]) << 16);
    bL[i] = p;
}

// ---------------- transpose + cast: [batch][R][C] (SRC) -> [batch][C][R] (bf16) ----------------
template <typename SRC>
__global__ __launch_bounds__(256) void tcast_k(const SRC* __restrict__ in,
                                               u16* __restrict__ out, int R, int C) {
    __shared__ u16 tile[32][33];
    int b = blockIdx.z;
    int c0 = blockIdx.x * 32, r0 = blockIdx.y * 32;
    int tx = threadIdx.x & 31, ty = threadIdx.x >> 5;
    const SRC* ip = in + ((size_t)b * R + r0) * C + c0;
#pragma unroll
    for (int i = 0; i < 4; ++i) {
        int r = ty + i * 8;
        SRC v = ip[(size_t)r * C + tx];
        if constexpr (sizeof(SRC) == 4) tile[r][tx] = f2b((float)v);
        else tile[r][tx] = (u16)v;
    }
    __syncthreads();
    u16* op = out + ((size_t)b * C + c0) * R + r0;
#pragma unroll
    for (int i = 0; i < 4; ++i) {
        int c = ty + i * 8;
        op[(size_t)c * R + tx] = tile[tx][c];
    }
}

// ---------------- bf16 MFMA GEMM (single precision-level), NT ----------------
template <bool ACC, bool FINAL, bool SUBPREV, bool WF32, bool WBF>
__global__ __launch_bounds__(256) void gemm_bf_k(const u16* __restrict__ A,
                                                 const u16* __restrict__ Bt,
                                                 const float* __restrict__ bias,
                                                 const float* __restrict__ prev,
                                                 float* __restrict__ C,
                                                 u16* __restrict__ Cb,
                                                 float alpha, int Ncols, int K,
                                                 long long sA, long long sB,
                                                 long long sPrev, long long sC) {
    __shared__ u16 As[128 * 32];
    __shared__ u16 Bs[128 * 32];
    int z = blockIdx.z;
    const u16* Ag = A + (size_t)z * sA;
    const u16* Bg = Bt + (size_t)z * sB;
    int br = blockIdx.y * 128, bc = blockIdx.x * 128;
    int tid = threadIdx.x, lane = tid & 63, wave = tid >> 6;
    int wr = (wave >> 1) * 64, wc = (wave & 1) * 64;
    int sr = tid >> 1;
    int c0 = tid & 1, c1 = (tid & 1) + 2;
    int swz = sr & 3;
    int w0 = sr * 32 + (c0 ^ swz) * 8;
    int w1 = sr * 32 + (c1 ^ swz) * 8;
    const u16* Agp = Ag + (size_t)(br + sr) * K;
    const u16* Bgp = Bg + (size_t)(bc + sr) * K;
    f32x4 acc[4][4] = {};
    int fr = lane & 15, fq = lane >> 4;
    for (int k0 = 0; k0 < K; k0 += 32) {
        int4 a0 = *(const int4*)(Agp + k0 + c0 * 8);
        int4 a1 = *(const int4*)(Agp + k0 + c1 * 8);
        int4 b0 = *(const int4*)(Bgp + k0 + c0 * 8);
        int4 b1 = *(const int4*)(Bgp + k0 + c1 * 8);
        *(int4*)&As[w0] = a0;
        *(int4*)&As[w1] = a1;
        *(int4*)&Bs[w0] = b0;
        *(int4*)&Bs[w1] = b1;
        __syncthreads();
        short8 af[4], bf[4];
#pragma unroll
        for (int mi = 0; mi < 4; ++mi) {
            int rr = wr + mi * 16 + fr;
            af[mi] = *(const short8*)&As[rr * 32 + ((fq ^ (rr & 3)) << 3)];
        }
#pragma unroll
        for (int ni = 0; ni < 4; ++ni) {
            int rr = wc + ni * 16 + fr;
            bf[ni] = *(const short8*)&Bs[rr * 32 + ((fq ^ (rr & 3)) << 3)];
        }
#pragma unroll
        for (int mi = 0; mi < 4; ++mi)
#pragma unroll
            for (int ni = 0; ni < 4; ++ni)
                acc[mi][ni] = __builtin_amdgcn_mfma_f32_16x16x32_bf16(af[mi], bf[ni], acc[mi][ni], 0, 0, 0);
        __syncthreads();
    }
    const float* Pp = SUBPREV ? prev + (size_t)z * sPrev : nullptr;
    float* Cp = C + (size_t)z * sC;
    u16* Cbp = WBF ? Cb + (size_t)z * sC : nullptr;
#pragma unroll
    for (int mi = 0; mi < 4; ++mi) {
#pragma unroll
        for (int rg = 0; rg < 4; ++rg) {
            int row = br + wr + mi * 16 + fq * 4 + rg;
            size_t rb = (size_t)row * Ncols;
#pragma unroll
            for (int ni = 0; ni < 4; ++ni) {
                int col = bc + wc + ni * 16 + fr;
                float v = alpha * acc[mi][ni][rg];
                if (SUBPREV) v -= Pp[rb + col];
                if (ACC) v += Cp[rb + col];
                if (FINAL) v = fmaxf(v + bias[col], 0.f);
                if (WF32) Cp[rb + col] = v;
                if (WBF) Cbp[rb + col] = f2b(v);
            }
        }
    }
}

// ---------------- split-bf16 3-MFMA GEMM (fp32-emulating), NT ----------------
// C = (Ahi+Alo)·(Bhi+Blo)^T ≈ Ahi·Bhi + Ahi·Blo + Alo·Bhi   (fp32 accumulate)
// WSPLIT: write hi/lo bf16 split of result; WF32: write fp32.
template <bool BIAS, bool WSPLIT, bool WF32>
__global__ __launch_bounds__(256) void gemm_bf3_k(const u16* __restrict__ Ahi,
                                                  const u16* __restrict__ Alo,
                                                  const u16* __restrict__ Bhi,
                                                  const u16* __restrict__ Blo,
                                                  const float* __restrict__ bias,
                                                  float* __restrict__ C,
                                                  u16* __restrict__ Chi,
                                                  u16* __restrict__ Clo,
                                                  int Ncols, int K,
                                                  long long sA, long long sB, long long sC) {
    __shared__ u16 Ash[128 * 32];
    __shared__ u16 Asl[128 * 32];
    __shared__ u16 Bsh[128 * 32];
    __shared__ u16 Bsl[128 * 32];
    int z = blockIdx.z;
    const u16* Agh = Ahi + (size_t)z * sA;
    const u16* Agl = Alo + (size_t)z * sA;
    const u16* Bgh = Bhi + (size_t)z * sB;
    const u16* Bgl = Blo + (size_t)z * sB;
    int br = blockIdx.y * 128, bc = blockIdx.x * 128;
    int tid = threadIdx.x, lane = tid & 63, wave = tid >> 6;
    int wr = (wave >> 1) * 64, wc = (wave & 1) * 64;
    int sr = tid >> 1;
    int c0 = tid & 1, c1 = (tid & 1) + 2;
    int swz = sr & 3;
    int w0 = sr * 32 + (c0 ^ swz) * 8;
    int w1 = sr * 32 + (c1 ^ swz) * 8;
    size_t rowA = (size_t)(br + sr) * K;
    size_t rowB = (size_t)(bc + sr) * K;
    f32x4 acc[4][4] = {};
    int fr = lane & 15, fq = lane >> 4;
    for (int k0 = 0; k0 < K; k0 += 32) {
        int4 ah0 = *(const int4*)(Agh + rowA + k0 + c0 * 8);
        int4 ah1 = *(const int4*)(Agh + rowA + k0 + c1 * 8);
        int4 al0 = *(const int4*)(Agl + rowA + k0 + c0 * 8);
        int4 al1 = *(const int4*)(Agl + rowA + k0 + c1 * 8);
        int4 bh0 = *(const int4*)(Bgh + rowB + k0 + c0 * 8);
        int4 bh1 = *(const int4*)(Bgh + rowB + k0 + c1 * 8);
        int4 bl0 = *(const int4*)(Bgl + rowB + k0 + c0 * 8);
        int4 bl1 = *(const int4*)(Bgl + rowB + k0 + c1 * 8);
        *(int4*)&Ash[w0] = ah0; *(int4*)&Ash[w1] = ah1;
        *(int4*)&Asl[w0] = al0; *(int4*)&Asl[w1] = al1;
        *(int4*)&Bsh[w0] = bh0; *(int4*)&Bsh[w1] = bh1;
        *(int4*)&Bsl[w0] = bl0; *(int4*)&Bsl[w1] = bl1;
        __syncthreads();
        short8 afh[4], afl[4], bfh[4], bfl[4];
#pragma unroll
        for (int mi = 0; mi < 4; ++mi) {
            int rr = wr + mi * 16 + fr;
            int off = rr * 32 + ((fq ^ (rr & 3)) << 3);
            afh[mi] = *(const short8*)&Ash[off];
            afl[mi] = *(const short8*)&Asl[off];
        }
#pragma unroll
        for (int ni = 0; ni < 4; ++ni) {
            int rr = wc + ni * 16 + fr;
            int off = rr * 32 + ((fq ^ (rr & 3)) << 3);
            bfh[ni] = *(const short8*)&Bsh[off];
            bfl[ni] = *(const short8*)&Bsl[off];
        }
#pragma unroll
        for (int mi = 0; mi < 4; ++mi)
#pragma unroll
            for (int ni = 0; ni < 4; ++ni) {
                acc[mi][ni] = __builtin_amdgcn_mfma_f32_16x16x32_bf16(afh[mi], bfh[ni], acc[mi][ni], 0, 0, 0);
                acc[mi][ni] = __builtin_amdgcn_mfma_f32_16x16x32_bf16(afh[mi], bfl[ni], acc[mi][ni], 0, 0, 0);
                acc[mi][ni] = __builtin_amdgcn_mfma_f32_16x16x32_bf16(afl[mi], bfh[ni], acc[mi][ni], 0, 0, 0);
            }
        __syncthreads();
    }
    float* Cp = WF32 ? C + (size_t)z * sC : nullptr;
    u16* Chp = WSPLIT ? Chi + (size_t)z * sC : nullptr;
    u16* Clp = WSPLIT ? Clo + (size_t)z * sC : nullptr;
#pragma unroll
    for (int mi = 0; mi < 4; ++mi) {
#pragma unroll
        for (int rg = 0; rg < 4; ++rg) {
            int row = br + wr + mi * 16 + fq * 4 + rg;
            size_t rb = (size_t)row * Ncols;
#pragma unroll
            for (int ni = 0; ni < 4; ++ni) {
                int col = bc + wc + ni * 16 + fr;
                float v = acc[mi][ni][rg];
                if (BIAS) v += bias[col];
                if (WF32) Cp[rb + col] = v;
                if (WSPLIT) {
                    u16 h = f2b(v);
                    Chp[rb + col] = h;
                    Clp[rb + col] = f2b(v - b2f(h));
                }
            }
        }
    }
}

extern "C" void kernel_launch(void* const* d_in, const int* in_sizes, int n_in,
                              void* d_out, int out_size, void* d_ws, size_t ws_size,
                              hipStream_t stream) {
    const float* x      = (const float*)d_in[0];
    const float* dis    = (const float*)d_in[1];
    const float* ln_w   = (const float*)d_in[2];
    const float* ln_b   = (const float*)d_in[3];
    const float* bn_g   = (const float*)d_in[4];
    const float* bn_b   = (const float*)d_in[5];
    const float* li_w   = (const float*)d_in[6];
    const float* li_b   = (const float*)d_in[7];
    const float* cheb_w = (const float*)d_in[8];
    const float* cheb_b = (const float*)d_in[9];
    float* out = (float*)d_out;

    const size_t BNT = (size_t)Bb * Nn * Td;   // 8388608
    const size_t BNN = (size_t)Bb * Nn * Nn;   // 4194304
    float* ws   = (float*)d_ws;
    // region 1: fp32 x_ln (persist through step 10)
    float* x_ln = ws;                           // BNT fp32
    // region 2: [BNT, 2BNT) floats — xhi/xlo (steps 1-2), then bufA/bufB (bf16, step 6+)
    u16* xhi  = (u16*)(x_ln + BNT);             // BNT u16
    u16* xlo  = xhi + BNT;                      // BNT u16
    u16* bufA = xhi;                            // reuse after step 3
    u16* bufB = xlo;
    // region 3: [2BNT, 3BNT) floats — xphi/xplo (steps 2-3), then bW + bTx2 (step 6b+)
    u16* xphi = (u16*)(x_ln + 2 * BNT);         // BNT u16
    u16* xplo = xphi + BNT;                     // BNT u16
    u16* bW   = xphi;                           // 3*T*T u16, reuse after step 3
    u16* bTx2 = bW + (size_t)3 * Td * Td;       // BNT u16
    // region 4: scores fp32
    float* sc = x_ln + 3 * BNT;                 // BNN fp32
    // small + bL + li_w splits
    float* smal = sc + BNN;
    float* lnst = smal;                         // 128
    float* dinv = smal + 128;                   // 16384
    float* bnsc = dinv + 16384;                 // 256
    float* bnsh = bnsc + 256;                   // 256
    float2* part = (float2*)(bnsh + 256);       // 4096 floats
    float* bigp = bnsh + 256 + 4096;
    u16* bL    = (u16*)bigp;                    // BNN u16
    u16* liwhi = bL + BNN;                      // T*T u16
    u16* liwlo = liwhi + (size_t)Td * Td;       // T*T u16

    // 1. LayerNorm (+ hi/lo split of x_ln)
    hipLaunchKernelGGL(ln_partial_k, dim3(32, Bb), dim3(256), 0, stream, (const float4*)x, part);
    hipLaunchKernelGGL(ln_final_k, dim3(Bb), dim3(64), 0, stream, part, lnst);
    hipLaunchKernelGGL(ln_apply_split_k, dim3(BNT / 1024), dim3(256), 0, stream,
                       (const float4*)x, (const float4*)ln_w, (const float4*)ln_b, lnst,
                       (float4*)x_ln, (uint2*)xhi, (uint2*)xlo);
    // 1b. li_w hi/lo split
    hipLaunchKernelGGL(cast_split_k, dim3((Td * Td / 4 + 255) / 256), dim3(256), 0, stream,
                       (const float4*)li_w, (uint2*)liwhi, (uint2*)liwlo, Td * Td / 4);
    // 2. xp = x_ln @ li_w^T + li_b  (split-bf16 3-MFMA; outputs hi/lo split)
    hipLaunchKernelGGL((gemm_bf3_k<true, true, false>), dim3(Td / 128, Bb * Nn / 128, 1), dim3(256), 0, stream,
                       xhi, xlo, liwhi, liwlo, li_b, (float*)nullptr, xphi, xplo,
                       Td, Td, 0LL, 0LL, 0LL);
    // 3. scores[b] = xp[b] @ xp[b]^T  (split-bf16; fp32 out)
    hipLaunchKernelGGL((gemm_bf3_k<false, false, true>), dim3(Nn / 128, Nn / 128, Bb), dim3(256), 0, stream,
                       xphi, xplo, xphi, xplo, (const float*)nullptr, sc, (u16*)nullptr, (u16*)nullptr,
                       Nn, Td, (long long)Nn * Td, (long long)Nn * Td, (long long)Nn * Nn);
    // 4. top-k threshold, +dis_adj, relu, degree
    hipLaunchKernelGGL(topk_k, dim3(Bb * Nn), dim3(256), 0, stream, sc, dis, dinv);
    // 5. L = D^-1/2 A D^-1/2 -> bf16 bL
    hipLaunchKernelGGL(lscale_cast_k, dim3(BNN / 1024), dim3(256), 0, stream,
                       (const float4*)sc, dinv, (uint2*)bL);
    // 6. BatchNorm: stats, then in-place apply + bf16 cast (bufA = bx_bn)
    hipLaunchKernelGGL(bn_partial_k, dim3(8, Nn), dim3(256), 0, stream, (const float4*)x_ln, part);
    hipLaunchKernelGGL(bn_final_k, dim3(Nn), dim3(64), 0, stream, part, bn_g, bn_b, bnsc, bnsh);
    hipLaunchKernelGGL(bn_apply_cast_k, dim3(BNT / 1024), dim3(256), 0, stream,
                       (float4*)x_ln, bnsc, bnsh, (uint2*)bufA);
    // 6b. transposes: x_bn^T -> bufB; cheb_w^T -> bW
    hipLaunchKernelGGL((tcast_k<float>), dim3(Td / 32, Nn / 32, Bb), dim3(256), 0, stream,
                       x_ln, bufB, Nn, Td);
    hipLaunchKernelGGL((tcast_k<float>), dim3(Td / 32, Td / 32, 3), dim3(256), 0, stream,
                       cheb_w, bW, Td, Td);
    // 7. out = Tx0 @ W0
    hipLaunchKernelGGL((gemm_bf_k<false, false, false, true, false>), dim3(Td / 128, Bb * Nn / 128, 1), dim3(256), 0, stream,
                       bufA, bW, (const float*)nullptr, (const float*)nullptr, out, (u16*)nullptr,
                       1.0f, Td, Td, 0LL, 0LL, 0LL, 0LL);
    // 8. Tx1 = L @ Tx0 -> bf16 only (bufA)
    hipLaunchKernelGGL((gemm_bf_k<false, false, false, false, true>), dim3(Td / 128, Nn / 128, Bb), dim3(256), 0, stream,
                       bL, bufB, (const float*)nullptr, (const float*)nullptr, out, bufA,
                       1.0f, Td, Nn, (long long)Nn * Nn, (long long)Td * Nn, 0LL, (long long)Nn * Td);
    // 9. out += Tx1 @ W1
    hipLaunchKernelGGL((gemm_bf_k<true, false, false, true, false>), dim3(Td / 128, Bb * Nn / 128, 1), dim3(256), 0, stream,
                       bufA, bW + (size_t)Td * Td, (const float*)nullptr, (const float*)nullptr, out, (u16*)nullptr,
                       1.0f, Td, Td, 0LL, 0LL, 0LL, 0LL);
    // 9b. Tx1^T -> bufB
    hipLaunchKernelGGL((tcast_k<u16>), dim3(Td / 32, Nn / 32, Bb), dim3(256), 0, stream,
                       bufA, bufB, Nn, Td);
    // 10. Tx2 = 2 L @ Tx1 - Tx0 -> bf16 only (bTx2)
    hipLaunchKernelGGL((gemm_bf_k<false, false, true, false, true>), dim3(Td / 128, Nn / 128, Bb), dim3(256), 0, stream,
                       bL, bufB, (const float*)nullptr, x_ln, out, bTx2,
                       2.0f, Td, Nn, (long long)Nn * Nn, (long long)Td * Nn, (long long)Nn * Td, (long long)Nn * Td);
    // 11. out = relu(out + Tx2 @ W2 + cheb_b)
    hipLaunchKernelGGL((gemm_bf_k<true, true, false, true, false>), dim3(Td / 128, Bb * Nn / 128, 1), dim3(256), 0, stream,
                       bTx2, bW + (size_t)2 * Td * Td, cheb_b, (const float*)nullptr, out, (u16*)nullptr,
                       1.0f, Td, Td, 0LL, 0LL, 0LL, 0LL);
}

// Round 5
// 383.646 us; speedup vs baseline: 3.0239x; 1.0530x over previous
//
#include <hip/hip_runtime.h>
#include <cstddef>

static constexpr int Bb = 64;     // batch
static constexpr int Nn = 256;    // nodes
static constexpr int Td = 512;    // time dim
static constexpr int NMAXS = 51;  // 256 // 5
static constexpr float EPSN = 1e-5f;
static constexpr float EPSD = 1e-10f;

typedef unsigned short u16;
typedef __attribute__((ext_vector_type(8))) short short8;
typedef __attribute__((ext_vector_type(4))) float f32x4;

__device__ __forceinline__ u16 f2b(float f) {
    unsigned u = __float_as_uint(f);
    return (u16)((u + 0x7fffu + ((u >> 16) & 1u)) >> 16);
}
__device__ __forceinline__ float b2f(u16 h) {
    return __uint_as_float(((unsigned)h) << 16);
}

// ---------------- LayerNorm stats: two-stage ----------------
__global__ __launch_bounds__(256) void ln_partial_k(const float4* __restrict__ x,
                                                    float2* __restrict__ part) {
    int b = blockIdx.y, c = blockIdx.x;
    int base = b * 32768 + c * 1024;
    float s = 0.f, s2 = 0.f;
#pragma unroll
    for (int j = 0; j < 4; ++j) {
        float4 v = x[base + j * 256 + threadIdx.x];
        s += v.x + v.y + v.z + v.w;
        s2 += v.x * v.x + v.y * v.y + v.z * v.z + v.w * v.w;
    }
    __shared__ float sh[256], sh2[256];
    sh[threadIdx.x] = s; sh2[threadIdx.x] = s2;
    __syncthreads();
    for (int o = 128; o > 0; o >>= 1) {
        if (threadIdx.x < o) { sh[threadIdx.x] += sh[threadIdx.x + o]; sh2[threadIdx.x] += sh2[threadIdx.x + o]; }
        __syncthreads();
    }
    if (threadIdx.x == 0) part[b * 32 + c] = make_float2(sh[0], sh2[0]);
}

__global__ __launch_bounds__(64) void ln_final_k(const float2* __restrict__ part,
                                                 float* __restrict__ st) {
    int b = blockIdx.x, t = threadIdx.x;
    float s = 0.f, s2 = 0.f;
    if (t < 32) { float2 p = part[b * 32 + t]; s = p.x; s2 = p.y; }
    for (int o = 32; o > 0; o >>= 1) { s += __shfl_down(s, o, 64); s2 += __shfl_down(s2, o, 64); }
    if (t == 0) {
        float inv = 1.f / (Nn * Td);
        float mu = s * inv;
        float var = s2 * inv - mu * mu;
        st[b * 2] = mu;
        st[b * 2 + 1] = rsqrtf(var + EPSN);
    }
}

// LN apply: write fp32 x_ln AND hi/lo bf16 split (for split-MFMA score path)
__global__ __launch_bounds__(256) void ln_apply_split_k(const float4* __restrict__ x,
                                                        const float4* __restrict__ w,
                                                        const float4* __restrict__ bia,
                                                        const float* __restrict__ st,
                                                        float4* __restrict__ out,
                                                        uint2* __restrict__ xhi,
                                                        uint2* __restrict__ xlo) {
    int i = blockIdx.x * 256 + threadIdx.x;
    int r = i & ((Nn * Td / 4) - 1);
    int b = i >> 15;
    float mu = st[b * 2], rs = st[b * 2 + 1];
    float4 xv = x[i], wv = w[r], bv = bia[r];
    float4 o;
    o.x = (xv.x - mu) * rs * wv.x + bv.x;
    o.y = (xv.y - mu) * rs * wv.y + bv.y;
    o.z = (xv.z - mu) * rs * wv.z + bv.z;
    o.w = (xv.w - mu) * rs * wv.w + bv.w;
    out[i] = o;
    u16 hx = f2b(o.x), hy = f2b(o.y), hz = f2b(o.z), hw = f2b(o.w);
    uint2 ph, pl;
    ph.x = (unsigned)hx | ((unsigned)hy << 16);
    ph.y = (unsigned)hz | ((unsigned)hw << 16);
    pl.x = (unsigned)f2b(o.x - b2f(hx)) | ((unsigned)f2b(o.y - b2f(hy)) << 16);
    pl.y = (unsigned)f2b(o.z - b2f(hz)) | ((unsigned)f2b(o.w - b2f(hw)) << 16);
    xhi[i] = ph;
    xlo[i] = pl;
}

// hi/lo split cast for a small fp32 matrix (li_w)
__global__ __launch_bounds__(256) void cast_split_k(const float4* __restrict__ in,
                                                    uint2* __restrict__ hi,
                                                    uint2* __restrict__ lo, int n4) {
    int i = blockIdx.x * 256 + threadIdx.x;
    if (i >= n4) return;
    float4 v = in[i];
    u16 hx = f2b(v.x), hy = f2b(v.y), hz = f2b(v.z), hw = f2b(v.w);
    uint2 ph, pl;
    ph.x = (unsigned)hx | ((unsigned)hy << 16);
    ph.y = (unsigned)hz | ((unsigned)hw << 16);
    pl.x = (unsigned)f2b(v.x - b2f(hx)) | ((unsigned)f2b(v.y - b2f(hy)) << 16);
    pl.y = (unsigned)f2b(v.z - b2f(hz)) | ((unsigned)f2b(v.w - b2f(hw)) << 16);
    hi[i] = ph;
    lo[i] = pl;
}

// ---------------- BatchNorm stats: two-stage ----------------
__global__ __launch_bounds__(256) void bn_partial_k(const float4* __restrict__ x,
                                                    float2* __restrict__ part) {
    int n = blockIdx.y, c = blockIdx.x;
    float s = 0.f, s2 = 0.f;
#pragma unroll
    for (int j = 0; j < 4; ++j) {
        int f = j * 256 + threadIdx.x;
        int bl = f >> 7, t4 = f & 127;
        float4 v = x[((size_t)(c * 8 + bl) * Nn + n) * 128 + t4];
        s += v.x + v.y + v.z + v.w;
        s2 += v.x * v.x + v.y * v.y + v.z * v.z + v.w * v.w;
    }
    __shared__ float sh[256], sh2[256];
    sh[threadIdx.x] = s; sh2[threadIdx.x] = s2;
    __syncthreads();
    for (int o = 128; o > 0; o >>= 1) {
        if (threadIdx.x < o) { sh[threadIdx.x] += sh[threadIdx.x + o]; sh2[threadIdx.x] += sh2[threadIdx.x + o]; }
        __syncthreads();
    }
    if (threadIdx.x == 0) part[n * 8 + c] = make_float2(sh[0], sh2[0]);
}

__global__ __launch_bounds__(64) void bn_final_k(const float2* __restrict__ part,
                                                 const float* __restrict__ g,
                                                 const float* __restrict__ be,
                                                 float* __restrict__ bnsc,
                                                 float* __restrict__ bnsh) {
    int n = blockIdx.x, t = threadIdx.x;
    float s = 0.f, s2 = 0.f;
    if (t < 8) { float2 p = part[n * 8 + t]; s = p.x; s2 = p.y; }
    for (int o = 32; o > 0; o >>= 1) { s += __shfl_down(s, o, 64); s2 += __shfl_down(s2, o, 64); }
    if (t == 0) {
        float inv = 1.f / (Bb * Td);
        float mu = s * inv;
        float var = s2 * inv - mu * mu;
        float rs = rsqrtf(var + EPSN);
        float scale = rs * g[n];
        bnsc[n] = scale;
        bnsh[n] = be[n] - mu * scale;
    }
}

// BN apply in-place (fp32) + fused bf16 row-major cast
__global__ __launch_bounds__(256) void bn_apply_cast_k(float4* __restrict__ x,
                                                       const float* __restrict__ sc,
                                                       const float* __restrict__ shf,
                                                       uint2* __restrict__ bx) {
    int i = blockIdx.x * 256 + threadIdx.x;
    int n = (i >> 7) & 255;
    float s = sc[n], h = shf[n];
    float4 v = x[i];
    v.x = v.x * s + h; v.y = v.y * s + h; v.z = v.z * s + h; v.w = v.w * s + h;
    x[i] = v;
    uint2 p;
    p.x = (unsigned)f2b(v.x) | ((unsigned)f2b(v.y) << 16);
    p.y = (unsigned)f2b(v.z) | ((unsigned)f2b(v.w) << 16);
    bx[i] = p;
}

// ---------------- top-k via histogram radix-select (exact kth largest) ----------------
// One block per row. key = order-preserving u32 transform; kth largest = rank 205
// (0-based ascending, 256-51). 4 passes of 8 bits msb->lsb.
__global__ __launch_bounds__(256) void topk_sel_k(float* __restrict__ sc,
                                                  const float* __restrict__ dis,
                                                  float* __restrict__ dinv) {
    int row = blockIdx.x;
    int n = row & 255;
    int tid = threadIdx.x;
    int lane = tid & 63, wv = tid >> 6;
    float* srow = sc + (size_t)row * Nn;
    float v = srow[tid];
    unsigned fu = __float_as_uint(v);
    unsigned key = (fu & 0x80000000u) ? ~fu : (fu | 0x80000000u);
    __shared__ int hist[256];
    __shared__ int cum[256];
    __shared__ unsigned sh_pref;
    __shared__ int sh_rank;
    __shared__ float wsum[4];
    if (tid == 0) { sh_pref = 0u; sh_rank = Nn - NMAXS; }  // 205
    __syncthreads();
#pragma unroll
    for (int shift = 24; shift >= 0; shift -= 8) {
        unsigned mhi = (shift == 24) ? 0u : (0xFFFFFFFFu << (shift + 8));
        unsigned pref = sh_pref;
        int rank = sh_rank;
        hist[tid] = 0;
        __syncthreads();
        if ((key & mhi) == pref) atomicAdd(&hist[(key >> shift) & 255], 1);
        __syncthreads();
        if (tid < 64) {
            int4 h = *(const int4*)&hist[tid * 4];
            int s0 = h.x, s1 = s0 + h.y, s2 = s1 + h.z, s3 = s2 + h.w;
            int t = s3;
#pragma unroll
            for (int o = 1; o < 64; o <<= 1) { int y = __shfl_up(t, o, 64); if (lane >= o) t += y; }
            int excl = t - s3;
            cum[tid * 4]     = excl + s0;
            cum[tid * 4 + 1] = excl + s1;
            cum[tid * 4 + 2] = excl + s2;
            cum[tid * 4 + 3] = excl + s3;
        }
        __syncthreads();
        int below = (tid == 0) ? 0 : cum[tid - 1];
        if (cum[tid] > rank && below <= rank) {
            sh_pref = pref | ((unsigned)tid << shift);
            sh_rank = rank - below;
        }
        __syncthreads();
    }
    unsigned kk = sh_pref;
    float kth = __uint_as_float((kk & 0x80000000u) ? (kk & 0x7FFFFFFFu) : ~kk);
    float as = (v >= kth) ? v : 0.f;
    float a = fmaxf(as + dis[(size_t)n * Nn + tid], 0.f);
    srow[tid] = a;
    float s = a;
#pragma unroll
    for (int o = 32; o > 0; o >>= 1) s += __shfl_down(s, o, 64);
    if (lane == 0) wsum[wv] = s;
    __syncthreads();
    if (tid == 0) dinv[row] = rsqrtf(wsum[0] + wsum[1] + wsum[2] + wsum[3] + EPSD);
}

// L = D^-1/2 A D^-1/2, cast to bf16
__global__ __launch_bounds__(256) void lscale_cast_k(const float4* __restrict__ Af,
                                                     const float* __restrict__ dinv,
                                                     uint2* __restrict__ bL) {
    int i = blockIdx.x * 256 + threadIdx.x;
    int bn = i >> 6;
    int b = bn >> 8;
    int m0 = (i & 63) << 2;
    float dn = dinv[bn];
    const float* dm = dinv + (b << 8) + m0;
    float4 v = Af[i];
    uint2 p;
    p.x = (unsigned)f2b(v.x * dn * dm[0]) | ((unsigned)f2b(v.y * dn * dm[1]) << 16);
    p.y = (unsigned)f2b(v.z * dn * dm[2]) | ((unsigned)f2b(v.w * dn * dm[3]) << 16);
    bL[i] = p;
}

// ---------------- transpose + cast: [batch][R][C] (SRC) -> [batch][C][R] (bf16) ----------------
template <typename SRC>
__global__ __launch_bounds__(256) void tcast_k(const SRC* __restrict__ in,
                                               u16* __restrict__ out, int R, int C) {
    __shared__ u16 tile[32][33];
    int b = blockIdx.z;
    int c0 = blockIdx.x * 32, r0 = blockIdx.y * 32;
    int tx = threadIdx.x & 31, ty = threadIdx.x >> 5;
    const SRC* ip = in + ((size_t)b * R + r0) * C + c0;
#pragma unroll
    for (int i = 0; i < 4; ++i) {
        int r = ty + i * 8;
        SRC v = ip[(size_t)r * C + tx];
        if constexpr (sizeof(SRC) == 4) tile[r][tx] = f2b((float)v);
        else tile[r][tx] = (u16)v;
    }
    __syncthreads();
    u16* op = out + ((size_t)b * C + c0) * R + r0;
#pragma unroll
    for (int i = 0; i < 4; ++i) {
        int c = ty + i * 8;
        op[(size_t)c * R + tx] = tile[tx][c];
    }
}

// ---------------- bf16 MFMA GEMM (single precision-level), NT ----------------
template <bool ACC, bool FINAL, bool SUBPREV, bool WF32, bool WBF>
__global__ __launch_bounds__(256) void gemm_bf_k(const u16* __restrict__ A,
                                                 const u16* __restrict__ Bt,
                                                 const float* __restrict__ bias,
                                                 const float* __restrict__ prev,
                                                 float* __restrict__ C,
                                                 u16* __restrict__ Cb,
                                                 float alpha, int Ncols, int K,
                                                 long long sA, long long sB,
                                                 long long sPrev, long long sC) {
    __shared__ u16 As[128 * 32];
    __shared__ u16 Bs[128 * 32];
    int z = blockIdx.z;
    const u16* Ag = A + (size_t)z * sA;
    const u16* Bg = Bt + (size_t)z * sB;
    int br = blockIdx.y * 128, bc = blockIdx.x * 128;
    int tid = threadIdx.x, lane = tid & 63, wave = tid >> 6;
    int wr = (wave >> 1) * 64, wc = (wave & 1) * 64;
    int sr = tid >> 1;
    int c0 = tid & 1, c1 = (tid & 1) + 2;
    int swz = sr & 3;
    int w0 = sr * 32 + (c0 ^ swz) * 8;
    int w1 = sr * 32 + (c1 ^ swz) * 8;
    const u16* Agp = Ag + (size_t)(br + sr) * K;
    const u16* Bgp = Bg + (size_t)(bc + sr) * K;
    f32x4 acc[4][4] = {};
    int fr = lane & 15, fq = lane >> 4;
    for (int k0 = 0; k0 < K; k0 += 32) {
        int4 a0 = *(const int4*)(Agp + k0 + c0 * 8);
        int4 a1 = *(const int4*)(Agp + k0 + c1 * 8);
        int4 b0 = *(const int4*)(Bgp + k0 + c0 * 8);
        int4 b1 = *(const int4*)(Bgp + k0 + c1 * 8);
        *(int4*)&As[w0] = a0;
        *(int4*)&As[w1] = a1;
        *(int4*)&Bs[w0] = b0;
        *(int4*)&Bs[w1] = b1;
        __syncthreads();
        short8 af[4], bf[4];
#pragma unroll
        for (int mi = 0; mi < 4; ++mi) {
            int rr = wr + mi * 16 + fr;
            af[mi] = *(const short8*)&As[rr * 32 + ((fq ^ (rr & 3)) << 3)];
        }
#pragma unroll
        for (int ni = 0; ni < 4; ++ni) {
            int rr = wc + ni * 16 + fr;
            bf[ni] = *(const short8*)&Bs[rr * 32 + ((fq ^ (rr & 3)) << 3)];
        }
#pragma unroll
        for (int mi = 0; mi < 4; ++mi)
#pragma unroll
            for (int ni = 0; ni < 4; ++ni)
                acc[mi][ni] = __builtin_amdgcn_mfma_f32_16x16x32_bf16(af[mi], bf[ni], acc[mi][ni], 0, 0, 0);
        __syncthreads();
    }
    const float* Pp = SUBPREV ? prev + (size_t)z * sPrev : nullptr;
    float* Cp = C + (size_t)z * sC;
    u16* Cbp = WBF ? Cb + (size_t)z * sC : nullptr;
#pragma unroll
    for (int mi = 0; mi < 4; ++mi) {
#pragma unroll
        for (int rg = 0; rg < 4; ++rg) {
            int row = br + wr + mi * 16 + fq * 4 + rg;
            size_t rb = (size_t)row * Ncols;
#pragma unroll
            for (int ni = 0; ni < 4; ++ni) {
                int col = bc + wc + ni * 16 + fr;
                float v = alpha * acc[mi][ni][rg];
                if (SUBPREV) v -= Pp[rb + col];
                if (ACC) v += Cp[rb + col];
                if (FINAL) v = fmaxf(v + bias[col], 0.f);
                if (WF32) Cp[rb + col] = v;
                if (WBF) Cbp[rb + col] = f2b(v);
            }
        }
    }
}

// ---------------- split-bf16 3-MFMA GEMM (fp32-emulating), NT ----------------
template <bool BIAS, bool WSPLIT, bool WF32>
__global__ __launch_bounds__(256) void gemm_bf3_k(const u16* __restrict__ Ahi,
                                                  const u16* __restrict__ Alo,
                                                  const u16* __restrict__ Bhi,
                                                  const u16* __restrict__ Blo,
                                                  const float* __restrict__ bias,
                                                  float* __restrict__ C,
                                                  u16* __restrict__ Chi,
                                                  u16* __restrict__ Clo,
                                                  int Ncols, int K,
                                                  long long sA, long long sB, long long sC) {
    __shared__ u16 Ash[128 * 32];
    __shared__ u16 Asl[128 * 32];
    __shared__ u16 Bsh[128 * 32];
    __shared__ u16 Bsl[128 * 32];
    int z = blockIdx.z;
    const u16* Agh = Ahi + (size_t)z * sA;
    const u16* Agl = Alo + (size_t)z * sA;
    const u16* Bgh = Bhi + (size_t)z * sB;
    const u16* Bgl = Blo + (size_t)z * sB;
    int br = blockIdx.y * 128, bc = blockIdx.x * 128;
    int tid = threadIdx.x, lane = tid & 63, wave = tid >> 6;
    int wr = (wave >> 1) * 64, wc = (wave & 1) * 64;
    int sr = tid >> 1;
    int c0 = tid & 1, c1 = (tid & 1) + 2;
    int swz = sr & 3;
    int w0 = sr * 32 + (c0 ^ swz) * 8;
    int w1 = sr * 32 + (c1 ^ swz) * 8;
    size_t rowA = (size_t)(br + sr) * K;
    size_t rowB = (size_t)(bc + sr) * K;
    f32x4 acc[4][4] = {};
    int fr = lane & 15, fq = lane >> 4;
    for (int k0 = 0; k0 < K; k0 += 32) {
        int4 ah0 = *(const int4*)(Agh + rowA + k0 + c0 * 8);
        int4 ah1 = *(const int4*)(Agh + rowA + k0 + c1 * 8);
        int4 al0 = *(const int4*)(Agl + rowA + k0 + c0 * 8);
        int4 al1 = *(const int4*)(Agl + rowA + k0 + c1 * 8);
        int4 bh0 = *(const int4*)(Bgh + rowB + k0 + c0 * 8);
        int4 bh1 = *(const int4*)(Bgh + rowB + k0 + c1 * 8);
        int4 bl0 = *(const int4*)(Bgl + rowB + k0 + c0 * 8);
        int4 bl1 = *(const int4*)(Bgl + rowB + k0 + c1 * 8);
        *(int4*)&Ash[w0] = ah0; *(int4*)&Ash[w1] = ah1;
        *(int4*)&Asl[w0] = al0; *(int4*)&Asl[w1] = al1;
        *(int4*)&Bsh[w0] = bh0; *(int4*)&Bsh[w1] = bh1;
        *(int4*)&Bsl[w0] = bl0; *(int4*)&Bsl[w1] = bl1;
        __syncthreads();
        short8 afh[4], afl[4], bfh[4], bfl[4];
#pragma unroll
        for (int mi = 0; mi < 4; ++mi) {
            int rr = wr + mi * 16 + fr;
            int off = rr * 32 + ((fq ^ (rr & 3)) << 3);
            afh[mi] = *(const short8*)&Ash[off];
            afl[mi] = *(const short8*)&Asl[off];
        }
#pragma unroll
        for (int ni = 0; ni < 4; ++ni) {
            int rr = wc + ni * 16 + fr;
            int off = rr * 32 + ((fq ^ (rr & 3)) << 3);
            bfh[ni] = *(const short8*)&Bsh[off];
            bfl[ni] = *(const short8*)&Bsl[off];
        }
#pragma unroll
        for (int mi = 0; mi < 4; ++mi)
#pragma unroll
            for (int ni = 0; ni < 4; ++ni) {
                acc[mi][ni] = __builtin_amdgcn_mfma_f32_16x16x32_bf16(afh[mi], bfh[ni], acc[mi][ni], 0, 0, 0);
                acc[mi][ni] = __builtin_amdgcn_mfma_f32_16x16x32_bf16(afh[mi], bfl[ni], acc[mi][ni], 0, 0, 0);
                acc[mi][ni] = __builtin_amdgcn_mfma_f32_16x16x32_bf16(afl[mi], bfh[ni], acc[mi][ni], 0, 0, 0);
            }
        __syncthreads();
    }
    float* Cp = WF32 ? C + (size_t)z * sC : nullptr;
    u16* Chp = WSPLIT ? Chi + (size_t)z * sC : nullptr;
    u16* Clp = WSPLIT ? Clo + (size_t)z * sC : nullptr;
#pragma unroll
    for (int mi = 0; mi < 4; ++mi) {
#pragma unroll
        for (int rg = 0; rg < 4; ++rg) {
            int row = br + wr + mi * 16 + fq * 4 + rg;
            size_t rb = (size_t)row * Ncols;
#pragma unroll
            for (int ni = 0; ni < 4; ++ni) {
                int col = bc + wc + ni * 16 + fr;
                float v = acc[mi][ni][rg];
                if (BIAS) v += bias[col];
                if (WF32) Cp[rb + col] = v;
                if (WSPLIT) {
                    u16 h = f2b(v);
                    Chp[rb + col] = h;
                    Clp[rb + col] = f2b(v - b2f(h));
                }
            }
        }
    }
}

extern "C" void kernel_launch(void* const* d_in, const int* in_sizes, int n_in,
                              void* d_out, int out_size, void* d_ws, size_t ws_size,
                              hipStream_t stream) {
    const float* x      = (const float*)d_in[0];
    const float* dis    = (const float*)d_in[1];
    const float* ln_w   = (const float*)d_in[2];
    const float* ln_b   = (const float*)d_in[3];
    const float* bn_g   = (const float*)d_in[4];
    const float* bn_b   = (const float*)d_in[5];
    const float* li_w   = (const float*)d_in[6];
    const float* li_b   = (const float*)d_in[7];
    const float* cheb_w = (const float*)d_in[8];
    const float* cheb_b = (const float*)d_in[9];
    float* out = (float*)d_out;

    const size_t BNT = (size_t)Bb * Nn * Td;   // 8388608
    const size_t BNN = (size_t)Bb * Nn * Nn;   // 4194304
    float* ws   = (float*)d_ws;
    float* x_ln = ws;                           // BNT fp32
    u16* xhi  = (u16*)(x_ln + BNT);             // BNT u16
    u16* xlo  = xhi + BNT;                      // BNT u16
    u16* bufA = xhi;                            // reuse after step 3
    u16* bufB = xlo;
    u16* xphi = (u16*)(x_ln + 2 * BNT);         // BNT u16
    u16* xplo = xphi + BNT;                     // BNT u16
    u16* bW   = xphi;                           // 3*T*T u16, reuse after step 3
    u16* bTx2 = bW + (size_t)3 * Td * Td;       // BNT u16
    float* sc = x_ln + 3 * BNT;                 // BNN fp32
    float* smal = sc + BNN;
    float* lnst = smal;                         // 128
    float* dinv = smal + 128;                   // 16384
    float* bnsc = dinv + 16384;                 // 256
    float* bnsh = bnsc + 256;                   // 256
    float2* part = (float2*)(bnsh + 256);       // 4096 floats
    float* bigp = bnsh + 256 + 4096;
    u16* bL    = (u16*)bigp;                    // BNN u16
    u16* liwhi = bL + BNN;                      // T*T u16
    u16* liwlo = liwhi + (size_t)Td * Td;       // T*T u16

    // 1. LayerNorm (+ hi/lo split of x_ln)
    hipLaunchKernelGGL(ln_partial_k, dim3(32, Bb), dim3(256), 0, stream, (const float4*)x, part);
    hipLaunchKernelGGL(ln_final_k, dim3(Bb), dim3(64), 0, stream, part, lnst);
    hipLaunchKernelGGL(ln_apply_split_k, dim3(BNT / 1024), dim3(256), 0, stream,
                       (const float4*)x, (const float4*)ln_w, (const float4*)ln_b, lnst,
                       (float4*)x_ln, (uint2*)xhi, (uint2*)xlo);
    // 1b. li_w hi/lo split
    hipLaunchKernelGGL(cast_split_k, dim3((Td * Td / 4 + 255) / 256), dim3(256), 0, stream,
                       (const float4*)li_w, (uint2*)liwhi, (uint2*)liwlo, Td * Td / 4);
    // 2. xp = x_ln @ li_w^T + li_b  (split-bf16 3-MFMA; outputs hi/lo split)
    hipLaunchKernelGGL((gemm_bf3_k<true, true, false>), dim3(Td / 128, Bb * Nn / 128, 1), dim3(256), 0, stream,
                       xhi, xlo, liwhi, liwlo, li_b, (float*)nullptr, xphi, xplo,
                       Td, Td, 0LL, 0LL, 0LL);
    // 3. scores[b] = xp[b] @ xp[b]^T  (split-bf16; fp32 out)
    hipLaunchKernelGGL((gemm_bf3_k<false, false, true>), dim3(Nn / 128, Nn / 128, Bb), dim3(256), 0, stream,
                       xphi, xplo, xphi, xplo, (const float*)nullptr, sc, (u16*)nullptr, (u16*)nullptr,
                       Nn, Td, (long long)Nn * Td, (long long)Nn * Td, (long long)Nn * Nn);
    // 4. top-k threshold (radix-select), +dis_adj, relu, degree
    hipLaunchKernelGGL(topk_sel_k, dim3(Bb * Nn), dim3(256), 0, stream, sc, dis, dinv);
    // 5. L = D^-1/2 A D^-1/2 -> bf16 bL
    hipLaunchKernelGGL(lscale_cast_k, dim3(BNN / 1024), dim3(256), 0, stream,
                       (const float4*)sc, dinv, (uint2*)bL);
    // 6. BatchNorm: stats, then in-place apply + bf16 cast (bufA = bx_bn)
    hipLaunchKernelGGL(bn_partial_k, dim3(8, Nn), dim3(256), 0, stream, (const float4*)x_ln, part);
    hipLaunchKernelGGL(bn_final_k, dim3(Nn), dim3(64), 0, stream, part, bn_g, bn_b, bnsc, bnsh);
    hipLaunchKernelGGL(bn_apply_cast_k, dim3(BNT / 1024), dim3(256), 0, stream,
                       (float4*)x_ln, bnsc, bnsh, (uint2*)bufA);
    // 6b. transposes: x_bn^T -> bufB; cheb_w^T -> bW
    hipLaunchKernelGGL((tcast_k<float>), dim3(Td / 32, Nn / 32, Bb), dim3(256), 0, stream,
                       x_ln, bufB, Nn, Td);
    hipLaunchKernelGGL((tcast_k<float>), dim3(Td / 32, Td / 32, 3), dim3(256), 0, stream,
                       cheb_w, bW, Td, Td);
    // 7. out = Tx0 @ W0
    hipLaunchKernelGGL((gemm_bf_k<false, false, false, true, false>), dim3(Td / 128, Bb * Nn / 128, 1), dim3(256), 0, stream,
                       bufA, bW, (const float*)nullptr, (const float*)nullptr, out, (u16*)nullptr,
                       1.0f, Td, Td, 0LL, 0LL, 0LL, 0LL);
    // 8. Tx1 = L @ Tx0 -> bf16 only (bufA)
    hipLaunchKernelGGL((gemm_bf_k<false, false, false, false, true>), dim3(Td / 128, Nn / 128, Bb), dim3(256), 0, stream,
                       bL, bufB, (const float*)nullptr, (const float*)nullptr, out, bufA,
                       1.0f, Td, Nn, (long long)Nn * Nn, (long long)Td * Nn, 0LL, (long long)Nn * Td);
    // 9. out += Tx1 @ W1
    hipLaunchKernelGGL((gemm_bf_k<true, false, false, true, false>), dim3(Td / 128, Bb * Nn / 128, 1), dim3(256), 0, stream,
                       bufA, bW + (size_t)Td * Td, (const float*)nullptr, (const float*)nullptr, out, (u16*)nullptr,
                       1.0f, Td, Td, 0LL, 0LL, 0LL, 0LL);
    // 9b. Tx1^T -> bufB
    hipLaunchKernelGGL((tcast_k<u16>), dim3(Td / 32, Nn / 32, Bb), dim3(256), 0, stream,
                       bufA, bufB, Nn, Td);
    // 10. Tx2 = 2 L @ Tx1 - Tx0 -> bf16 only (bTx2)
    hipLaunchKernelGGL((gemm_bf_k<false, false, true, false, true>), dim3(Td / 128, Nn / 128, Bb), dim3(256), 0, stream,
                       bL, bufB, (const float*)nullptr, x_ln, out, bTx2,
                       2.0f, Td, Nn, (long long)Nn * Nn, (long long)Td * Nn, (long long)Nn * Td, (long long)Nn * Td);
    // 11. out = relu(out + Tx2 @ W2 + cheb_b)
    hipLaunchKernelGGL((gemm_bf_k<true, true, false, true, false>), dim3(Td / 128, Bb * Nn / 128, 1), dim3(256), 0, stream,
                       bTx2, bW + (size_t)2 * Td * Td, cheb_b, (const float*)nullptr, out, (u16*)nullptr,
                       1.0f, Td, Td, 0LL, 0LL, 0LL, 0LL);
}

// Round 6
// 362.356 us; speedup vs baseline: 3.2016x; 1.0588x over previous
//
#include <hip/hip_runtime.h>
#include <cstddef>

static constexpr int Bb = 64;     // batch
static constexpr int Nn = 256;    // nodes
static constexpr int Td = 512;    // time dim
static constexpr int NMAXS = 51;  // 256 // 5
static constexpr float EPSN = 1e-5f;
static constexpr float EPSD = 1e-10f;

typedef unsigned short u16;
typedef __attribute__((ext_vector_type(8))) short short8;
typedef __attribute__((ext_vector_type(4))) float f32x4;

__device__ __forceinline__ u16 f2b(float f) {
    unsigned u = __float_as_uint(f);
    return (u16)((u + 0x7fffu + ((u >> 16) & 1u)) >> 16);
}
__device__ __forceinline__ float b2f(u16 h) {
    return __uint_as_float(((unsigned)h) << 16);
}

// async global->LDS DMA, 16B/lane. LDS dest = wave-uniform base + lane*16.
__device__ __forceinline__ void gload_lds(const u16* g, u16* l) {
    __builtin_amdgcn_global_load_lds(
        (const __attribute__((address_space(1))) unsigned int*)g,
        (__attribute__((address_space(3))) unsigned int*)l, 16, 0, 0);
}
// swizzle: chunk permutation per row; 2-way LDS bank aliasing only (free)
__device__ __forceinline__ int swz4(int r) { return (r ^ (r >> 2)) & 3; }

// ---------------- LayerNorm stats: two-stage ----------------
__global__ __launch_bounds__(256) void ln_partial_k(const float4* __restrict__ x,
                                                    float2* __restrict__ part) {
    int b = blockIdx.y, c = blockIdx.x;
    int base = b * 32768 + c * 1024;
    float s = 0.f, s2 = 0.f;
#pragma unroll
    for (int j = 0; j < 4; ++j) {
        float4 v = x[base + j * 256 + threadIdx.x];
        s += v.x + v.y + v.z + v.w;
        s2 += v.x * v.x + v.y * v.y + v.z * v.z + v.w * v.w;
    }
    __shared__ float sh[256], sh2[256];
    sh[threadIdx.x] = s; sh2[threadIdx.x] = s2;
    __syncthreads();
    for (int o = 128; o > 0; o >>= 1) {
        if (threadIdx.x < o) { sh[threadIdx.x] += sh[threadIdx.x + o]; sh2[threadIdx.x] += sh2[threadIdx.x + o]; }
        __syncthreads();
    }
    if (threadIdx.x == 0) part[b * 32 + c] = make_float2(sh[0], sh2[0]);
}

__global__ __launch_bounds__(64) void ln_final_k(const float2* __restrict__ part,
                                                 float* __restrict__ st) {
    int b = blockIdx.x, t = threadIdx.x;
    float s = 0.f, s2 = 0.f;
    if (t < 32) { float2 p = part[b * 32 + t]; s = p.x; s2 = p.y; }
    for (int o = 32; o > 0; o >>= 1) { s += __shfl_down(s, o, 64); s2 += __shfl_down(s2, o, 64); }
    if (t == 0) {
        float inv = 1.f / (Nn * Td);
        float mu = s * inv;
        float var = s2 * inv - mu * mu;
        st[b * 2] = mu;
        st[b * 2 + 1] = rsqrtf(var + EPSN);
    }
}

// LN apply: write fp32 x_ln AND hi/lo bf16 split (for split-MFMA score path)
__global__ __launch_bounds__(256) void ln_apply_split_k(const float4* __restrict__ x,
                                                        const float4* __restrict__ w,
                                                        const float4* __restrict__ bia,
                                                        const float* __restrict__ st,
                                                        float4* __restrict__ out,
                                                        uint2* __restrict__ xhi,
                                                        uint2* __restrict__ xlo) {
    int i = blockIdx.x * 256 + threadIdx.x;
    int r = i & ((Nn * Td / 4) - 1);
    int b = i >> 15;
    float mu = st[b * 2], rs = st[b * 2 + 1];
    float4 xv = x[i], wv = w[r], bv = bia[r];
    float4 o;
    o.x = (xv.x - mu) * rs * wv.x + bv.x;
    o.y = (xv.y - mu) * rs * wv.y + bv.y;
    o.z = (xv.z - mu) * rs * wv.z + bv.z;
    o.w = (xv.w - mu) * rs * wv.w + bv.w;
    out[i] = o;
    u16 hx = f2b(o.x), hy = f2b(o.y), hz = f2b(o.z), hw = f2b(o.w);
    uint2 ph, pl;
    ph.x = (unsigned)hx | ((unsigned)hy << 16);
    ph.y = (unsigned)hz | ((unsigned)hw << 16);
    pl.x = (unsigned)f2b(o.x - b2f(hx)) | ((unsigned)f2b(o.y - b2f(hy)) << 16);
    pl.y = (unsigned)f2b(o.z - b2f(hz)) | ((unsigned)f2b(o.w - b2f(hw)) << 16);
    xhi[i] = ph;
    xlo[i] = pl;
}

// hi/lo split cast for a small fp32 matrix (li_w)
__global__ __launch_bounds__(256) void cast_split_k(const float4* __restrict__ in,
                                                    uint2* __restrict__ hi,
                                                    uint2* __restrict__ lo, int n4) {
    int i = blockIdx.x * 256 + threadIdx.x;
    if (i >= n4) return;
    float4 v = in[i];
    u16 hx = f2b(v.x), hy = f2b(v.y), hz = f2b(v.z), hw = f2b(v.w);
    uint2 ph, pl;
    ph.x = (unsigned)hx | ((unsigned)hy << 16);
    ph.y = (unsigned)hz | ((unsigned)hw << 16);
    pl.x = (unsigned)f2b(v.x - b2f(hx)) | ((unsigned)f2b(v.y - b2f(hy)) << 16);
    pl.y = (unsigned)f2b(v.z - b2f(hz)) | ((unsigned)f2b(v.w - b2f(hw)) << 16);
    hi[i] = ph;
    lo[i] = pl;
}

// ---------------- BatchNorm stats: two-stage ----------------
__global__ __launch_bounds__(256) void bn_partial_k(const float4* __restrict__ x,
                                                    float2* __restrict__ part) {
    int n = blockIdx.y, c = blockIdx.x;
    float s = 0.f, s2 = 0.f;
#pragma unroll
    for (int j = 0; j < 4; ++j) {
        int f = j * 256 + threadIdx.x;
        int bl = f >> 7, t4 = f & 127;
        float4 v = x[((size_t)(c * 8 + bl) * Nn + n) * 128 + t4];
        s += v.x + v.y + v.z + v.w;
        s2 += v.x * v.x + v.y * v.y + v.z * v.z + v.w * v.w;
    }
    __shared__ float sh[256], sh2[256];
    sh[threadIdx.x] = s; sh2[threadIdx.x] = s2;
    __syncthreads();
    for (int o = 128; o > 0; o >>= 1) {
        if (threadIdx.x < o) { sh[threadIdx.x] += sh[threadIdx.x + o]; sh2[threadIdx.x] += sh2[threadIdx.x + o]; }
        __syncthreads();
    }
    if (threadIdx.x == 0) part[n * 8 + c] = make_float2(sh[0], sh2[0]);
}

__global__ __launch_bounds__(64) void bn_final_k(const float2* __restrict__ part,
                                                 const float* __restrict__ g,
                                                 const float* __restrict__ be,
                                                 float* __restrict__ bnsc,
                                                 float* __restrict__ bnsh) {
    int n = blockIdx.x, t = threadIdx.x;
    float s = 0.f, s2 = 0.f;
    if (t < 8) { float2 p = part[n * 8 + t]; s = p.x; s2 = p.y; }
    for (int o = 32; o > 0; o >>= 1) { s += __shfl_down(s, o, 64); s2 += __shfl_down(s2, o, 64); }
    if (t == 0) {
        float inv = 1.f / (Bb * Td);
        float mu = s * inv;
        float var = s2 * inv - mu * mu;
        float rs = rsqrtf(var + EPSN);
        float scale = rs * g[n];
        bnsc[n] = scale;
        bnsh[n] = be[n] - mu * scale;
    }
}

// BN apply: read fp32 x_ln, write bf16 x_bn ONLY (fp32 x_bn never materialized)
__global__ __launch_bounds__(256) void bn_apply_cast_k(const float4* __restrict__ x,
                                                       const float* __restrict__ sc,
                                                       const float* __restrict__ shf,
                                                       uint2* __restrict__ bx) {
    int i = blockIdx.x * 256 + threadIdx.x;
    int n = (i >> 7) & 255;
    float s = sc[n], h = shf[n];
    float4 v = x[i];
    v.x = v.x * s + h; v.y = v.y * s + h; v.z = v.z * s + h; v.w = v.w * s + h;
    uint2 p;
    p.x = (unsigned)f2b(v.x) | ((unsigned)f2b(v.y) << 16);
    p.y = (unsigned)f2b(v.z) | ((unsigned)f2b(v.w) << 16);
    bx[i] = p;
}

// ---------------- top-k via histogram radix-select (exact kth largest) ----------------
__global__ __launch_bounds__(256) void topk_sel_k(float* __restrict__ sc,
                                                  const float* __restrict__ dis,
                                                  float* __restrict__ dinv) {
    int row = blockIdx.x;
    int n = row & 255;
    int tid = threadIdx.x;
    int lane = tid & 63, wv = tid >> 6;
    float* srow = sc + (size_t)row * Nn;
    float v = srow[tid];
    unsigned fu = __float_as_uint(v);
    unsigned key = (fu & 0x80000000u) ? ~fu : (fu | 0x80000000u);
    __shared__ int hist[256];
    __shared__ int cum[256];
    __shared__ unsigned sh_pref;
    __shared__ int sh_rank;
    __shared__ float wsum[4];
    if (tid == 0) { sh_pref = 0u; sh_rank = Nn - NMAXS; }  // 205
    __syncthreads();
#pragma unroll
    for (int shift = 24; shift >= 0; shift -= 8) {
        unsigned mhi = (shift == 24) ? 0u : (0xFFFFFFFFu << (shift + 8));
        unsigned pref = sh_pref;
        int rank = sh_rank;
        hist[tid] = 0;
        __syncthreads();
        if ((key & mhi) == pref) atomicAdd(&hist[(key >> shift) & 255], 1);
        __syncthreads();
        if (tid < 64) {
            int4 h = *(const int4*)&hist[tid * 4];
            int s0 = h.x, s1 = s0 + h.y, s2 = s1 + h.z, s3 = s2 + h.w;
            int t = s3;
#pragma unroll
            for (int o = 1; o < 64; o <<= 1) { int y = __shfl_up(t, o, 64); if (lane >= o) t += y; }
            int excl = t - s3;
            cum[tid * 4]     = excl + s0;
            cum[tid * 4 + 1] = excl + s1;
            cum[tid * 4 + 2] = excl + s2;
            cum[tid * 4 + 3] = excl + s3;
        }
        __syncthreads();
        int below = (tid == 0) ? 0 : cum[tid - 1];
        if (cum[tid] > rank && below <= rank) {
            sh_pref = pref | ((unsigned)tid << shift);
            sh_rank = rank - below;
        }
        __syncthreads();
    }
    unsigned kk = sh_pref;
    float kth = __uint_as_float((kk & 0x80000000u) ? (kk & 0x7FFFFFFFu) : ~kk);
    float as = (v >= kth) ? v : 0.f;
    float a = fmaxf(as + dis[(size_t)n * Nn + tid], 0.f);
    srow[tid] = a;
    float s = a;
#pragma unroll
    for (int o = 32; o > 0; o >>= 1) s += __shfl_down(s, o, 64);
    if (lane == 0) wsum[wv] = s;
    __syncthreads();
    if (tid == 0) dinv[row] = rsqrtf(wsum[0] + wsum[1] + wsum[2] + wsum[3] + EPSD);
}

// L = D^-1/2 A D^-1/2, cast to bf16
__global__ __launch_bounds__(256) void lscale_cast_k(const float4* __restrict__ Af,
                                                     const float* __restrict__ dinv,
                                                     uint2* __restrict__ bL) {
    int i = blockIdx.x * 256 + threadIdx.x;
    int bn = i >> 6;
    int b = bn >> 8;
    int m0 = (i & 63) << 2;
    float dn = dinv[bn];
    const float* dm = dinv + (b << 8) + m0;
    float4 v = Af[i];
    uint2 p;
    p.x = (unsigned)f2b(v.x * dn * dm[0]) | ((unsigned)f2b(v.y * dn * dm[1]) << 16);
    p.y = (unsigned)f2b(v.z * dn * dm[2]) | ((unsigned)f2b(v.w * dn * dm[3]) << 16);
    bL[i] = p;
}

// ---------------- transpose + cast: [batch][R][C] (SRC) -> [batch][C][R] (bf16) ----------------
template <typename SRC>
__global__ __launch_bounds__(256) void tcast_k(const SRC* __restrict__ in,
                                               u16* __restrict__ out, int R, int C) {
    __shared__ u16 tile[32][33];
    int b = blockIdx.z;
    int c0 = blockIdx.x * 32, r0 = blockIdx.y * 32;
    int tx = threadIdx.x & 31, ty = threadIdx.x >> 5;
    const SRC* ip = in + ((size_t)b * R + r0) * C + c0;
#pragma unroll
    for (int i = 0; i < 4; ++i) {
        int r = ty + i * 8;
        SRC v = ip[(size_t)r * C + tx];
        if constexpr (sizeof(SRC) == 4) tile[r][tx] = f2b((float)v);
        else tile[r][tx] = (u16)v;
    }
    __syncthreads();
    u16* op = out + ((size_t)b * C + c0) * R + r0;
#pragma unroll
    for (int i = 0; i < 4; ++i) {
        int c = ty + i * 8;
        op[(size_t)c * R + tx] = tile[tx][c];
    }
}

// ---------------- bf16 MFMA GEMM, NT, global_load_lds staging ----------------
// br from blockIdx.x (rows fastest -> same-A col-blocks share an XCD).
// SUBPREV reads bf16 prev.
template <bool ACC, bool FINAL, bool SUBPREV, bool WF32, bool WBF>
__global__ __launch_bounds__(256) void gemm_bf_k(const u16* __restrict__ A,
                                                 const u16* __restrict__ Bt,
                                                 const float* __restrict__ bias,
                                                 const u16* __restrict__ prevb,
                                                 float* __restrict__ C,
                                                 u16* __restrict__ Cb,
                                                 float alpha, int Ncols, int K,
                                                 long long sA, long long sB,
                                                 long long sPrev, long long sC) {
    __shared__ u16 As[128 * 32];
    __shared__ u16 Bs[128 * 32];
    int z = blockIdx.z;
    const u16* Ag = A + (size_t)z * sA;
    const u16* Bg = Bt + (size_t)z * sB;
    int br = blockIdx.x * 128, bc = blockIdx.y * 128;
    int tid = threadIdx.x, lane = tid & 63, wave = tid >> 6;
    int wr = (wave >> 1) * 64, wc = (wave & 1) * 64;
    // staging: wave issues DMA instrs {2w, 2w+1} per buffer; instr i covers rows [16i,16i+16)
    int i0 = wave * 2;
    int rl0 = i0 * 16 + (lane >> 2);
    int rl1 = rl0 + 16;
    int cp = lane & 3;
    int ca0 = (cp ^ swz4(rl0)) * 8;
    int ca1 = (cp ^ swz4(rl1)) * 8;
    const u16* gA0 = Ag + (size_t)(br + rl0) * K + ca0;
    const u16* gA1 = Ag + (size_t)(br + rl1) * K + ca1;
    const u16* gB0 = Bg + (size_t)(bc + rl0) * K + ca0;
    const u16* gB1 = Bg + (size_t)(bc + rl1) * K + ca1;
    u16* lA0 = &As[i0 * 512];
    u16* lA1 = lA0 + 512;
    u16* lB0 = &Bs[i0 * 512];
    u16* lB1 = lB0 + 512;
    f32x4 acc[4][4] = {};
    int fr = lane & 15, fq = lane >> 4;
    for (int k0 = 0; k0 < K; k0 += 32) {
        gload_lds(gA0 + k0, lA0);
        gload_lds(gA1 + k0, lA1);
        gload_lds(gB0 + k0, lB0);
        gload_lds(gB1 + k0, lB1);
        __syncthreads();
        short8 af[4], bf[4];
#pragma unroll
        for (int mi = 0; mi < 4; ++mi) {
            int rr = wr + mi * 16 + fr;
            af[mi] = *(const short8*)&As[rr * 32 + ((fq ^ swz4(rr)) << 3)];
        }
#pragma unroll
        for (int ni = 0; ni < 4; ++ni) {
            int rr = wc + ni * 16 + fr;
            bf[ni] = *(const short8*)&Bs[rr * 32 + ((fq ^ swz4(rr)) << 3)];
        }
#pragma unroll
        for (int mi = 0; mi < 4; ++mi)
#pragma unroll
            for (int ni = 0; ni < 4; ++ni)
                acc[mi][ni] = __builtin_amdgcn_mfma_f32_16x16x32_bf16(af[mi], bf[ni], acc[mi][ni], 0, 0, 0);
        __syncthreads();
    }
    const u16* Pp = SUBPREV ? prevb + (size_t)z * sPrev : nullptr;
    float* Cp = C + (size_t)z * sC;
    u16* Cbp = WBF ? Cb + (size_t)z * sC : nullptr;
#pragma unroll
    for (int mi = 0; mi < 4; ++mi) {
#pragma unroll
        for (int rg = 0; rg < 4; ++rg) {
            int row = br + wr + mi * 16 + fq * 4 + rg;
            size_t rb = (size_t)row * Ncols;
#pragma unroll
            for (int ni = 0; ni < 4; ++ni) {
                int col = bc + wc + ni * 16 + fr;
                float v = alpha * acc[mi][ni][rg];
                if (SUBPREV) v -= b2f(Pp[rb + col]);
                if (ACC) v += Cp[rb + col];
                if (FINAL) v = fmaxf(v + bias[col], 0.f);
                if (WF32) Cp[rb + col] = v;
                if (WBF) Cbp[rb + col] = f2b(v);
            }
        }
    }
}

// ---------------- split-bf16 3-MFMA GEMM (fp32-emulating), NT, DMA staging ----------------
template <bool BIAS, bool WSPLIT, bool WF32>
__global__ __launch_bounds__(256) void gemm_bf3_k(const u16* __restrict__ Ahi,
                                                  const u16* __restrict__ Alo,
                                                  const u16* __restrict__ Bhi,
                                                  const u16* __restrict__ Blo,
                                                  const float* __restrict__ bias,
                                                  float* __restrict__ C,
                                                  u16* __restrict__ Chi,
                                                  u16* __restrict__ Clo,
                                                  int Ncols, int K,
                                                  long long sA, long long sB, long long sC) {
    __shared__ u16 Ash[128 * 32];
    __shared__ u16 Asl[128 * 32];
    __shared__ u16 Bsh[128 * 32];
    __shared__ u16 Bsl[128 * 32];
    int z = blockIdx.z;
    const u16* Agh = Ahi + (size_t)z * sA;
    const u16* Agl = Alo + (size_t)z * sA;
    const u16* Bgh = Bhi + (size_t)z * sB;
    const u16* Bgl = Blo + (size_t)z * sB;
    int br = blockIdx.x * 128, bc = blockIdx.y * 128;
    int tid = threadIdx.x, lane = tid & 63, wave = tid >> 6;
    int wr = (wave >> 1) * 64, wc = (wave & 1) * 64;
    int i0 = wave * 2;
    int rl0 = i0 * 16 + (lane >> 2);
    int rl1 = rl0 + 16;
    int cp = lane & 3;
    int ca0 = (cp ^ swz4(rl0)) * 8;
    int ca1 = (cp ^ swz4(rl1)) * 8;
    size_t oA0 = (size_t)(br + rl0) * K + ca0;
    size_t oA1 = (size_t)(br + rl1) * K + ca1;
    size_t oB0 = (size_t)(bc + rl0) * K + ca0;
    size_t oB1 = (size_t)(bc + rl1) * K + ca1;
    u16* lA0 = &Ash[i0 * 512]; u16* lA1 = lA0 + 512;
    u16* lAl0 = &Asl[i0 * 512]; u16* lAl1 = lAl0 + 512;
    u16* lB0 = &Bsh[i0 * 512]; u16* lB1 = lB0 + 512;
    u16* lBl0 = &Bsl[i0 * 512]; u16* lBl1 = lBl0 + 512;
    f32x4 acc[4][4] = {};
    int fr = lane & 15, fq = lane >> 4;
    for (int k0 = 0; k0 < K; k0 += 32) {
        gload_lds(Agh + oA0 + k0, lA0);
        gload_lds(Agh + oA1 + k0, lA1);
        gload_lds(Agl + oA0 + k0, lAl0);
        gload_lds(Agl + oA1 + k0, lAl1);
        gload_lds(Bgh + oB0 + k0, lB0);
        gload_lds(Bgh + oB1 + k0, lB1);
        gload_lds(Bgl + oB0 + k0, lBl0);
        gload_lds(Bgl + oB1 + k0, lBl1);
        __syncthreads();
        short8 afh[4], afl[4], bfh[4], bfl[4];
#pragma unroll
        for (int mi = 0; mi < 4; ++mi) {
            int rr = wr + mi * 16 + fr;
            int off = rr * 32 + ((fq ^ swz4(rr)) << 3);
            afh[mi] = *(const short8*)&Ash[off];
            afl[mi] = *(const short8*)&Asl[off];
        }
#pragma unroll
        for (int ni = 0; ni < 4; ++ni) {
            int rr = wc + ni * 16 + fr;
            int off = rr * 32 + ((fq ^ swz4(rr)) << 3);
            bfh[ni] = *(const short8*)&Bsh[off];
            bfl[ni] = *(const short8*)&Bsl[off];
        }
#pragma unroll
        for (int mi = 0; mi < 4; ++mi)
#pragma unroll
            for (int ni = 0; ni < 4; ++ni) {
                acc[mi][ni] = __builtin_amdgcn_mfma_f32_16x16x32_bf16(afh[mi], bfh[ni], acc[mi][ni], 0, 0, 0);
                acc[mi][ni] = __builtin_amdgcn_mfma_f32_16x16x32_bf16(afh[mi], bfl[ni], acc[mi][ni], 0, 0, 0);
                acc[mi][ni] = __builtin_amdgcn_mfma_f32_16x16x32_bf16(afl[mi], bfh[ni], acc[mi][ni], 0, 0, 0);
            }
        __syncthreads();
    }
    float* Cp = WF32 ? C + (size_t)z * sC : nullptr;
    u16* Chp = WSPLIT ? Chi + (size_t)z * sC : nullptr;
    u16* Clp = WSPLIT ? Clo + (size_t)z * sC : nullptr;
#pragma unroll
    for (int mi = 0; mi < 4; ++mi) {
#pragma unroll
        for (int rg = 0; rg < 4; ++rg) {
            int row = br + wr + mi * 16 + fq * 4 + rg;
            size_t rb = (size_t)row * Ncols;
#pragma unroll
            for (int ni = 0; ni < 4; ++ni) {
                int col = bc + wc + ni * 16 + fr;
                float v = acc[mi][ni][rg];
                if (BIAS) v += bias[col];
                if (WF32) Cp[rb + col] = v;
                if (WSPLIT) {
                    u16 h = f2b(v);
                    Chp[rb + col] = h;
                    Clp[rb + col] = f2b(v - b2f(h));
                }
            }
        }
    }
}

extern "C" void kernel_launch(void* const* d_in, const int* in_sizes, int n_in,
                              void* d_out, int out_size, void* d_ws, size_t ws_size,
                              hipStream_t stream) {
    const float* x      = (const float*)d_in[0];
    const float* dis    = (const float*)d_in[1];
    const float* ln_w   = (const float*)d_in[2];
    const float* ln_b   = (const float*)d_in[3];
    const float* bn_g   = (const float*)d_in[4];
    const float* bn_b   = (const float*)d_in[5];
    const float* li_w   = (const float*)d_in[6];
    const float* li_b   = (const float*)d_in[7];
    const float* cheb_w = (const float*)d_in[8];
    const float* cheb_b = (const float*)d_in[9];
    float* out = (float*)d_out;

    const size_t BNT = (size_t)Bb * Nn * Td;   // 8388608
    const size_t BNN = (size_t)Bb * Nn * Nn;   // 4194304
    float* ws   = (float*)d_ws;
    // region1: fp32 x_ln (dead after bn_apply_cast) -> then bTx1 bf16
    float* x_ln = ws;                           // BNT fp32
    u16* bTx1 = (u16*)x_ln;                     // reuse after step 6
    // region2: xhi/xlo (steps 1-2) -> bufA (Tx0 bf16, persists) / bufB (transposes)
    u16* xhi  = (u16*)(x_ln + BNT);
    u16* xlo  = xhi + BNT;
    u16* bufA = xhi;
    u16* bufB = xlo;
    // region3: xphi/xplo (steps 2-3) -> bW + bTx2
    u16* xphi = (u16*)(x_ln + 2 * BNT);
    u16* xplo = xphi + BNT;
    u16* bW   = xphi;
    u16* bTx2 = bW + (size_t)3 * Td * Td;
    // region4: scores fp32
    float* sc = x_ln + 3 * BNT;
    float* smal = sc + BNN;
    float* lnst = smal;                         // 128
    float* dinv = smal + 128;                   // 16384
    float* bnsc = dinv + 16384;                 // 256
    float* bnsh = bnsc + 256;                   // 256
    float2* part = (float2*)(bnsh + 256);       // 4096 floats
    float* bigp = bnsh + 256 + 4096;
    u16* bL    = (u16*)bigp;                    // BNN u16
    u16* liwhi = bL + BNN;                      // T*T u16
    u16* liwlo = liwhi + (size_t)Td * Td;       // T*T u16

    // 1. LayerNorm (+ hi/lo split of x_ln)
    hipLaunchKernelGGL(ln_partial_k, dim3(32, Bb), dim3(256), 0, stream, (const float4*)x, part);
    hipLaunchKernelGGL(ln_final_k, dim3(Bb), dim3(64), 0, stream, part, lnst);
    hipLaunchKernelGGL(ln_apply_split_k, dim3(BNT / 1024), dim3(256), 0, stream,
                       (const float4*)x, (const float4*)ln_w, (const float4*)ln_b, lnst,
                       (float4*)x_ln, (uint2*)xhi, (uint2*)xlo);
    // 1b. li_w hi/lo split
    hipLaunchKernelGGL(cast_split_k, dim3((Td * Td / 4 + 255) / 256), dim3(256), 0, stream,
                       (const float4*)li_w, (uint2*)liwhi, (uint2*)liwlo, Td * Td / 4);
    // 2. xp = x_ln @ li_w^T + li_b  (split-bf16 3-MFMA; rows on blockIdx.x)
    hipLaunchKernelGGL((gemm_bf3_k<true, true, false>), dim3(Bb * Nn / 128, Td / 128, 1), dim3(256), 0, stream,
                       xhi, xlo, liwhi, liwlo, li_b, (float*)nullptr, xphi, xplo,
                       Td, Td, 0LL, 0LL, 0LL);
    // 3. scores[b] = xp[b] @ xp[b]^T  (split-bf16; fp32 out)
    hipLaunchKernelGGL((gemm_bf3_k<false, false, true>), dim3(Nn / 128, Nn / 128, Bb), dim3(256), 0, stream,
                       xphi, xplo, xphi, xplo, (const float*)nullptr, sc, (u16*)nullptr, (u16*)nullptr,
                       Nn, Td, (long long)Nn * Td, (long long)Nn * Td, (long long)Nn * Nn);
    // 4. top-k threshold (radix-select), +dis_adj, relu, degree
    hipLaunchKernelGGL(topk_sel_k, dim3(Bb * Nn), dim3(256), 0, stream, sc, dis, dinv);
    // 5. L = D^-1/2 A D^-1/2 -> bf16 bL
    hipLaunchKernelGGL(lscale_cast_k, dim3(BNN / 1024), dim3(256), 0, stream,
                       (const float4*)sc, dinv, (uint2*)bL);
    // 6. BatchNorm: stats, then apply + bf16 cast only (bufA = Tx0 bf16)
    hipLaunchKernelGGL(bn_partial_k, dim3(8, Nn), dim3(256), 0, stream, (const float4*)x_ln, part);
    hipLaunchKernelGGL(bn_final_k, dim3(Nn), dim3(64), 0, stream, part, bn_g, bn_b, bnsc, bnsh);
    hipLaunchKernelGGL(bn_apply_cast_k, dim3(BNT / 1024), dim3(256), 0, stream,
                       (const float4*)x_ln, bnsc, bnsh, (uint2*)bufA);
    // 6b. transposes: Tx0^T (u16->u16) -> bufB; cheb_w^T -> bW
    hipLaunchKernelGGL((tcast_k<u16>), dim3(Td / 32, Nn / 32, Bb), dim3(256), 0, stream,
                       bufA, bufB, Nn, Td);
    hipLaunchKernelGGL((tcast_k<float>), dim3(Td / 32, Td / 32, 3), dim3(256), 0, stream,
                       cheb_w, bW, Td, Td);
    // 7. out = Tx0 @ W0
    hipLaunchKernelGGL((gemm_bf_k<false, false, false, true, false>), dim3(Bb * Nn / 128, Td / 128, 1), dim3(256), 0, stream,
                       bufA, bW, (const float*)nullptr, (const u16*)nullptr, out, (u16*)nullptr,
                       1.0f, Td, Td, 0LL, 0LL, 0LL, 0LL);
    // 8. Tx1 = L @ Tx0 -> bf16 (bTx1, in freed x_ln region)
    hipLaunchKernelGGL((gemm_bf_k<false, false, false, false, true>), dim3(Nn / 128, Td / 128, Bb), dim3(256), 0, stream,
                       bL, bufB, (const float*)nullptr, (const u16*)nullptr, out, bTx1,
                       1.0f, Td, Nn, (long long)Nn * Nn, (long long)Td * Nn, 0LL, (long long)Nn * Td);
    // 9. out += Tx1 @ W1
    hipLaunchKernelGGL((gemm_bf_k<true, false, false, true, false>), dim3(Bb * Nn / 128, Td / 128, 1), dim3(256), 0, stream,
                       bTx1, bW + (size_t)Td * Td, (const float*)nullptr, (const u16*)nullptr, out, (u16*)nullptr,
                       1.0f, Td, Td, 0LL, 0LL, 0LL, 0LL);
    // 9b. Tx1^T -> bufB
    hipLaunchKernelGGL((tcast_k<u16>), dim3(Td / 32, Nn / 32, Bb), dim3(256), 0, stream,
                       bTx1, bufB, Nn, Td);
    // 10. Tx2 = 2 L @ Tx1 - Tx0 -> bf16 (bTx2); prev = bufA (bf16 Tx0)
    hipLaunchKernelGGL((gemm_bf_k<false, false, true, false, true>), dim3(Nn / 128, Td / 128, Bb), dim3(256), 0, stream,
                       bL, bufB, (const float*)nullptr, bufA, out, bTx2,
                       2.0f, Td, Nn, (long long)Nn * Nn, (long long)Td * Nn, (long long)Nn * Td, (long long)Nn * Td);
    // 11. out = relu(out + Tx2 @ W2 + cheb_b)
    hipLaunchKernelGGL((gemm_bf_k<true, true, false, true, false>), dim3(Bb * Nn / 128, Td / 128, 1), dim3(256), 0, stream,
                       bTx2, bW + (size_t)2 * Td * Td, cheb_b, (const u16*)nullptr, out, (u16*)nullptr,
                       1.0f, Td, Td, 0LL, 0LL, 0LL, 0LL);
}

// Round 7
// 332.775 us; speedup vs baseline: 3.4862x; 1.0889x over previous
//
#include <hip/hip_runtime.h>
#include <cstddef>

static constexpr int Bb = 64;     // batch
static constexpr int Nn = 256;    // nodes
static constexpr int Td = 512;    // time dim
static constexpr int NMAXS = 51;  // 256 // 5
static constexpr float EPSN = 1e-5f;
static constexpr float EPSD = 1e-10f;

typedef unsigned short u16;
typedef __attribute__((ext_vector_type(8))) short short8;
typedef __attribute__((ext_vector_type(4))) float f32x4;

__device__ __forceinline__ u16 f2b(float f) {
    unsigned u = __float_as_uint(f);
    return (u16)((u + 0x7fffu + ((u >> 16) & 1u)) >> 16);
}
__device__ __forceinline__ float b2f(u16 h) {
    return __uint_as_float(((unsigned)h) << 16);
}
__device__ __forceinline__ float4 unp2(uint2 h, uint2 l) {
    float4 r;
    r.x = b2f((u16)h.x) + b2f((u16)l.x);
    r.y = b2f((u16)(h.x >> 16)) + b2f((u16)(l.x >> 16));
    r.z = b2f((u16)h.y) + b2f((u16)l.y);
    r.w = b2f((u16)(h.y >> 16)) + b2f((u16)(l.y >> 16));
    return r;
}

// async global->LDS DMA, 16B/lane. LDS dest = wave-uniform base + lane*16.
__device__ __forceinline__ void gload_lds(const u16* g, u16* l) {
    __builtin_amdgcn_global_load_lds(
        (const __attribute__((address_space(1))) unsigned int*)g,
        (__attribute__((address_space(3))) unsigned int*)l, 16, 0, 0);
}
__device__ __forceinline__ int swz4(int r) { return (r ^ (r >> 2)) & 3; }

// ---------------- LayerNorm stats: two-stage ----------------
__global__ __launch_bounds__(256) void ln_partial_k(const float4* __restrict__ x,
                                                    float2* __restrict__ part) {
    int b = blockIdx.y, c = blockIdx.x;
    int base = b * 32768 + c * 1024;
    float s = 0.f, s2 = 0.f;
#pragma unroll
    for (int j = 0; j < 4; ++j) {
        float4 v = x[base + j * 256 + threadIdx.x];
        s += v.x + v.y + v.z + v.w;
        s2 += v.x * v.x + v.y * v.y + v.z * v.z + v.w * v.w;
    }
    __shared__ float sh[256], sh2[256];
    sh[threadIdx.x] = s; sh2[threadIdx.x] = s2;
    __syncthreads();
    for (int o = 128; o > 0; o >>= 1) {
        if (threadIdx.x < o) { sh[threadIdx.x] += sh[threadIdx.x + o]; sh2[threadIdx.x] += sh2[threadIdx.x + o]; }
        __syncthreads();
    }
    if (threadIdx.x == 0) part[b * 32 + c] = make_float2(sh[0], sh2[0]);
}

__global__ __launch_bounds__(64) void ln_final_k(const float2* __restrict__ part,
                                                 float* __restrict__ st) {
    int b = blockIdx.x, t = threadIdx.x;
    float s = 0.f, s2 = 0.f;
    if (t < 32) { float2 p = part[b * 32 + t]; s = p.x; s2 = p.y; }
    for (int o = 32; o > 0; o >>= 1) { s += __shfl_down(s, o, 64); s2 += __shfl_down(s2, o, 64); }
    if (t == 0) {
        float inv = 1.f / (Nn * Td);
        float mu = s * inv;
        float var = s2 * inv - mu * mu;
        st[b * 2] = mu;
        st[b * 2 + 1] = rsqrtf(var + EPSN);
    }
}

// LN apply: write hi/lo bf16 split only (fp32 x_ln never materialized)
__global__ __launch_bounds__(256) void ln_apply_split_k(const float4* __restrict__ x,
                                                        const float4* __restrict__ w,
                                                        const float4* __restrict__ bia,
                                                        const float* __restrict__ st,
                                                        uint2* __restrict__ xhi,
                                                        uint2* __restrict__ xlo) {
    int i = blockIdx.x * 256 + threadIdx.x;
    int r = i & ((Nn * Td / 4) - 1);
    int b = i >> 15;
    float mu = st[b * 2], rs = st[b * 2 + 1];
    float4 xv = x[i], wv = w[r], bv = bia[r];
    float4 o;
    o.x = (xv.x - mu) * rs * wv.x + bv.x;
    o.y = (xv.y - mu) * rs * wv.y + bv.y;
    o.z = (xv.z - mu) * rs * wv.z + bv.z;
    o.w = (xv.w - mu) * rs * wv.w + bv.w;
    u16 hx = f2b(o.x), hy = f2b(o.y), hz = f2b(o.z), hw = f2b(o.w);
    uint2 ph, pl;
    ph.x = (unsigned)hx | ((unsigned)hy << 16);
    ph.y = (unsigned)hz | ((unsigned)hw << 16);
    pl.x = (unsigned)f2b(o.x - b2f(hx)) | ((unsigned)f2b(o.y - b2f(hy)) << 16);
    pl.y = (unsigned)f2b(o.z - b2f(hz)) | ((unsigned)f2b(o.w - b2f(hw)) << 16);
    xhi[i] = ph;
    xlo[i] = pl;
}

// hi/lo split cast for a small fp32 matrix (li_w)
__global__ __launch_bounds__(256) void cast_split_k(const float4* __restrict__ in,
                                                    uint2* __restrict__ hi,
                                                    uint2* __restrict__ lo, int n4) {
    int i = blockIdx.x * 256 + threadIdx.x;
    if (i >= n4) return;
    float4 v = in[i];
    u16 hx = f2b(v.x), hy = f2b(v.y), hz = f2b(v.z), hw = f2b(v.w);
    uint2 ph, pl;
    ph.x = (unsigned)hx | ((unsigned)hy << 16);
    ph.y = (unsigned)hz | ((unsigned)hw << 16);
    pl.x = (unsigned)f2b(v.x - b2f(hx)) | ((unsigned)f2b(v.y - b2f(hy)) << 16);
    pl.y = (unsigned)f2b(v.z - b2f(hz)) | ((unsigned)f2b(v.w - b2f(hw)) << 16);
    hi[i] = ph;
    lo[i] = pl;
}

// ---------------- BatchNorm stats from hi/lo split ----------------
__global__ __launch_bounds__(256) void bn_partial_k(const uint2* __restrict__ xhi,
                                                    const uint2* __restrict__ xlo,
                                                    float2* __restrict__ part) {
    int n = blockIdx.y, c = blockIdx.x;
    float s = 0.f, s2 = 0.f;
#pragma unroll
    for (int j = 0; j < 4; ++j) {
        int f = j * 256 + threadIdx.x;
        int bl = f >> 7, t4 = f & 127;
        size_t idx = ((size_t)(c * 8 + bl) * Nn + n) * 128 + t4;
        float4 v = unp2(xhi[idx], xlo[idx]);
        s += v.x + v.y + v.z + v.w;
        s2 += v.x * v.x + v.y * v.y + v.z * v.z + v.w * v.w;
    }
    __shared__ float sh[256], sh2[256];
    sh[threadIdx.x] = s; sh2[threadIdx.x] = s2;
    __syncthreads();
    for (int o = 128; o > 0; o >>= 1) {
        if (threadIdx.x < o) { sh[threadIdx.x] += sh[threadIdx.x + o]; sh2[threadIdx.x] += sh2[threadIdx.x + o]; }
        __syncthreads();
    }
    if (threadIdx.x == 0) part[n * 8 + c] = make_float2(sh[0], sh2[0]);
}

__global__ __launch_bounds__(64) void bn_final_k(const float2* __restrict__ part,
                                                 const float* __restrict__ g,
                                                 const float* __restrict__ be,
                                                 float* __restrict__ bnsc,
                                                 float* __restrict__ bnsh) {
    int n = blockIdx.x, t = threadIdx.x;
    float s = 0.f, s2 = 0.f;
    if (t < 8) { float2 p = part[n * 8 + t]; s = p.x; s2 = p.y; }
    for (int o = 32; o > 0; o >>= 1) { s += __shfl_down(s, o, 64); s2 += __shfl_down(s2, o, 64); }
    if (t == 0) {
        float inv = 1.f / (Bb * Td);
        float mu = s * inv;
        float var = s2 * inv - mu * mu;
        float rs = rsqrtf(var + EPSN);
        float scale = rs * g[n];
        bnsc[n] = scale;
        bnsh[n] = be[n] - mu * scale;
    }
}

// BN apply from hi/lo, write Tx0 bf16 into concat[.,0:512] (row stride 1536)
__global__ __launch_bounds__(256) void bn_apply_cast_k(const uint2* __restrict__ xhi,
                                                       const uint2* __restrict__ xlo,
                                                       const float* __restrict__ sc,
                                                       const float* __restrict__ shf,
                                                       uint2* __restrict__ cat) {
    int i = blockIdx.x * 256 + threadIdx.x;   // uint2 index over BNT/4
    int row = i >> 7, c4 = i & 127;
    int n = row & 255;
    float s = sc[n], h = shf[n];
    float4 v = unp2(xhi[i], xlo[i]);
    v.x = v.x * s + h; v.y = v.y * s + h; v.z = v.z * s + h; v.w = v.w * s + h;
    uint2 p;
    p.x = (unsigned)f2b(v.x) | ((unsigned)f2b(v.y) << 16);
    p.y = (unsigned)f2b(v.z) | ((unsigned)f2b(v.w) << 16);
    cat[(size_t)row * 384 + c4] = p;   // 1536 u16 = 384 uint2 per row
}

// ---------------- top-k radix-select + adjacency; writes bf16 A + dinv ----------------
__global__ __launch_bounds__(256) void topk_sel_k(const float* __restrict__ sc,
                                                  const float* __restrict__ dis,
                                                  u16* __restrict__ bA,
                                                  float* __restrict__ dinv) {
    int row = blockIdx.x;
    int n = row & 255;
    int tid = threadIdx.x;
    int lane = tid & 63, wv = tid >> 6;
    const float* srow = sc + (size_t)row * Nn;
    float v = srow[tid];
    unsigned fu = __float_as_uint(v);
    unsigned key = (fu & 0x80000000u) ? ~fu : (fu | 0x80000000u);
    __shared__ int hist[256];
    __shared__ int cum[256];
    __shared__ unsigned sh_pref;
    __shared__ int sh_rank;
    __shared__ float wsum[4];
    if (tid == 0) { sh_pref = 0u; sh_rank = Nn - NMAXS; }  // 205
    __syncthreads();
#pragma unroll
    for (int shift = 24; shift >= 0; shift -= 8) {
        unsigned mhi = (shift == 24) ? 0u : (0xFFFFFFFFu << (shift + 8));
        unsigned pref = sh_pref;
        int rank = sh_rank;
        hist[tid] = 0;
        __syncthreads();
        if ((key & mhi) == pref) atomicAdd(&hist[(key >> shift) & 255], 1);
        __syncthreads();
        if (tid < 64) {
            int4 h = *(const int4*)&hist[tid * 4];
            int s0 = h.x, s1 = s0 + h.y, s2 = s1 + h.z, s3 = s2 + h.w;
            int t = s3;
#pragma unroll
            for (int o = 1; o < 64; o <<= 1) { int y = __shfl_up(t, o, 64); if (lane >= o) t += y; }
            int excl = t - s3;
            cum[tid * 4]     = excl + s0;
            cum[tid * 4 + 1] = excl + s1;
            cum[tid * 4 + 2] = excl + s2;
            cum[tid * 4 + 3] = excl + s3;
        }
        __syncthreads();
        int below = (tid == 0) ? 0 : cum[tid - 1];
        if (cum[tid] > rank && below <= rank) {
            sh_pref = pref | ((unsigned)tid << shift);
            sh_rank = rank - below;
        }
        __syncthreads();
    }
    unsigned kk = sh_pref;
    float kth = __uint_as_float((kk & 0x80000000u) ? (kk & 0x7FFFFFFFu) : ~kk);
    float as = (v >= kth) ? v : 0.f;
    float a = fmaxf(as + dis[(size_t)n * Nn + tid], 0.f);
    bA[(size_t)row * Nn + tid] = f2b(a);
    float s = a;
#pragma unroll
    for (int o = 32; o > 0; o >>= 1) s += __shfl_down(s, o, 64);
    if (lane == 0) wsum[wv] = s;
    __syncthreads();
    if (tid == 0) dinv[row] = rsqrtf(wsum[0] + wsum[1] + wsum[2] + wsum[3] + EPSD);
}

// ---------------- generalized transpose+cast (+optional per-input-row scale) ----------------
// out[b*obz + (c0+c)*oldr + (r0+tx)] = cast(in[b*ibz + (r0+r)*ildr + c0+tx]) * rs[b*rsz + r0+r]
template <typename SRC>
__global__ __launch_bounds__(256) void tcast_k(const SRC* __restrict__ in,
                                               u16* __restrict__ out,
                                               long long ibz, int ildr,
                                               long long obz, int oldr,
                                               const float* __restrict__ rs, int rsz) {
    __shared__ u16 tile[32][33];
    int b = blockIdx.z;
    int c0 = blockIdx.x * 32, r0 = blockIdx.y * 32;
    int tx = threadIdx.x & 31, ty = threadIdx.x >> 5;
#pragma unroll
    for (int i = 0; i < 4; ++i) {
        int r = ty + i * 8;
        SRC v = in[(size_t)b * ibz + (size_t)(r0 + r) * ildr + c0 + tx];
        float f;
        if constexpr (sizeof(SRC) == 4) f = (float)v;
        else f = b2f((u16)v);
        if (rs) f *= rs[b * rsz + r0 + r];
        tile[r][tx] = f2b(f);
    }
    __syncthreads();
#pragma unroll
    for (int i = 0; i < 4; ++i) {
        int c = ty + i * 8;
        out[(size_t)b * obz + (size_t)(c0 + c) * oldr + (r0 + tx)] = tile[tx][c];
    }
}

// ---------------- bf16 MFMA GEMM, NT, DMA staging ----------------
// v = alpha*acc; RSCALE: v *= rs[row]; SUBPREV: v -= bf16(prev[row*ldprev+col]);
// FINAL: v = relu(v+bias[col]); WF32: C[row*Ncols+col]=v; WBF: Cb[row*ldcb+col]=bf16(v)
template <bool FINAL, bool SUBPREV, bool RSCALE, bool WF32, bool WBF>
__global__ __launch_bounds__(256) void gemm_bf_k(const u16* __restrict__ A,
                                                 const u16* __restrict__ Bt,
                                                 const float* __restrict__ bias,
                                                 const u16* __restrict__ prevb, int ldprev,
                                                 float* __restrict__ C,
                                                 u16* __restrict__ Cb, int ldcb,
                                                 const float* __restrict__ rscale, int rsz,
                                                 float alpha, int Ncols, int K,
                                                 long long sA, long long sB, long long sPrev,
                                                 long long sC, long long sCb) {
    __shared__ u16 As[128 * 32];
    __shared__ u16 Bs[128 * 32];
    int z = blockIdx.z;
    const u16* Ag = A + (size_t)z * sA;
    const u16* Bg = Bt + (size_t)z * sB;
    int br = blockIdx.x * 128, bc = blockIdx.y * 128;
    int tid = threadIdx.x, lane = tid & 63, wave = tid >> 6;
    int wr = (wave >> 1) * 64, wc = (wave & 1) * 64;
    int i0 = wave * 2;
    int rl0 = i0 * 16 + (lane >> 2);
    int rl1 = rl0 + 16;
    int cp = lane & 3;
    int ca0 = (cp ^ swz4(rl0)) * 8;
    int ca1 = (cp ^ swz4(rl1)) * 8;
    const u16* gA0 = Ag + (size_t)(br + rl0) * K + ca0;
    const u16* gA1 = Ag + (size_t)(br + rl1) * K + ca1;
    const u16* gB0 = Bg + (size_t)(bc + rl0) * K + ca0;
    const u16* gB1 = Bg + (size_t)(bc + rl1) * K + ca1;
    u16* lA0 = &As[i0 * 512];
    u16* lA1 = lA0 + 512;
    u16* lB0 = &Bs[i0 * 512];
    u16* lB1 = lB0 + 512;
    f32x4 acc[4][4] = {};
    int fr = lane & 15, fq = lane >> 4;
    for (int k0 = 0; k0 < K; k0 += 32) {
        gload_lds(gA0 + k0, lA0);
        gload_lds(gA1 + k0, lA1);
        gload_lds(gB0 + k0, lB0);
        gload_lds(gB1 + k0, lB1);
        __syncthreads();
        short8 af[4], bf[4];
#pragma unroll
        for (int mi = 0; mi < 4; ++mi) {
            int rr = wr + mi * 16 + fr;
            af[mi] = *(const short8*)&As[rr * 32 + ((fq ^ swz4(rr)) << 3)];
        }
#pragma unroll
        for (int ni = 0; ni < 4; ++ni) {
            int rr = wc + ni * 16 + fr;
            bf[ni] = *(const short8*)&Bs[rr * 32 + ((fq ^ swz4(rr)) << 3)];
        }
#pragma unroll
        for (int mi = 0; mi < 4; ++mi)
#pragma unroll
            for (int ni = 0; ni < 4; ++ni)
                acc[mi][ni] = __builtin_amdgcn_mfma_f32_16x16x32_bf16(af[mi], bf[ni], acc[mi][ni], 0, 0, 0);
        __syncthreads();
    }
    const u16* Pp = SUBPREV ? prevb + (size_t)z * sPrev : nullptr;
    float* Cp = WF32 ? C + (size_t)z * sC : nullptr;
    u16* Cbp = WBF ? Cb + (size_t)z * sCb : nullptr;
    const float* rsp = RSCALE ? rscale + (size_t)z * rsz : nullptr;
#pragma unroll
    for (int mi = 0; mi < 4; ++mi) {
#pragma unroll
        for (int rg = 0; rg < 4; ++rg) {
            int row = br + wr + mi * 16 + fq * 4 + rg;
            float rowsc = RSCALE ? rsp[row] : 1.f;
#pragma unroll
            for (int ni = 0; ni < 4; ++ni) {
                int col = bc + wc + ni * 16 + fr;
                float v = alpha * acc[mi][ni][rg];
                if (RSCALE) v *= rowsc;
                if (SUBPREV) v -= b2f(Pp[(size_t)row * ldprev + col]);
                if (FINAL) v = fmaxf(v + bias[col], 0.f);
                if (WF32) Cp[(size_t)row * Ncols + col] = v;
                if (WBF) Cbp[(size_t)row * ldcb + col] = f2b(v);
            }
        }
    }
}

// ---------------- split-bf16 3-MFMA GEMM (fp32-emulating), NT, DMA staging ----------------
template <bool BIAS, bool WSPLIT, bool WF32>
__global__ __launch_bounds__(256) void gemm_bf3_k(const u16* __restrict__ Ahi,
                                                  const u16* __restrict__ Alo,
                                                  const u16* __restrict__ Bhi,
                                                  const u16* __restrict__ Blo,
                                                  const float* __restrict__ bias,
                                                  float* __restrict__ C,
                                                  u16* __restrict__ Chi,
                                                  u16* __restrict__ Clo,
                                                  int Ncols, int K,
                                                  long long sA, long long sB, long long sC) {
    __shared__ u16 Ash[128 * 32];
    __shared__ u16 Asl[128 * 32];
    __shared__ u16 Bsh[128 * 32];
    __shared__ u16 Bsl[128 * 32];
    int z = blockIdx.z;
    const u16* Agh = Ahi + (size_t)z * sA;
    const u16* Agl = Alo + (size_t)z * sA;
    const u16* Bgh = Bhi + (size_t)z * sB;
    const u16* Bgl = Blo + (size_t)z * sB;
    int br = blockIdx.x * 128, bc = blockIdx.y * 128;
    int tid = threadIdx.x, lane = tid & 63, wave = tid >> 6;
    int wr = (wave >> 1) * 64, wc = (wave & 1) * 64;
    int i0 = wave * 2;
    int rl0 = i0 * 16 + (lane >> 2);
    int rl1 = rl0 + 16;
    int cp = lane & 3;
    int ca0 = (cp ^ swz4(rl0)) * 8;
    int ca1 = (cp ^ swz4(rl1)) * 8;
    size_t oA0 = (size_t)(br + rl0) * K + ca0;
    size_t oA1 = (size_t)(br + rl1) * K + ca1;
    size_t oB0 = (size_t)(bc + rl0) * K + ca0;
    size_t oB1 = (size_t)(bc + rl1) * K + ca1;
    u16* lA0 = &Ash[i0 * 512]; u16* lA1 = lA0 + 512;
    u16* lAl0 = &Asl[i0 * 512]; u16* lAl1 = lAl0 + 512;
    u16* lB0 = &Bsh[i0 * 512]; u16* lB1 = lB0 + 512;
    u16* lBl0 = &Bsl[i0 * 512]; u16* lBl1 = lBl0 + 512;
    f32x4 acc[4][4] = {};
    int fr = lane & 15, fq = lane >> 4;
    for (int k0 = 0; k0 < K; k0 += 32) {
        gload_lds(Agh + oA0 + k0, lA0);
        gload_lds(Agh + oA1 + k0, lA1);
        gload_lds(Agl + oA0 + k0, lAl0);
        gload_lds(Agl + oA1 + k0, lAl1);
        gload_lds(Bgh + oB0 + k0, lB0);
        gload_lds(Bgh + oB1 + k0, lB1);
        gload_lds(Bgl + oB0 + k0, lBl0);
        gload_lds(Bgl + oB1 + k0, lBl1);
        __syncthreads();
        short8 afh[4], afl[4], bfh[4], bfl[4];
#pragma unroll
        for (int mi = 0; mi < 4; ++mi) {
            int rr = wr + mi * 16 + fr;
            int off = rr * 32 + ((fq ^ swz4(rr)) << 3);
            afh[mi] = *(const short8*)&Ash[off];
            afl[mi] = *(const short8*)&Asl[off];
        }
#pragma unroll
        for (int ni = 0; ni < 4; ++ni) {
            int rr = wc + ni * 16 + fr;
            int off = rr * 32 + ((fq ^ swz4(rr)) << 3);
            bfh[ni] = *(const short8*)&Bsh[off];
            bfl[ni] = *(const short8*)&Bsl[off];
        }
#pragma unroll
        for (int mi = 0; mi < 4; ++mi)
#pragma unroll
            for (int ni = 0; ni < 4; ++ni) {
                acc[mi][ni] = __builtin_amdgcn_mfma_f32_16x16x32_bf16(afh[mi], bfh[ni], acc[mi][ni], 0, 0, 0);
                acc[mi][ni] = __builtin_amdgcn_mfma_f32_16x16x32_bf16(afh[mi], bfl[ni], acc[mi][ni], 0, 0, 0);
                acc[mi][ni] = __builtin_amdgcn_mfma_f32_16x16x32_bf16(afl[mi], bfh[ni], acc[mi][ni], 0, 0, 0);
            }
        __syncthreads();
    }
    float* Cp = WF32 ? C + (size_t)z * sC : nullptr;
    u16* Chp = WSPLIT ? Chi + (size_t)z * sC : nullptr;
    u16* Clp = WSPLIT ? Clo + (size_t)z * sC : nullptr;
#pragma unroll
    for (int mi = 0; mi < 4; ++mi) {
#pragma unroll
        for (int rg = 0; rg < 4; ++rg) {
            int row = br + wr + mi * 16 + fq * 4 + rg;
            size_t rb = (size_t)row * Ncols;
#pragma unroll
            for (int ni = 0; ni < 4; ++ni) {
                int col = bc + wc + ni * 16 + fr;
                float v = acc[mi][ni][rg];
                if (BIAS) v += bias[col];
                if (WF32) Cp[rb + col] = v;
                if (WSPLIT) {
                    u16 h = f2b(v);
                    Chp[rb + col] = h;
                    Clp[rb + col] = f2b(v - b2f(h));
                }
            }
        }
    }
}

extern "C" void kernel_launch(void* const* d_in, const int* in_sizes, int n_in,
                              void* d_out, int out_size, void* d_ws, size_t ws_size,
                              hipStream_t stream) {
    const float* x      = (const float*)d_in[0];
    const float* dis    = (const float*)d_in[1];
    const float* ln_w   = (const float*)d_in[2];
    const float* ln_b   = (const float*)d_in[3];
    const float* bn_g   = (const float*)d_in[4];
    const float* bn_b   = (const float*)d_in[5];
    const float* li_w   = (const float*)d_in[6];
    const float* li_b   = (const float*)d_in[7];
    const float* cheb_w = (const float*)d_in[8];
    const float* cheb_b = (const float*)d_in[9];
    float* out = (float*)d_out;

    const size_t BNT = (size_t)Bb * Nn * Td;   // 8388608
    const size_t BNN = (size_t)Bb * Nn * Nn;   // 4194304
    float* ws = (float*)d_ws;
    // [0, BNT): xhi/xlo (u16), live step1 -> bn_apply
    u16* xhi = (u16*)ws;
    u16* xlo = xhi + BNT;
    // [BNT, 2BNT): xphi/xplo (u16), live steps 2-3; then concat spans [BNT, 2BNT+BNN)
    u16* xphi = (u16*)(ws + BNT);
    u16* xplo = xphi + BNT;
    u16* cat  = (u16*)(ws + BNT);               // [16384][1536] bf16 = BNT+BNN floats
    // [2BNT, 2BNT+BNN): scores fp32 (dead after topk; overwritten by concat tail)
    float* sc = ws + 2 * BNT;
    float* p4 = ws + 2 * BNT + BNN;
    u16* bufB = (u16*)p4;                        // BNT u16 (Tx^T scratch)
    float* p5 = p4 + BNT / 2;
    u16* bA = (u16*)p5;                          // BNN u16
    float* p6 = p5 + BNN / 2;
    u16* bWc = (u16*)p6;                         // 512*1536 u16
    float* p7 = p6 + (512 * 1536) / 2;
    u16* liwhi = (u16*)p7;                       // 512*512 u16 x2
    u16* liwlo = liwhi + 512 * 512;
    float* p8 = p7 + 262144;
    float* lnst = p8;                            // 128
    float* dinv = p8 + 128;                      // 16384
    float* bnsc = dinv + 16384;                  // 256
    float* bnsh = bnsc + 256;                    // 256
    float2* part = (float2*)(bnsh + 256);        // 4096 floats

    // 1. LayerNorm -> hi/lo split only
    hipLaunchKernelGGL(ln_partial_k, dim3(32, Bb), dim3(256), 0, stream, (const float4*)x, part);
    hipLaunchKernelGGL(ln_final_k, dim3(Bb), dim3(64), 0, stream, part, lnst);
    hipLaunchKernelGGL(ln_apply_split_k, dim3(BNT / 1024), dim3(256), 0, stream,
                       (const float4*)x, (const float4*)ln_w, (const float4*)ln_b, lnst,
                       (uint2*)xhi, (uint2*)xlo);
    // 1b. param prep: li_w split; cheb_w^T -> bWc [f][3*512] (col offset per k)
    hipLaunchKernelGGL(cast_split_k, dim3((Td * Td / 4 + 255) / 256), dim3(256), 0, stream,
                       (const float4*)li_w, (uint2*)liwhi, (uint2*)liwlo, Td * Td / 4);
    hipLaunchKernelGGL((tcast_k<float>), dim3(16, 16, 3), dim3(256), 0, stream,
                       cheb_w, bWc, (long long)Td * Td, Td, 512LL, 1536,
                       (const float*)nullptr, 0);
    // 2. xp = x_ln @ li_w^T + li_b  (split-bf16 3-MFMA -> hi/lo)
    hipLaunchKernelGGL((gemm_bf3_k<true, true, false>), dim3(Bb * Nn / 128, Td / 128, 1), dim3(256), 0, stream,
                       xhi, xlo, liwhi, liwlo, li_b, (float*)nullptr, xphi, xplo,
                       Td, Td, 0LL, 0LL, 0LL);
    // 3. scores[b] = xp[b] @ xp[b]^T  (split-bf16 -> fp32)
    hipLaunchKernelGGL((gemm_bf3_k<false, false, true>), dim3(Nn / 128, Nn / 128, Bb), dim3(256), 0, stream,
                       xphi, xplo, xphi, xplo, (const float*)nullptr, sc, (u16*)nullptr, (u16*)nullptr,
                       Nn, Td, (long long)Nn * Td, (long long)Nn * Td, (long long)Nn * Nn);
    // 4. top-k radix-select; A = relu(A_s + dis) -> bf16 bA; dinv
    hipLaunchKernelGGL(topk_sel_k, dim3(Bb * Nn), dim3(256), 0, stream, sc, dis, bA, dinv);
    // 5. BatchNorm: stats from hi/lo; apply -> concat cols [0,512)  (Tx0)
    hipLaunchKernelGGL(bn_partial_k, dim3(8, Nn), dim3(256), 0, stream,
                       (const uint2*)xhi, (const uint2*)xlo, part);
    hipLaunchKernelGGL(bn_final_k, dim3(Nn), dim3(64), 0, stream, part, bn_g, bn_b, bnsc, bnsh);
    hipLaunchKernelGGL(bn_apply_cast_k, dim3(BNT / 1024), dim3(256), 0, stream,
                       (const uint2*)xhi, (const uint2*)xlo, bnsc, bnsh, (uint2*)cat);
    // 6. bufB[b][t][m] = Tx0[b][m][t] * d[b][m]
    hipLaunchKernelGGL((tcast_k<u16>), dim3(16, 8, Bb), dim3(256), 0, stream,
                       cat, bufB, (long long)Nn * 1536, 1536, (long long)Td * Nn, Nn,
                       dinv, Nn);
    // 7. Tx1 = d*(A @ (d*Tx0)) -> concat cols [512,1024)
    hipLaunchKernelGGL((gemm_bf_k<false, false, true, false, true>), dim3(Nn / 128, Td / 128, Bb), dim3(256), 0, stream,
                       bA, bufB, (const float*)nullptr, (const u16*)nullptr, 0,
                       (float*)nullptr, cat + 512, 1536, dinv, Nn,
                       1.0f, Td, Nn, (long long)Nn * Nn, (long long)Td * Nn, 0LL, 0LL,
                       (long long)Nn * 1536);
    // 8. bufB[b][t][m] = Tx1[b][m][t] * d[b][m]
    hipLaunchKernelGGL((tcast_k<u16>), dim3(16, 8, Bb), dim3(256), 0, stream,
                       cat + 512, bufB, (long long)Nn * 1536, 1536, (long long)Td * Nn, Nn,
                       dinv, Nn);
    // 9. Tx2 = 2*d*(A @ (d*Tx1)) - Tx0 -> concat cols [1024,1536)
    hipLaunchKernelGGL((gemm_bf_k<false, true, true, false, true>), dim3(Nn / 128, Td / 128, Bb), dim3(256), 0, stream,
                       bA, bufB, (const float*)nullptr, cat, 1536,
                       (float*)nullptr, cat + 1024, 1536, dinv, Nn,
                       2.0f, Td, Nn, (long long)Nn * Nn, (long long)Td * Nn, (long long)Nn * 1536, 0LL,
                       (long long)Nn * 1536);
    // 10. out = relu([Tx0|Tx1|Tx2] @ [W0;W1;W2]^T + cheb_b)   (K=1536)
    hipLaunchKernelGGL((gemm_bf_k<true, false, false, true, false>), dim3(Bb * Nn / 128, Td / 128, 1), dim3(256), 0, stream,
                       cat, bWc, cheb_b, (const u16*)nullptr, 0,
                       out, (u16*)nullptr, 0, (const float*)nullptr, 0,
                       1.0f, Td, 1536, 0LL, 0LL, 0LL, 0LL, 0LL);
}

// Round 8
// 307.419 us; speedup vs baseline: 3.7737x; 1.0825x over previous
//
#include <hip/hip_runtime.h>
#include <cstddef>

static constexpr int Bb = 64;     // batch
static constexpr int Nn = 256;    // nodes
static constexpr int Td = 512;    // time dim
static constexpr int NMAXS = 51;  // 256 // 5
static constexpr float EPSN = 1e-5f;
static constexpr float EPSD = 1e-10f;

typedef unsigned short u16;
typedef __attribute__((ext_vector_type(8))) short short8;
typedef __attribute__((ext_vector_type(4))) float f32x4;

__device__ __forceinline__ u16 f2b(float f) {
    unsigned u = __float_as_uint(f);
    return (u16)((u + 0x7fffu + ((u >> 16) & 1u)) >> 16);
}
__device__ __forceinline__ float b2f(u16 h) {
    return __uint_as_float(((unsigned)h) << 16);
}
__device__ __forceinline__ float4 unp2(uint2 h, uint2 l) {
    float4 r;
    r.x = b2f((u16)h.x) + b2f((u16)l.x);
    r.y = b2f((u16)(h.x >> 16)) + b2f((u16)(l.x >> 16));
    r.z = b2f((u16)h.y) + b2f((u16)l.y);
    r.w = b2f((u16)(h.y >> 16)) + b2f((u16)(l.y >> 16));
    return r;
}

// async global->LDS DMA, 16B/lane. LDS dest = wave-uniform base + lane*16.
__device__ __forceinline__ void gload_lds(const u16* g, u16* l) {
    __builtin_amdgcn_global_load_lds(
        (const __attribute__((address_space(1))) unsigned int*)g,
        (__attribute__((address_space(3))) unsigned int*)l, 16, 0, 0);
}
__device__ __forceinline__ int swz4(int r) { return (r ^ (r >> 2)) & 3; }

// ---------------- LayerNorm stats stage A ----------------
__global__ __launch_bounds__(256) void ln_partial_k(const float4* __restrict__ x,
                                                    float2* __restrict__ part) {
    int b = blockIdx.y, c = blockIdx.x;
    int base = b * 32768 + c * 1024;
    float s = 0.f, s2 = 0.f;
#pragma unroll
    for (int j = 0; j < 4; ++j) {
        float4 v = x[base + j * 256 + threadIdx.x];
        s += v.x + v.y + v.z + v.w;
        s2 += v.x * v.x + v.y * v.y + v.z * v.z + v.w * v.w;
    }
    __shared__ float sh[256], sh2[256];
    sh[threadIdx.x] = s; sh2[threadIdx.x] = s2;
    __syncthreads();
    for (int o = 128; o > 0; o >>= 1) {
        if (threadIdx.x < o) { sh[threadIdx.x] += sh[threadIdx.x + o]; sh2[threadIdx.x] += sh2[threadIdx.x + o]; }
        __syncthreads();
    }
    if (threadIdx.x == 0) part[b * 32 + c] = make_float2(sh[0], sh2[0]);
}

// LN apply (finalize fused via shfl over 32 partials): hi/lo bf16 split out
__global__ __launch_bounds__(256) void ln_apply_split_k(const float4* __restrict__ x,
                                                        const float4* __restrict__ w,
                                                        const float4* __restrict__ bia,
                                                        const float2* __restrict__ part,
                                                        uint2* __restrict__ xhi,
                                                        uint2* __restrict__ xlo) {
    int i = blockIdx.x * 256 + threadIdx.x;
    int r = i & ((Nn * Td / 4) - 1);
    int b = i >> 15;
    float2 p = part[b * 32 + (threadIdx.x & 31)];
    float s = p.x, s2 = p.y;
#pragma unroll
    for (int o = 16; o > 0; o >>= 1) { s += __shfl_xor(s, o, 32); s2 += __shfl_xor(s2, o, 32); }
    float inv = 1.f / (Nn * Td);
    float mu = s * inv;
    float var = s2 * inv - mu * mu;
    float rs = rsqrtf(var + EPSN);
    float4 xv = x[i], wv = w[r], bv = bia[r];
    float4 o;
    o.x = (xv.x - mu) * rs * wv.x + bv.x;
    o.y = (xv.y - mu) * rs * wv.y + bv.y;
    o.z = (xv.z - mu) * rs * wv.z + bv.z;
    o.w = (xv.w - mu) * rs * wv.w + bv.w;
    u16 hx = f2b(o.x), hy = f2b(o.y), hz = f2b(o.z), hw = f2b(o.w);
    uint2 ph, pl;
    ph.x = (unsigned)hx | ((unsigned)hy << 16);
    ph.y = (unsigned)hz | ((unsigned)hw << 16);
    pl.x = (unsigned)f2b(o.x - b2f(hx)) | ((unsigned)f2b(o.y - b2f(hy)) << 16);
    pl.y = (unsigned)f2b(o.z - b2f(hz)) | ((unsigned)f2b(o.w - b2f(hw)) << 16);
    xhi[i] = ph;
    xlo[i] = pl;
}

// ---------------- param prep: cheb_w^T -> bWc (z<3) ; li_w hi/lo split (z==3) ----------------
__global__ __launch_bounds__(256) void param_prep_k(const float* __restrict__ cheb_w,
                                                    u16* __restrict__ bWc,
                                                    const float* __restrict__ li_w,
                                                    u16* __restrict__ liwhi,
                                                    u16* __restrict__ liwlo) {
    int z = blockIdx.z;
    int c0 = blockIdx.x * 32, r0 = blockIdx.y * 32;
    int tx = threadIdx.x & 31, ty = threadIdx.x >> 5;
    if (z < 3) {
        __shared__ u16 tile[32][33];
        const float* ip = cheb_w + (size_t)z * Td * Td;
#pragma unroll
        for (int i = 0; i < 4; ++i) {
            int r = ty + i * 8;
            tile[r][tx] = f2b(ip[(size_t)(r0 + r) * Td + c0 + tx]);
        }
        __syncthreads();
#pragma unroll
        for (int i = 0; i < 4; ++i) {
            int c = ty + i * 8;
            bWc[(size_t)(c0 + c) * 1536 + z * 512 + (r0 + tx)] = tile[tx][c];
        }
    } else {
#pragma unroll
        for (int i = 0; i < 4; ++i) {
            int r = r0 + ty + i * 8;
            size_t idx = (size_t)r * Td + c0 + tx;
            float v = li_w[idx];
            u16 h = f2b(v);
            liwhi[idx] = h;
            liwlo[idx] = f2b(v - b2f(h));
        }
    }
}

// ---------------- BatchNorm stats stage A (from hi/lo split) ----------------
__global__ __launch_bounds__(256) void bn_partial_k(const uint2* __restrict__ xhi,
                                                    const uint2* __restrict__ xlo,
                                                    float2* __restrict__ part) {
    int n = blockIdx.y, c = blockIdx.x;
    float s = 0.f, s2 = 0.f;
#pragma unroll
    for (int j = 0; j < 4; ++j) {
        int f = j * 256 + threadIdx.x;
        int bl = f >> 7, t4 = f & 127;
        size_t idx = ((size_t)(c * 8 + bl) * Nn + n) * 128 + t4;
        float4 v = unp2(xhi[idx], xlo[idx]);
        s += v.x + v.y + v.z + v.w;
        s2 += v.x * v.x + v.y * v.y + v.z * v.z + v.w * v.w;
    }
    __shared__ float sh[256], sh2[256];
    sh[threadIdx.x] = s; sh2[threadIdx.x] = s2;
    __syncthreads();
    for (int o = 128; o > 0; o >>= 1) {
        if (threadIdx.x < o) { sh[threadIdx.x] += sh[threadIdx.x + o]; sh2[threadIdx.x] += sh2[threadIdx.x + o]; }
        __syncthreads();
    }
    if (threadIdx.x == 0) part[n * 8 + c] = make_float2(sh[0], sh2[0]);
}

// BN apply (finalize fused via shfl over 8 partials); writes Tx0 bf16 into cat[.,0:512]
__global__ __launch_bounds__(256) void bn_apply_cast_k(const uint2* __restrict__ xhi,
                                                       const uint2* __restrict__ xlo,
                                                       const float2* __restrict__ part,
                                                       const float* __restrict__ g,
                                                       const float* __restrict__ be,
                                                       uint2* __restrict__ cat) {
    int i = blockIdx.x * 256 + threadIdx.x;   // uint2 index over BNT/4
    int row = i >> 7, c4 = i & 127;
    int n = row & 255;
    float2 p = part[n * 8 + (threadIdx.x & 7)];
    float s = p.x, s2 = p.y;
#pragma unroll
    for (int o = 4; o > 0; o >>= 1) { s += __shfl_xor(s, o, 8); s2 += __shfl_xor(s2, o, 8); }
    float inv = 1.f / (Bb * Td);
    float mu = s * inv;
    float var = s2 * inv - mu * mu;
    float rs = rsqrtf(var + EPSN);
    float scale = rs * g[n];
    float shift = be[n] - mu * scale;
    float4 v = unp2(xhi[i], xlo[i]);
    v.x = v.x * scale + shift; v.y = v.y * scale + shift;
    v.z = v.z * scale + shift; v.w = v.w * scale + shift;
    uint2 o2;
    o2.x = (unsigned)f2b(v.x) | ((unsigned)f2b(v.y) << 16);
    o2.y = (unsigned)f2b(v.z) | ((unsigned)f2b(v.w) << 16);
    cat[(size_t)row * 384 + c4] = o2;   // 1536 u16 = 384 uint2 per row
}

// ---------------- top-k radix-select + adjacency; writes bf16 A + dinv ----------------
__global__ __launch_bounds__(256) void topk_sel_k(const float* __restrict__ sc,
                                                  const float* __restrict__ dis,
                                                  u16* __restrict__ bA,
                                                  float* __restrict__ dinv) {
    int row = blockIdx.x;
    int n = row & 255;
    int tid = threadIdx.x;
    int lane = tid & 63, wv = tid >> 6;
    const float* srow = sc + (size_t)row * Nn;
    float v = srow[tid];
    unsigned fu = __float_as_uint(v);
    unsigned key = (fu & 0x80000000u) ? ~fu : (fu | 0x80000000u);
    __shared__ int hist[256];
    __shared__ int cum[256];
    __shared__ unsigned sh_pref;
    __shared__ int sh_rank;
    __shared__ float wsum[4];
    if (tid == 0) { sh_pref = 0u; sh_rank = Nn - NMAXS; }  // 205
    __syncthreads();
#pragma unroll
    for (int shift = 24; shift >= 0; shift -= 8) {
        unsigned mhi = (shift == 24) ? 0u : (0xFFFFFFFFu << (shift + 8));
        unsigned pref = sh_pref;
        int rank = sh_rank;
        hist[tid] = 0;
        __syncthreads();
        if ((key & mhi) == pref) atomicAdd(&hist[(key >> shift) & 255], 1);
        __syncthreads();
        if (tid < 64) {
            int4 h = *(const int4*)&hist[tid * 4];
            int s0 = h.x, s1 = s0 + h.y, s2 = s1 + h.z, s3 = s2 + h.w;
            int t = s3;
#pragma unroll
            for (int o = 1; o < 64; o <<= 1) { int y = __shfl_up(t, o, 64); if (lane >= o) t += y; }
            int excl = t - s3;
            cum[tid * 4]     = excl + s0;
            cum[tid * 4 + 1] = excl + s1;
            cum[tid * 4 + 2] = excl + s2;
            cum[tid * 4 + 3] = excl + s3;
        }
        __syncthreads();
        int below = (tid == 0) ? 0 : cum[tid - 1];
        if (cum[tid] > rank && below <= rank) {
            sh_pref = pref | ((unsigned)tid << shift);
            sh_rank = rank - below;
        }
        __syncthreads();
    }
    unsigned kk = sh_pref;
    float kth = __uint_as_float((kk & 0x80000000u) ? (kk & 0x7FFFFFFFu) : ~kk);
    float as = (v >= kth) ? v : 0.f;
    float a = fmaxf(as + dis[(size_t)n * Nn + tid], 0.f);
    bA[(size_t)row * Nn + tid] = f2b(a);
    float s = a;
#pragma unroll
    for (int o = 32; o > 0; o >>= 1) s += __shfl_down(s, o, 64);
    if (lane == 0) wsum[wv] = s;
    __syncthreads();
    if (tid == 0) dinv[row] = rsqrtf(wsum[0] + wsum[1] + wsum[2] + wsum[3] + EPSD);
}

// ---------------- transpose u16 (+optional per-input-row scale) ----------------
// out[b*obz + (c0+c)*oldr + (r0+tx)] = in[b*ibz + (r0+r)*ildr + c0+tx] * rs[b*rsz + r0+r]
__global__ __launch_bounds__(256) void tscale_k(const u16* __restrict__ in,
                                                u16* __restrict__ out,
                                                long long ibz, int ildr,
                                                long long obz, int oldr,
                                                const float* __restrict__ rs, int rsz) {
    __shared__ u16 tile[32][33];
    int b = blockIdx.z;
    int c0 = blockIdx.x * 32, r0 = blockIdx.y * 32;
    int tx = threadIdx.x & 31, ty = threadIdx.x >> 5;
#pragma unroll
    for (int i = 0; i < 4; ++i) {
        int r = ty + i * 8;
        float f = b2f(in[(size_t)b * ibz + (size_t)(r0 + r) * ildr + c0 + tx]);
        f *= rs[b * rsz + r0 + r];
        tile[r][tx] = f2b(f);
    }
    __syncthreads();
#pragma unroll
    for (int i = 0; i < 4; ++i) {
        int c = ty + i * 8;
        out[(size_t)b * obz + (size_t)(c0 + c) * oldr + (r0 + tx)] = tile[tx][c];
    }
}

// ---------------- bf16 MFMA GEMM, NT, DMA staging, BK=64 ----------------
template <bool FINAL, bool SUBPREV, bool RSCALE, bool WF32, bool WBF>
__global__ __launch_bounds__(256) void gemm_bf_k(const u16* __restrict__ A,
                                                 const u16* __restrict__ Bt,
                                                 const float* __restrict__ bias,
                                                 const u16* __restrict__ prevb, int ldprev,
                                                 float* __restrict__ C,
                                                 u16* __restrict__ Cb, int ldcb,
                                                 const float* __restrict__ rscale, int rsz,
                                                 float alpha, int Ncols, int K,
                                                 long long sA, long long sB, long long sPrev,
                                                 long long sC, long long sCb) {
    __shared__ u16 As[2][128 * 32];
    __shared__ u16 Bs[2][128 * 32];
    int z = blockIdx.z;
    const u16* Ag = A + (size_t)z * sA;
    const u16* Bg = Bt + (size_t)z * sB;
    int br = blockIdx.x * 128, bc = blockIdx.y * 128;
    int tid = threadIdx.x, lane = tid & 63, wave = tid >> 6;
    int wr = (wave >> 1) * 64, wc = (wave & 1) * 64;
    int i0 = wave * 2;
    int rl0 = i0 * 16 + (lane >> 2);
    int rl1 = rl0 + 16;
    int cp = lane & 3;
    int ca0 = (cp ^ swz4(rl0)) * 8;
    int ca1 = (cp ^ swz4(rl1)) * 8;
    const u16* gA0 = Ag + (size_t)(br + rl0) * K + ca0;
    const u16* gA1 = Ag + (size_t)(br + rl1) * K + ca1;
    const u16* gB0 = Bg + (size_t)(bc + rl0) * K + ca0;
    const u16* gB1 = Bg + (size_t)(bc + rl1) * K + ca1;
    f32x4 acc[4][4] = {};
    int fr = lane & 15, fq = lane >> 4;
    for (int k0 = 0; k0 < K; k0 += 64) {
#pragma unroll
        for (int h = 0; h < 2; ++h) {
            int kk = k0 + h * 32;
            gload_lds(gA0 + kk, &As[h][i0 * 512]);
            gload_lds(gA1 + kk, &As[h][i0 * 512 + 512]);
            gload_lds(gB0 + kk, &Bs[h][i0 * 512]);
            gload_lds(gB1 + kk, &Bs[h][i0 * 512 + 512]);
        }
        __syncthreads();
#pragma unroll
        for (int h = 0; h < 2; ++h) {
            short8 af[4], bf[4];
#pragma unroll
            for (int mi = 0; mi < 4; ++mi) {
                int rr = wr + mi * 16 + fr;
                af[mi] = *(const short8*)&As[h][rr * 32 + ((fq ^ swz4(rr)) << 3)];
            }
#pragma unroll
            for (int ni = 0; ni < 4; ++ni) {
                int rr = wc + ni * 16 + fr;
                bf[ni] = *(const short8*)&Bs[h][rr * 32 + ((fq ^ swz4(rr)) << 3)];
            }
#pragma unroll
            for (int mi = 0; mi < 4; ++mi)
#pragma unroll
                for (int ni = 0; ni < 4; ++ni)
                    acc[mi][ni] = __builtin_amdgcn_mfma_f32_16x16x32_bf16(af[mi], bf[ni], acc[mi][ni], 0, 0, 0);
        }
        __syncthreads();
    }
    const u16* Pp = SUBPREV ? prevb + (size_t)z * sPrev : nullptr;
    float* Cp = WF32 ? C + (size_t)z * sC : nullptr;
    u16* Cbp = WBF ? Cb + (size_t)z * sCb : nullptr;
    const float* rsp = RSCALE ? rscale + (size_t)z * rsz : nullptr;
#pragma unroll
    for (int mi = 0; mi < 4; ++mi) {
#pragma unroll
        for (int rg = 0; rg < 4; ++rg) {
            int row = br + wr + mi * 16 + fq * 4 + rg;
            float rowsc = RSCALE ? rsp[row] : 1.f;
#pragma unroll
            for (int ni = 0; ni < 4; ++ni) {
                int col = bc + wc + ni * 16 + fr;
                float v = alpha * acc[mi][ni][rg];
                if (RSCALE) v *= rowsc;
                if (SUBPREV) v -= b2f(Pp[(size_t)row * ldprev + col]);
                if (FINAL) v = fmaxf(v + bias[col], 0.f);
                if (WF32) Cp[(size_t)row * Ncols + col] = v;
                if (WBF) Cbp[(size_t)row * ldcb + col] = f2b(v);
            }
        }
    }
}

// ---------------- split-bf16 3-MFMA GEMM (fp32-emulating), NT, DMA, BK=64 ----------------
template <bool BIAS, bool WSPLIT, bool WF32>
__global__ __launch_bounds__(256) void gemm_bf3_k(const u16* __restrict__ Ahi,
                                                  const u16* __restrict__ Alo,
                                                  const u16* __restrict__ Bhi,
                                                  const u16* __restrict__ Blo,
                                                  const float* __restrict__ bias,
                                                  float* __restrict__ C,
                                                  u16* __restrict__ Chi,
                                                  u16* __restrict__ Clo,
                                                  int Ncols, int K,
                                                  long long sA, long long sB, long long sC) {
    __shared__ u16 Ash[2][128 * 32];
    __shared__ u16 Asl[2][128 * 32];
    __shared__ u16 Bsh[2][128 * 32];
    __shared__ u16 Bsl[2][128 * 32];
    int z = blockIdx.z;
    const u16* Agh = Ahi + (size_t)z * sA;
    const u16* Agl = Alo + (size_t)z * sA;
    const u16* Bgh = Bhi + (size_t)z * sB;
    const u16* Bgl = Blo + (size_t)z * sB;
    int br = blockIdx.x * 128, bc = blockIdx.y * 128;
    int tid = threadIdx.x, lane = tid & 63, wave = tid >> 6;
    int wr = (wave >> 1) * 64, wc = (wave & 1) * 64;
    int i0 = wave * 2;
    int rl0 = i0 * 16 + (lane >> 2);
    int rl1 = rl0 + 16;
    int cp = lane & 3;
    int ca0 = (cp ^ swz4(rl0)) * 8;
    int ca1 = (cp ^ swz4(rl1)) * 8;
    size_t oA0 = (size_t)(br + rl0) * K + ca0;
    size_t oA1 = (size_t)(br + rl1) * K + ca1;
    size_t oB0 = (size_t)(bc + rl0) * K + ca0;
    size_t oB1 = (size_t)(bc + rl1) * K + ca1;
    f32x4 acc[4][4] = {};
    int fr = lane & 15, fq = lane >> 4;
    for (int k0 = 0; k0 < K; k0 += 64) {
#pragma unroll
        for (int h = 0; h < 2; ++h) {
            int kk = k0 + h * 32;
            gload_lds(Agh + oA0 + kk, &Ash[h][i0 * 512]);
            gload_lds(Agh + oA1 + kk, &Ash[h][i0 * 512 + 512]);
            gload_lds(Agl + oA0 + kk, &Asl[h][i0 * 512]);
            gload_lds(Agl + oA1 + kk, &Asl[h][i0 * 512 + 512]);
            gload_lds(Bgh + oB0 + kk, &Bsh[h][i0 * 512]);
            gload_lds(Bgh + oB1 + kk, &Bsh[h][i0 * 512 + 512]);
            gload_lds(Bgl + oB0 + kk, &Bsl[h][i0 * 512]);
            gload_lds(Bgl + oB1 + kk, &Bsl[h][i0 * 512 + 512]);
        }
        __syncthreads();
#pragma unroll
        for (int h = 0; h < 2; ++h) {
            short8 afh[4], afl[4], bfh[4], bfl[4];
#pragma unroll
            for (int mi = 0; mi < 4; ++mi) {
                int rr = wr + mi * 16 + fr;
                int off = rr * 32 + ((fq ^ swz4(rr)) << 3);
                afh[mi] = *(const short8*)&Ash[h][off];
                afl[mi] = *(const short8*)&Asl[h][off];
            }
#pragma unroll
            for (int ni = 0; ni < 4; ++ni) {
                int rr = wc + ni * 16 + fr;
                int off = rr * 32 + ((fq ^ swz4(rr)) << 3);
                bfh[ni] = *(const short8*)&Bsh[h][off];
                bfl[ni] = *(const short8*)&Bsl[h][off];
            }
#pragma unroll
            for (int mi = 0; mi < 4; ++mi)
#pragma unroll
                for (int ni = 0; ni < 4; ++ni) {
                    acc[mi][ni] = __builtin_amdgcn_mfma_f32_16x16x32_bf16(afh[mi], bfh[ni], acc[mi][ni], 0, 0, 0);
                    acc[mi][ni] = __builtin_amdgcn_mfma_f32_16x16x32_bf16(afh[mi], bfl[ni], acc[mi][ni], 0, 0, 0);
                    acc[mi][ni] = __builtin_amdgcn_mfma_f32_16x16x32_bf16(afl[mi], bfh[ni], acc[mi][ni], 0, 0, 0);
                }
        }
        __syncthreads();
    }
    float* Cp = WF32 ? C + (size_t)z * sC : nullptr;
    u16* Chp = WSPLIT ? Chi + (size_t)z * sC : nullptr;
    u16* Clp = WSPLIT ? Clo + (size_t)z * sC : nullptr;
#pragma unroll
    for (int mi = 0; mi < 4; ++mi) {
#pragma unroll
        for (int rg = 0; rg < 4; ++rg) {
            int row = br + wr + mi * 16 + fq * 4 + rg;
            size_t rb = (size_t)row * Ncols;
#pragma unroll
            for (int ni = 0; ni < 4; ++ni) {
                int col = bc + wc + ni * 16 + fr;
                float v = acc[mi][ni][rg];
                if (BIAS) v += bias[col];
                if (WF32) Cp[rb + col] = v;
                if (WSPLIT) {
                    u16 h = f2b(v);
                    Chp[rb + col] = h;
                    Clp[rb + col] = f2b(v - b2f(h));
                }
            }
        }
    }
}

extern "C" void kernel_launch(void* const* d_in, const int* in_sizes, int n_in,
                              void* d_out, int out_size, void* d_ws, size_t ws_size,
                              hipStream_t stream) {
    const float* x      = (const float*)d_in[0];
    const float* dis    = (const float*)d_in[1];
    const float* ln_w   = (const float*)d_in[2];
    const float* ln_b   = (const float*)d_in[3];
    const float* bn_g   = (const float*)d_in[4];
    const float* bn_b   = (const float*)d_in[5];
    const float* li_w   = (const float*)d_in[6];
    const float* li_b   = (const float*)d_in[7];
    const float* cheb_w = (const float*)d_in[8];
    const float* cheb_b = (const float*)d_in[9];
    float* out = (float*)d_out;

    const size_t BNT = (size_t)Bb * Nn * Td;   // 8388608
    const size_t BNN = (size_t)Bb * Nn * Nn;   // 4194304
    float* ws = (float*)d_ws;
    // [0, BNT): xhi/xlo (u16), live step1 -> bn_apply
    u16* xhi = (u16*)ws;
    u16* xlo = xhi + BNT;
    // [BNT, 2BNT): xphi/xplo (u16), live steps 2-3; then concat spans [BNT, 2BNT+BNN)
    u16* xphi = (u16*)(ws + BNT);
    u16* xplo = xphi + BNT;
    u16* cat  = (u16*)(ws + BNT);               // [16384][1536] bf16 = BNT+BNN floats
    // [2BNT, 2BNT+BNN): scores fp32 (dead after topk; overwritten by concat tail)
    float* sc = ws + 2 * BNT;
    float* p4 = ws + 2 * BNT + BNN;
    u16* bufB = (u16*)p4;                        // BNT u16 (Tx^T scratch)
    float* p5 = p4 + BNT / 2;
    u16* bA = (u16*)p5;                          // BNN u16
    float* p6 = p5 + BNN / 2;
    u16* bWc = (u16*)p6;                         // 512*1536 u16
    float* p7 = p6 + (512 * 1536) / 2;
    u16* liwhi = (u16*)p7;                       // 512*512 u16 x2
    u16* liwlo = liwhi + 512 * 512;
    float* p8 = p7 + 262144;
    float* dinv = p8;                            // 16384
    float2* part = (float2*)(dinv + 16384);      // 4096 floats

    // 1. LayerNorm stage A, then apply (finalize fused) -> hi/lo split
    hipLaunchKernelGGL(ln_partial_k, dim3(32, Bb), dim3(256), 0, stream, (const float4*)x, part);
    hipLaunchKernelGGL(ln_apply_split_k, dim3(BNT / 1024), dim3(256), 0, stream,
                       (const float4*)x, (const float4*)ln_w, (const float4*)ln_b, part,
                       (uint2*)xhi, (uint2*)xlo);
    // 1b. param prep: cheb_w^T -> bWc; li_w hi/lo split
    hipLaunchKernelGGL(param_prep_k, dim3(16, 16, 4), dim3(256), 0, stream,
                       cheb_w, bWc, li_w, liwhi, liwlo);
    // 2. xp = x_ln @ li_w^T + li_b  (split-bf16 3-MFMA -> hi/lo)
    hipLaunchKernelGGL((gemm_bf3_k<true, true, false>), dim3(Bb * Nn / 128, Td / 128, 1), dim3(256), 0, stream,
                       xhi, xlo, liwhi, liwlo, li_b, (float*)nullptr, xphi, xplo,
                       Td, Td, 0LL, 0LL, 0LL);
    // 3. scores[b] = xp[b] @ xp[b]^T  (split-bf16 -> fp32)
    hipLaunchKernelGGL((gemm_bf3_k<false, false, true>), dim3(Nn / 128, Nn / 128, Bb), dim3(256), 0, stream,
                       xphi, xplo, xphi, xplo, (const float*)nullptr, sc, (u16*)nullptr, (u16*)nullptr,
                       Nn, Td, (long long)Nn * Td, (long long)Nn * Td, (long long)Nn * Nn);
    // 4. top-k radix-select; A = relu(A_s + dis) -> bf16 bA; dinv
    hipLaunchKernelGGL(topk_sel_k, dim3(Bb * Nn), dim3(256), 0, stream, sc, dis, bA, dinv);
    // 5. BatchNorm stage A, then apply (finalize fused) -> concat cols [0,512)  (Tx0)
    hipLaunchKernelGGL(bn_partial_k, dim3(8, Nn), dim3(256), 0, stream,
                       (const uint2*)xhi, (const uint2*)xlo, part);
    hipLaunchKernelGGL(bn_apply_cast_k, dim3(BNT / 1024), dim3(256), 0, stream,
                       (const uint2*)xhi, (const uint2*)xlo, part, bn_g, bn_b, (uint2*)cat);
    // 6. bufB[b][t][m] = Tx0[b][m][t] * d[b][m]
    hipLaunchKernelGGL(tscale_k, dim3(16, 8, Bb), dim3(256), 0, stream,
                       cat, bufB, (long long)Nn * 1536, 1536, (long long)Td * Nn, Nn,
                       dinv, Nn);
    // 7. Tx1 = d*(A @ (d*Tx0)) -> concat cols [512,1024)
    hipLaunchKernelGGL((gemm_bf_k<false, false, true, false, true>), dim3(Nn / 128, Td / 128, Bb), dim3(256), 0, stream,
                       bA, bufB, (const float*)nullptr, (const u16*)nullptr, 0,
                       (float*)nullptr, cat + 512, 1536, dinv, Nn,
                       1.0f, Td, Nn, (long long)Nn * Nn, (long long)Td * Nn, 0LL, 0LL,
                       (long long)Nn * 1536);
    // 8. bufB[b][t][m] = Tx1[b][m][t] * d[b][m]
    hipLaunchKernelGGL(tscale_k, dim3(16, 8, Bb), dim3(256), 0, stream,
                       cat + 512, bufB, (long long)Nn * 1536, 1536, (long long)Td * Nn, Nn,
                       dinv, Nn);
    // 9. Tx2 = 2*d*(A @ (d*Tx1)) - Tx0 -> concat cols [1024,1536)
    hipLaunchKernelGGL((gemm_bf_k<false, true, true, false, true>), dim3(Nn / 128, Td / 128, Bb), dim3(256), 0, stream,
                       bA, bufB, (const float*)nullptr, cat, 1536,
                       (float*)nullptr, cat + 1024, 1536, dinv, Nn,
                       2.0f, Td, Nn, (long long)Nn * Nn, (long long)Td * Nn, (long long)Nn * 1536, 0LL,
                       (long long)Nn * 1536);
    // 10. out = relu([Tx0|Tx1|Tx2] @ [W0;W1;W2]^T + cheb_b)   (K=1536)
    hipLaunchKernelGGL((gemm_bf_k<true, false, false, true, false>), dim3(Bb * Nn / 128, Td / 128, 1), dim3(256), 0, stream,
                       cat, bWc, cheb_b, (const u16*)nullptr, 0,
                       out, (u16*)nullptr, 0, (const float*)nullptr, 0,
                       1.0f, Td, 1536, 0LL, 0LL, 0LL, 0LL, 0LL);
}

// Round 9
// 303.281 us; speedup vs baseline: 3.8252x; 1.0136x over previous
//
#include <hip/hip_runtime.h>
#include <cstddef>

static constexpr int Bb = 64;     // batch
static constexpr int Nn = 256;    // nodes
static constexpr int Td = 512;    // time dim
static constexpr int NMAXS = 51;  // 256 // 5
static constexpr float EPSN = 1e-5f;
static constexpr float EPSD = 1e-10f;

typedef unsigned short u16;
typedef __attribute__((ext_vector_type(8))) short short8;
typedef __attribute__((ext_vector_type(4))) float f32x4;

__device__ __forceinline__ u16 f2b(float f) {
    unsigned u = __float_as_uint(f);
    return (u16)((u + 0x7fffu + ((u >> 16) & 1u)) >> 16);
}
__device__ __forceinline__ float b2f(u16 h) {
    return __uint_as_float(((unsigned)h) << 16);
}
__device__ __forceinline__ float4 unp2(uint2 h, uint2 l) {
    float4 r;
    r.x = b2f((u16)h.x) + b2f((u16)l.x);
    r.y = b2f((u16)(h.x >> 16)) + b2f((u16)(l.x >> 16));
    r.z = b2f((u16)h.y) + b2f((u16)l.y);
    r.w = b2f((u16)(h.y >> 16)) + b2f((u16)(l.y >> 16));
    return r;
}

// async global->LDS DMA, 16B/lane. LDS dest = wave-uniform base + lane*16.
__device__ __forceinline__ void gload_lds(const u16* g, u16* l) {
    __builtin_amdgcn_global_load_lds(
        (const __attribute__((address_space(1))) unsigned int*)g,
        (__attribute__((address_space(3))) unsigned int*)l, 16, 0, 0);
}
__device__ __forceinline__ int swz4(int r) { return (r ^ (r >> 2)) & 3; }

// ---------------- LayerNorm stats stage A ----------------
__global__ __launch_bounds__(256) void ln_partial_k(const float4* __restrict__ x,
                                                    float2* __restrict__ part) {
    int b = blockIdx.y, c = blockIdx.x;
    int base = b * 32768 + c * 1024;
    float s = 0.f, s2 = 0.f;
#pragma unroll
    for (int j = 0; j < 4; ++j) {
        float4 v = x[base + j * 256 + threadIdx.x];
        s += v.x + v.y + v.z + v.w;
        s2 += v.x * v.x + v.y * v.y + v.z * v.z + v.w * v.w;
    }
    __shared__ float sh[256], sh2[256];
    sh[threadIdx.x] = s; sh2[threadIdx.x] = s2;
    __syncthreads();
    for (int o = 128; o > 0; o >>= 1) {
        if (threadIdx.x < o) { sh[threadIdx.x] += sh[threadIdx.x + o]; sh2[threadIdx.x] += sh2[threadIdx.x + o]; }
        __syncthreads();
    }
    if (threadIdx.x == 0) part[b * 32 + c] = make_float2(sh[0], sh2[0]);
}

// LN apply (finalize fused via shfl over 32 partials): hi/lo bf16 split out
__global__ __launch_bounds__(256) void ln_apply_split_k(const float4* __restrict__ x,
                                                        const float4* __restrict__ w,
                                                        const float4* __restrict__ bia,
                                                        const float2* __restrict__ part,
                                                        uint2* __restrict__ xhi,
                                                        uint2* __restrict__ xlo) {
    int i = blockIdx.x * 256 + threadIdx.x;
    int r = i & ((Nn * Td / 4) - 1);
    int b = i >> 15;
    float2 p = part[b * 32 + (threadIdx.x & 31)];
    float s = p.x, s2 = p.y;
#pragma unroll
    for (int o = 16; o > 0; o >>= 1) { s += __shfl_xor(s, o, 32); s2 += __shfl_xor(s2, o, 32); }
    float inv = 1.f / (Nn * Td);
    float mu = s * inv;
    float var = s2 * inv - mu * mu;
    float rs = rsqrtf(var + EPSN);
    float4 xv = x[i], wv = w[r], bv = bia[r];
    float4 o;
    o.x = (xv.x - mu) * rs * wv.x + bv.x;
    o.y = (xv.y - mu) * rs * wv.y + bv.y;
    o.z = (xv.z - mu) * rs * wv.z + bv.z;
    o.w = (xv.w - mu) * rs * wv.w + bv.w;
    u16 hx = f2b(o.x), hy = f2b(o.y), hz = f2b(o.z), hw = f2b(o.w);
    uint2 ph, pl;
    ph.x = (unsigned)hx | ((unsigned)hy << 16);
    ph.y = (unsigned)hz | ((unsigned)hw << 16);
    pl.x = (unsigned)f2b(o.x - b2f(hx)) | ((unsigned)f2b(o.y - b2f(hy)) << 16);
    pl.y = (unsigned)f2b(o.z - b2f(hz)) | ((unsigned)f2b(o.w - b2f(hw)) << 16);
    xhi[i] = ph;
    xlo[i] = pl;
}

// ---------------- param prep: cheb_w^T -> bWc (z<3) ; li_w hi/lo split (z==3) ----------------
__global__ __launch_bounds__(256) void param_prep_k(const float* __restrict__ cheb_w,
                                                    u16* __restrict__ bWc,
                                                    const float* __restrict__ li_w,
                                                    u16* __restrict__ liwhi,
                                                    u16* __restrict__ liwlo) {
    int z = blockIdx.z;
    int c0 = blockIdx.x * 32, r0 = blockIdx.y * 32;
    int tx = threadIdx.x & 31, ty = threadIdx.x >> 5;
    if (z < 3) {
        __shared__ u16 tile[32][33];
        const float* ip = cheb_w + (size_t)z * Td * Td;
#pragma unroll
        for (int i = 0; i < 4; ++i) {
            int r = ty + i * 8;
            tile[r][tx] = f2b(ip[(size_t)(r0 + r) * Td + c0 + tx]);
        }
        __syncthreads();
#pragma unroll
        for (int i = 0; i < 4; ++i) {
            int c = ty + i * 8;
            bWc[(size_t)(c0 + c) * 1536 + z * 512 + (r0 + tx)] = tile[tx][c];
        }
    } else {
#pragma unroll
        for (int i = 0; i < 4; ++i) {
            int r = r0 + ty + i * 8;
            size_t idx = (size_t)r * Td + c0 + tx;
            float v = li_w[idx];
            u16 h = f2b(v);
            liwhi[idx] = h;
            liwlo[idx] = f2b(v - b2f(h));
        }
    }
}

// ---------------- BatchNorm stats stage A (from hi/lo split) ----------------
__global__ __launch_bounds__(256) void bn_partial_k(const uint2* __restrict__ xhi,
                                                    const uint2* __restrict__ xlo,
                                                    float2* __restrict__ part) {
    int n = blockIdx.y, c = blockIdx.x;
    float s = 0.f, s2 = 0.f;
#pragma unroll
    for (int j = 0; j < 4; ++j) {
        int f = j * 256 + threadIdx.x;
        int bl = f >> 7, t4 = f & 127;
        size_t idx = ((size_t)(c * 8 + bl) * Nn + n) * 128 + t4;
        float4 v = unp2(xhi[idx], xlo[idx]);
        s += v.x + v.y + v.z + v.w;
        s2 += v.x * v.x + v.y * v.y + v.z * v.z + v.w * v.w;
    }
    __shared__ float sh[256], sh2[256];
    sh[threadIdx.x] = s; sh2[threadIdx.x] = s2;
    __syncthreads();
    for (int o = 128; o > 0; o >>= 1) {
        if (threadIdx.x < o) { sh[threadIdx.x] += sh[threadIdx.x + o]; sh2[threadIdx.x] += sh2[threadIdx.x + o]; }
        __syncthreads();
    }
    if (threadIdx.x == 0) part[n * 8 + c] = make_float2(sh[0], sh2[0]);
}

// BN apply (finalize fused via shfl over 8 partials); writes Tx0 bf16 into cat[.,0:512]
__global__ __launch_bounds__(256) void bn_apply_cast_k(const uint2* __restrict__ xhi,
                                                       const uint2* __restrict__ xlo,
                                                       const float2* __restrict__ part,
                                                       const float* __restrict__ g,
                                                       const float* __restrict__ be,
                                                       uint2* __restrict__ cat) {
    int i = blockIdx.x * 256 + threadIdx.x;   // uint2 index over BNT/4
    int row = i >> 7, c4 = i & 127;
    int n = row & 255;
    float2 p = part[n * 8 + (threadIdx.x & 7)];
    float s = p.x, s2 = p.y;
#pragma unroll
    for (int o = 4; o > 0; o >>= 1) { s += __shfl_xor(s, o, 8); s2 += __shfl_xor(s2, o, 8); }
    float inv = 1.f / (Bb * Td);
    float mu = s * inv;
    float var = s2 * inv - mu * mu;
    float rs = rsqrtf(var + EPSN);
    float scale = rs * g[n];
    float shift = be[n] - mu * scale;
    float4 v = unp2(xhi[i], xlo[i]);
    v.x = v.x * scale + shift; v.y = v.y * scale + shift;
    v.z = v.z * scale + shift; v.w = v.w * scale + shift;
    uint2 o2;
    o2.x = (unsigned)f2b(v.x) | ((unsigned)f2b(v.y) << 16);
    o2.y = (unsigned)f2b(v.z) | ((unsigned)f2b(v.w) << 16);
    cat[(size_t)row * 384 + c4] = o2;   // 1536 u16 = 384 uint2 per row
}

// ---------------- top-k radix-select + adjacency; writes bf16 A + dinv ----------------
__global__ __launch_bounds__(256) void topk_sel_k(const float* __restrict__ sc,
                                                  const float* __restrict__ dis,
                                                  u16* __restrict__ bA,
                                                  float* __restrict__ dinv) {
    int row = blockIdx.x;
    int n = row & 255;
    int tid = threadIdx.x;
    int lane = tid & 63, wv = tid >> 6;
    const float* srow = sc + (size_t)row * Nn;
    float v = srow[tid];
    unsigned fu = __float_as_uint(v);
    unsigned key = (fu & 0x80000000u) ? ~fu : (fu | 0x80000000u);
    __shared__ int hist[256];
    __shared__ int cum[256];
    __shared__ unsigned sh_pref;
    __shared__ int sh_rank;
    __shared__ float wsum[4];
    if (tid == 0) { sh_pref = 0u; sh_rank = Nn - NMAXS; }  // 205
    __syncthreads();
#pragma unroll
    for (int shift = 24; shift >= 0; shift -= 8) {
        unsigned mhi = (shift == 24) ? 0u : (0xFFFFFFFFu << (shift + 8));
        unsigned pref = sh_pref;
        int rank = sh_rank;
        hist[tid] = 0;
        __syncthreads();
        if ((key & mhi) == pref) atomicAdd(&hist[(key >> shift) & 255], 1);
        __syncthreads();
        if (tid < 64) {
            int4 h = *(const int4*)&hist[tid * 4];
            int s0 = h.x, s1 = s0 + h.y, s2 = s1 + h.z, s3 = s2 + h.w;
            int t = s3;
#pragma unroll
            for (int o = 1; o < 64; o <<= 1) { int y = __shfl_up(t, o, 64); if (lane >= o) t += y; }
            int excl = t - s3;
            cum[tid * 4]     = excl + s0;
            cum[tid * 4 + 1] = excl + s1;
            cum[tid * 4 + 2] = excl + s2;
            cum[tid * 4 + 3] = excl + s3;
        }
        __syncthreads();
        int below = (tid == 0) ? 0 : cum[tid - 1];
        if (cum[tid] > rank && below <= rank) {
            sh_pref = pref | ((unsigned)tid << shift);
            sh_rank = rank - below;
        }
        __syncthreads();
    }
    unsigned kk = sh_pref;
    float kth = __uint_as_float((kk & 0x80000000u) ? (kk & 0x7FFFFFFFu) : ~kk);
    float as = (v >= kth) ? v : 0.f;
    float a = fmaxf(as + dis[(size_t)n * Nn + tid], 0.f);
    bA[(size_t)row * Nn + tid] = f2b(a);
    float s = a;
#pragma unroll
    for (int o = 32; o > 0; o >>= 1) s += __shfl_down(s, o, 64);
    if (lane == 0) wsum[wv] = s;
    __syncthreads();
    if (tid == 0) dinv[row] = rsqrtf(wsum[0] + wsum[1] + wsum[2] + wsum[3] + EPSD);
}

// ---------------- transpose u16 (+per-input-row scale) ----------------
__global__ __launch_bounds__(256) void tscale_k(const u16* __restrict__ in,
                                                u16* __restrict__ out,
                                                long long ibz, int ildr,
                                                long long obz, int oldr,
                                                const float* __restrict__ rs, int rsz) {
    __shared__ u16 tile[32][33];
    int b = blockIdx.z;
    int c0 = blockIdx.x * 32, r0 = blockIdx.y * 32;
    int tx = threadIdx.x & 31, ty = threadIdx.x >> 5;
#pragma unroll
    for (int i = 0; i < 4; ++i) {
        int r = ty + i * 8;
        float f = b2f(in[(size_t)b * ibz + (size_t)(r0 + r) * ildr + c0 + tx]);
        f *= rs[b * rsz + r0 + r];
        tile[r][tx] = f2b(f);
    }
    __syncthreads();
#pragma unroll
    for (int i = 0; i < 4; ++i) {
        int c = ty + i * 8;
        out[(size_t)b * obz + (size_t)(c0 + c) * oldr + (r0 + tx)] = tile[tx][c];
    }
}

// ---------------- bf16 MFMA GEMM, NT, DMA + double-buffered prefetch, BK=64 ----------------
// Pipeline: stage(buf0); loop { barrier(drains last stage); prefetch(buf^1); compute(buf); }
// The barrier's vmcnt(0) drain targets a DMA issued one full compute phase earlier -> cheap.
template <bool FINAL, bool SUBPREV, bool RSCALE, bool WF32, bool WBF>
__global__ __launch_bounds__(256) void gemm_bf_k(const u16* __restrict__ A,
                                                 const u16* __restrict__ Bt,
                                                 const float* __restrict__ bias,
                                                 const u16* __restrict__ prevb, int ldprev,
                                                 float* __restrict__ C,
                                                 u16* __restrict__ Cb, int ldcb,
                                                 const float* __restrict__ rscale, int rsz,
                                                 float alpha, int Ncols, int K,
                                                 long long sA, long long sB, long long sPrev,
                                                 long long sC, long long sCb) {
    __shared__ u16 As[2][8192];   // [buf][h*4096 + row*32 + swizzled chunk]
    __shared__ u16 Bs[2][8192];
    int z = blockIdx.z;
    const u16* Ag = A + (size_t)z * sA;
    const u16* Bg = Bt + (size_t)z * sB;
    int br = blockIdx.x * 128, bc = blockIdx.y * 128;
    int tid = threadIdx.x, lane = tid & 63, wave = tid >> 6;
    int wr = (wave >> 1) * 64, wc = (wave & 1) * 64;
    int i0 = wave * 2;
    int rl0 = i0 * 16 + (lane >> 2);
    int rl1 = rl0 + 16;
    int cp = lane & 3;
    int ca0 = (cp ^ swz4(rl0)) * 8;
    int ca1 = (cp ^ swz4(rl1)) * 8;
    const u16* gA0 = Ag + (size_t)(br + rl0) * K + ca0;
    const u16* gA1 = Ag + (size_t)(br + rl1) * K + ca1;
    const u16* gB0 = Bg + (size_t)(bc + rl0) * K + ca0;
    const u16* gB1 = Bg + (size_t)(bc + rl1) * K + ca1;
    f32x4 acc[4][4] = {};
    int fr = lane & 15, fq = lane >> 4;
    auto stage = [&](int buf, int k0) {
#pragma unroll
        for (int h = 0; h < 2; ++h) {
            int kk = k0 + h * 32;
            int ho = h * 4096;
            gload_lds(gA0 + kk, &As[buf][ho + i0 * 512]);
            gload_lds(gA1 + kk, &As[buf][ho + i0 * 512 + 512]);
            gload_lds(gB0 + kk, &Bs[buf][ho + i0 * 512]);
            gload_lds(gB1 + kk, &Bs[buf][ho + i0 * 512 + 512]);
        }
    };
    int nIter = K >> 6;
    stage(0, 0);
    for (int it = 0; it < nIter; ++it) {
        int cur = it & 1;
        __syncthreads();                       // drains stage(cur) issued one iter ago
        if (it + 1 < nIter) stage(1 - cur, (it + 1) << 6);
#pragma unroll
        for (int h = 0; h < 2; ++h) {
            int ho = h * 4096;
            short8 af[4], bf[4];
#pragma unroll
            for (int mi = 0; mi < 4; ++mi) {
                int rr = wr + mi * 16 + fr;
                af[mi] = *(const short8*)&As[cur][ho + rr * 32 + ((fq ^ swz4(rr)) << 3)];
            }
#pragma unroll
            for (int ni = 0; ni < 4; ++ni) {
                int rr = wc + ni * 16 + fr;
                bf[ni] = *(const short8*)&Bs[cur][ho + rr * 32 + ((fq ^ swz4(rr)) << 3)];
            }
#pragma unroll
            for (int mi = 0; mi < 4; ++mi)
#pragma unroll
                for (int ni = 0; ni < 4; ++ni)
                    acc[mi][ni] = __builtin_amdgcn_mfma_f32_16x16x32_bf16(af[mi], bf[ni], acc[mi][ni], 0, 0, 0);
        }
    }
    const u16* Pp = SUBPREV ? prevb + (size_t)z * sPrev : nullptr;
    float* Cp = WF32 ? C + (size_t)z * sC : nullptr;
    u16* Cbp = WBF ? Cb + (size_t)z * sCb : nullptr;
    const float* rsp = RSCALE ? rscale + (size_t)z * rsz : nullptr;
#pragma unroll
    for (int mi = 0; mi < 4; ++mi) {
#pragma unroll
        for (int rg = 0; rg < 4; ++rg) {
            int row = br + wr + mi * 16 + fq * 4 + rg;
            float rowsc = RSCALE ? rsp[row] : 1.f;
#pragma unroll
            for (int ni = 0; ni < 4; ++ni) {
                int col = bc + wc + ni * 16 + fr;
                float v = alpha * acc[mi][ni][rg];
                if (RSCALE) v *= rowsc;
                if (SUBPREV) v -= b2f(Pp[(size_t)row * ldprev + col]);
                if (FINAL) v = fmaxf(v + bias[col], 0.f);
                if (WF32) Cp[(size_t)row * Ncols + col] = v;
                if (WBF) Cbp[(size_t)row * ldcb + col] = f2b(v);
            }
        }
    }
}

// ---------------- split-bf16 3-MFMA GEMM, NT, DMA + double-buffered prefetch, BK=32 ----------------
template <bool BIAS, bool WSPLIT, bool WF32>
__global__ __launch_bounds__(256) void gemm_bf3_k(const u16* __restrict__ Ahi,
                                                  const u16* __restrict__ Alo,
                                                  const u16* __restrict__ Bhi,
                                                  const u16* __restrict__ Blo,
                                                  const float* __restrict__ bias,
                                                  float* __restrict__ C,
                                                  u16* __restrict__ Chi,
                                                  u16* __restrict__ Clo,
                                                  int Ncols, int K,
                                                  long long sA, long long sB, long long sC) {
    __shared__ u16 Ash[2][4096];
    __shared__ u16 Asl[2][4096];
    __shared__ u16 Bsh[2][4096];
    __shared__ u16 Bsl[2][4096];
    int z = blockIdx.z;
    const u16* Agh = Ahi + (size_t)z * sA;
    const u16* Agl = Alo + (size_t)z * sA;
    const u16* Bgh = Bhi + (size_t)z * sB;
    const u16* Bgl = Blo + (size_t)z * sB;
    int br = blockIdx.x * 128, bc = blockIdx.y * 128;
    int tid = threadIdx.x, lane = tid & 63, wave = tid >> 6;
    int wr = (wave >> 1) * 64, wc = (wave & 1) * 64;
    int i0 = wave * 2;
    int rl0 = i0 * 16 + (lane >> 2);
    int rl1 = rl0 + 16;
    int cp = lane & 3;
    int ca0 = (cp ^ swz4(rl0)) * 8;
    int ca1 = (cp ^ swz4(rl1)) * 8;
    size_t oA0 = (size_t)(br + rl0) * K + ca0;
    size_t oA1 = (size_t)(br + rl1) * K + ca1;
    size_t oB0 = (size_t)(bc + rl0) * K + ca0;
    size_t oB1 = (size_t)(bc + rl1) * K + ca1;
    f32x4 acc[4][4] = {};
    int fr = lane & 15, fq = lane >> 4;
    auto stage = [&](int buf, int kk) {
        gload_lds(Agh + oA0 + kk, &Ash[buf][i0 * 512]);
        gload_lds(Agh + oA1 + kk, &Ash[buf][i0 * 512 + 512]);
        gload_lds(Agl + oA0 + kk, &Asl[buf][i0 * 512]);
        gload_lds(Agl + oA1 + kk, &Asl[buf][i0 * 512 + 512]);
        gload_lds(Bgh + oB0 + kk, &Bsh[buf][i0 * 512]);
        gload_lds(Bgh + oB1 + kk, &Bsh[buf][i0 * 512 + 512]);
        gload_lds(Bgl + oB0 + kk, &Bsl[buf][i0 * 512]);
        gload_lds(Bgl + oB1 + kk, &Bsl[buf][i0 * 512 + 512]);
    };
    int nIter = K >> 5;
    stage(0, 0);
    for (int it = 0; it < nIter; ++it) {
        int cur = it & 1;
        __syncthreads();
        if (it + 1 < nIter) stage(1 - cur, (it + 1) << 5);
        short8 afh[4], afl[4], bfh[4], bfl[4];
#pragma unroll
        for (int mi = 0; mi < 4; ++mi) {
            int rr = wr + mi * 16 + fr;
            int off = rr * 32 + ((fq ^ swz4(rr)) << 3);
            afh[mi] = *(const short8*)&Ash[cur][off];
            afl[mi] = *(const short8*)&Asl[cur][off];
        }
#pragma unroll
        for (int ni = 0; ni < 4; ++ni) {
            int rr = wc + ni * 16 + fr;
            int off = rr * 32 + ((fq ^ swz4(rr)) << 3);
            bfh[ni] = *(const short8*)&Bsh[cur][off];
            bfl[ni] = *(const short8*)&Bsl[cur][off];
        }
#pragma unroll
        for (int mi = 0; mi < 4; ++mi)
#pragma unroll
            for (int ni = 0; ni < 4; ++ni) {
                acc[mi][ni] = __builtin_amdgcn_mfma_f32_16x16x32_bf16(afh[mi], bfh[ni], acc[mi][ni], 0, 0, 0);
                acc[mi][ni] = __builtin_amdgcn_mfma_f32_16x16x32_bf16(afh[mi], bfl[ni], acc[mi][ni], 0, 0, 0);
                acc[mi][ni] = __builtin_amdgcn_mfma_f32_16x16x32_bf16(afl[mi], bfh[ni], acc[mi][ni], 0, 0, 0);
            }
    }
    float* Cp = WF32 ? C + (size_t)z * sC : nullptr;
    u16* Chp = WSPLIT ? Chi + (size_t)z * sC : nullptr;
    u16* Clp = WSPLIT ? Clo + (size_t)z * sC : nullptr;
#pragma unroll
    for (int mi = 0; mi < 4; ++mi) {
#pragma unroll
        for (int rg = 0; rg < 4; ++rg) {
            int row = br + wr + mi * 16 + fq * 4 + rg;
            size_t rb = (size_t)row * Ncols;
#pragma unroll
            for (int ni = 0; ni < 4; ++ni) {
                int col = bc + wc + ni * 16 + fr;
                float v = acc[mi][ni][rg];
                if (BIAS) v += bias[col];
                if (WF32) Cp[rb + col] = v;
                if (WSPLIT) {
                    u16 h = f2b(v);
                    Chp[rb + col] = h;
                    Clp[rb + col] = f2b(v - b2f(h));
                }
            }
        }
    }
}

extern "C" void kernel_launch(void* const* d_in, const int* in_sizes, int n_in,
                              void* d_out, int out_size, void* d_ws, size_t ws_size,
                              hipStream_t stream) {
    const float* x      = (const float*)d_in[0];
    const float* dis    = (const float*)d_in[1];
    const float* ln_w   = (const float*)d_in[2];
    const float* ln_b   = (const float*)d_in[3];
    const float* bn_g   = (const float*)d_in[4];
    const float* bn_b   = (const float*)d_in[5];
    const float* li_w   = (const float*)d_in[6];
    const float* li_b   = (const float*)d_in[7];
    const float* cheb_w = (const float*)d_in[8];
    const float* cheb_b = (const float*)d_in[9];
    float* out = (float*)d_out;

    const size_t BNT = (size_t)Bb * Nn * Td;   // 8388608
    const size_t BNN = (size_t)Bb * Nn * Nn;   // 4194304
    float* ws = (float*)d_ws;
    u16* xhi = (u16*)ws;
    u16* xlo = xhi + BNT;
    u16* xphi = (u16*)(ws + BNT);
    u16* xplo = xphi + BNT;
    u16* cat  = (u16*)(ws + BNT);               // [16384][1536] bf16
    float* sc = ws + 2 * BNT;
    float* p4 = ws + 2 * BNT + BNN;
    u16* bufB = (u16*)p4;                        // BNT u16 (Tx^T scratch)
    float* p5 = p4 + BNT / 2;
    u16* bA = (u16*)p5;                          // BNN u16
    float* p6 = p5 + BNN / 2;
    u16* bWc = (u16*)p6;                         // 512*1536 u16
    float* p7 = p6 + (512 * 1536) / 2;
    u16* liwhi = (u16*)p7;                       // 512*512 u16 x2
    u16* liwlo = liwhi + 512 * 512;
    float* p8 = p7 + 262144;
    float* dinv = p8;                            // 16384
    float2* part = (float2*)(dinv + 16384);      // 4096 floats

    // 1. LayerNorm stage A, then apply (finalize fused) -> hi/lo split
    hipLaunchKernelGGL(ln_partial_k, dim3(32, Bb), dim3(256), 0, stream, (const float4*)x, part);
    hipLaunchKernelGGL(ln_apply_split_k, dim3(BNT / 1024), dim3(256), 0, stream,
                       (const float4*)x, (const float4*)ln_w, (const float4*)ln_b, part,
                       (uint2*)xhi, (uint2*)xlo);
    // 1b. param prep: cheb_w^T -> bWc; li_w hi/lo split
    hipLaunchKernelGGL(param_prep_k, dim3(16, 16, 4), dim3(256), 0, stream,
                       cheb_w, bWc, li_w, liwhi, liwlo);
    // 2. xp = x_ln @ li_w^T + li_b  (split-bf16 3-MFMA -> hi/lo)
    hipLaunchKernelGGL((gemm_bf3_k<true, true, false>), dim3(Bb * Nn / 128, Td / 128, 1), dim3(256), 0, stream,
                       xhi, xlo, liwhi, liwlo, li_b, (float*)nullptr, xphi, xplo,
                       Td, Td, 0LL, 0LL, 0LL);
    // 3. scores[b] = xp[b] @ xp[b]^T  (split-bf16 -> fp32)
    hipLaunchKernelGGL((gemm_bf3_k<false, false, true>), dim3(Nn / 128, Nn / 128, Bb), dim3(256), 0, stream,
                       xphi, xplo, xphi, xplo, (const float*)nullptr, sc, (u16*)nullptr, (u16*)nullptr,
                       Nn, Td, (long long)Nn * Td, (long long)Nn * Td, (long long)Nn * Nn);
    // 4. top-k radix-select; A = relu(A_s + dis) -> bf16 bA; dinv
    hipLaunchKernelGGL(topk_sel_k, dim3(Bb * Nn), dim3(256), 0, stream, sc, dis, bA, dinv);
    // 5. BatchNorm stage A, then apply (finalize fused) -> concat cols [0,512)  (Tx0)
    hipLaunchKernelGGL(bn_partial_k, dim3(8, Nn), dim3(256), 0, stream,
                       (const uint2*)xhi, (const uint2*)xlo, part);
    hipLaunchKernelGGL(bn_apply_cast_k, dim3(BNT / 1024), dim3(256), 0, stream,
                       (const uint2*)xhi, (const uint2*)xlo, part, bn_g, bn_b, (uint2*)cat);
    // 6. bufB[b][t][m] = Tx0[b][m][t] * d[b][m]
    hipLaunchKernelGGL(tscale_k, dim3(16, 8, Bb), dim3(256), 0, stream,
                       cat, bufB, (long long)Nn * 1536, 1536, (long long)Td * Nn, Nn,
                       dinv, Nn);
    // 7. Tx1 = d*(A @ (d*Tx0)) -> concat cols [512,1024)
    hipLaunchKernelGGL((gemm_bf_k<false, false, true, false, true>), dim3(Nn / 128, Td / 128, Bb), dim3(256), 0, stream,
                       bA, bufB, (const float*)nullptr, (const u16*)nullptr, 0,
                       (float*)nullptr, cat + 512, 1536, dinv, Nn,
                       1.0f, Td, Nn, (long long)Nn * Nn, (long long)Td * Nn, 0LL, 0LL,
                       (long long)Nn * 1536);
    // 8. bufB[b][t][m] = Tx1[b][m][t] * d[b][m]
    hipLaunchKernelGGL(tscale_k, dim3(16, 8, Bb), dim3(256), 0, stream,
                       cat + 512, bufB, (long long)Nn * 1536, 1536, (long long)Td * Nn, Nn,
                       dinv, Nn);
    // 9. Tx2 = 2*d*(A @ (d*Tx1)) - Tx0 -> concat cols [1024,1536)
    hipLaunchKernelGGL((gemm_bf_k<false, true, true, false, true>), dim3(Nn / 128, Td / 128, Bb), dim3(256), 0, stream,
                       bA, bufB, (const float*)nullptr, cat, 1536,
                       (float*)nullptr, cat + 1024, 1536, dinv, Nn,
                       2.0f, Td, Nn, (long long)Nn * Nn, (long long)Td * Nn, (long long)Nn * 1536, 0LL,
                       (long long)Nn * 1536);
    // 10. out = relu([Tx0|Tx1|Tx2] @ [W0;W1;W2]^T + cheb_b)   (K=1536)
    hipLaunchKernelGGL((gemm_bf_k<true, false, false, true, false>), dim3(Bb * Nn / 128, Td / 128, 1), dim3(256), 0, stream,
                       cat, bWc, cheb_b, (const u16*)nullptr, 0,
                       out, (u16*)nullptr, 0, (const float*)nullptr, 0,
                       1.0f, Td, 1536, 0LL, 0LL, 0LL, 0LL, 0LL);
}